// Round 3
// baseline (783.760 us; speedup 1.0000x reference)
//
#include <hip/hip_runtime.h>
#include <hip/hip_bf16.h>

typedef __hip_bfloat16 bf16;
#define DI __device__ __forceinline__

constexpr int CH = 128;
constexpr int HH = 96, WW = 96;
constexpr int HW = HH * WW;        // 9216
constexpr int NB = 4;
constexpr int NPIX = NB * HW;      // 36864
constexpr int DKH = 32;            // head dim

struct __attribute__((aligned(8)))  bf16x4 { bf16 h[4]; };
struct __attribute__((aligned(16))) bf16x8 { bf16 h[8]; };

DI float b2f(bf16 x) { return __bfloat162float(x); }
DI bf16  f2b(float x) { return __float2bfloat16(x); }

// ---------------------------------------------------------------------------
// 1x1 conv over channels == per-pixel GEMM: out[o,p] = sum_c W[o,c] x[c,p]
// External dtypes: W/bias always f32. x/resid: f32 (XF32/RF32) or bf16 stages.
// Output: bf16 stage (OUTF32=0) or f32 pre-LN scratch (OUTF32=1).
// Block: 256 threads, tile = 64 pixels x 128 outs. Thread = 8 px x 4 outs.
// W and x are converted to bf16 in LDS (bf16-tolerance mode licenses this).
// ---------------------------------------------------------------------------
template<bool XF32, bool RF32, bool BIAS, bool RELU, bool RESID, bool OUTF32>
__global__ __launch_bounds__(256, 2)
void conv1x1(const void* __restrict__ xv, const float* __restrict__ w,
             const float* __restrict__ bias, const void* __restrict__ residv,
             void* __restrict__ outp)
{
    __shared__ bf16 wl[CH * 132];
    __shared__ bf16 xl[CH][64];
    const int t = threadIdx.x;

    // W: f32 coalesced load -> bf16 LDS, padded stride 132
    #pragma unroll
    for (int i = 0; i < 8; ++i) {
        int vi = t + 256 * i;              // 0..2047
        int o  = vi >> 4;                  // 0..127
        int c0 = (vi & 15) * 8;            // 0..120
        float4 a = *reinterpret_cast<const float4*>(w + o * CH + c0);
        float4 c = *reinterpret_cast<const float4*>(w + o * CH + c0 + 4);
        bf16x4 lo = { f2b(a.x), f2b(a.y), f2b(a.z), f2b(a.w) };
        bf16x4 hi = { f2b(c.x), f2b(c.y), f2b(c.z), f2b(c.w) };
        *reinterpret_cast<bf16x4*>(&wl[o * 132 + c0])     = lo;
        *reinterpret_cast<bf16x4*>(&wl[o * 132 + c0 + 4]) = hi;
    }

    const int pb  = blockIdx.x * 64;       // tiles never straddle batch (HW%64==0)
    const int b   = pb / HW;
    const int hw0 = pb % HW;
    const size_t xoff = (size_t)b * CH * HW + hw0;
    #pragma unroll
    for (int i = 0; i < 8; ++i) {
        int vi = t + 256 * i;
        int c  = vi >> 4;                  // channel 0..127
        int p4 = (vi & 15) * 4;            // pixel 0..60
        bf16x4 pk;
        if (XF32) {
            float4 v = *reinterpret_cast<const float4*>(
                (const float*)xv + xoff + (size_t)c * HW + p4);
            pk.h[0] = f2b(v.x); pk.h[1] = f2b(v.y);
            pk.h[2] = f2b(v.z); pk.h[3] = f2b(v.w);
        } else {
            pk = *reinterpret_cast<const bf16x4*>(
                (const bf16*)xv + xoff + (size_t)c * HW + p4);
        }
        *reinterpret_cast<bf16x4*>(&xl[c][p4]) = pk;
    }
    __syncthreads();

    const int pg = t & 7, og = t >> 3;
    const int pp = pg * 8, oo = og * 4;
    float acc[4][8];
    #pragma unroll
    for (int j = 0; j < 4; ++j)
        #pragma unroll
        for (int i = 0; i < 8; ++i) acc[j][i] = 0.f;

    #pragma unroll 4
    for (int c = 0; c < CH; ++c) {
        bf16x8 xv8 = *reinterpret_cast<const bf16x8*>(&xl[c][pp]);
        float xf[8];
        #pragma unroll
        for (int i = 0; i < 8; ++i) xf[i] = b2f(xv8.h[i]);
        #pragma unroll
        for (int j = 0; j < 4; ++j) {
            float wf = b2f(wl[(oo + j) * 132 + c]);
            #pragma unroll
            for (int i = 0; i < 8; ++i) acc[j][i] += wf * xf[i];
        }
    }

    const size_t ob = (size_t)b * CH * HW + hw0 + pp;
    #pragma unroll
    for (int j = 0; j < 4; ++j) {
        const int o = oo + j;
        float r[8];
        #pragma unroll
        for (int i = 0; i < 8; ++i) r[i] = acc[j][i];
        if (BIAS) {
            float bv = bias[o];
            #pragma unroll
            for (int i = 0; i < 8; ++i) r[i] += bv;
        }
        if (RESID) {
            if (RF32) {
                const float* rp = (const float*)residv + ob + (size_t)o * HW;
                float4 a = *reinterpret_cast<const float4*>(rp);
                float4 c = *reinterpret_cast<const float4*>(rp + 4);
                r[0] += a.x; r[1] += a.y; r[2] += a.z; r[3] += a.w;
                r[4] += c.x; r[5] += c.y; r[6] += c.z; r[7] += c.w;
            } else {
                bf16x8 rv = *reinterpret_cast<const bf16x8*>(
                    (const bf16*)residv + ob + (size_t)o * HW);
                #pragma unroll
                for (int i = 0; i < 8; ++i) r[i] += b2f(rv.h[i]);
            }
        }
        if (RELU) {
            #pragma unroll
            for (int i = 0; i < 8; ++i) r[i] = fmaxf(r[i], 0.f);
        }
        if (OUTF32) {
            float* op = (float*)outp + ob + (size_t)o * HW;
            *reinterpret_cast<float4*>(op)     = make_float4(r[0], r[1], r[2], r[3]);
            *reinterpret_cast<float4*>(op + 4) = make_float4(r[4], r[5], r[6], r[7]);
        } else {
            bf16x8 pv;
            #pragma unroll
            for (int i = 0; i < 8; ++i) pv.h[i] = f2b(r[i]);
            *reinterpret_cast<bf16x8*>((bf16*)outp + ob + (size_t)o * HW) = pv;
        }
    }
}

// ---------------------------------------------------------------------------
// 5x5 zero-padded local attention over bf16 stages, softmax over 25 shifts
// (temp sqrt(32)). OOB shifts keep logit exactly 0 in the denominator.
// T MAY ALIAS Q: each thread reads only its own Q elements before writing T
// at the same addresses -> no __restrict__ on Q/T.
// ---------------------------------------------------------------------------
__global__ __launch_bounds__(256)
void attn5(const bf16* Q, const bf16* __restrict__ K,
           const bf16* __restrict__ V, bf16* T)
{
    const int p  = blockIdx.x * 256 + threadIdx.x;   // 0..36863
    const int n  = blockIdx.y;                        // head
    const int b  = p / HW;
    const int hw = p % HW;
    const int yy = hw / WW, xx = hw % WW;
    const size_t cb = ((size_t)b * CH + n * DKH) * HW + hw;

    float q[DKH];
    #pragma unroll
    for (int c = 0; c < DKH; ++c) q[c] = b2f(Q[cb + (size_t)c * HW]);

    float corr[25];
    {
        int j = 0;
        #pragma unroll
        for (int dy = -2; dy <= 2; ++dy) {
            #pragma unroll
            for (int dx = -2; dx <= 2; ++dx) {
                float s = 0.f;
                int y2 = yy + dy, x2 = xx + dx;
                if (y2 >= 0 && y2 < HH && x2 >= 0 && x2 < WW) {
                    const bf16* kp = K + cb + (dy * WW + dx);
                    #pragma unroll
                    for (int c = 0; c < DKH; ++c) s += q[c] * b2f(kp[(size_t)c * HW]);
                }
                corr[j++] = s;
            }
        }
    }

    float m = corr[0];
    #pragma unroll
    for (int j = 1; j < 25; ++j) m = fmaxf(m, corr[j]);
    const float sc = 0.17677669529663689f;            // 1/sqrt(32)
    float sum = 0.f;
    #pragma unroll
    for (int j = 0; j < 25; ++j) {
        float e = __expf((corr[j] - m) * sc);
        corr[j] = e;
        sum += e;
    }
    const float inv = 1.f / sum;

    float o[DKH];
    #pragma unroll
    for (int c = 0; c < DKH; ++c) o[c] = 0.f;
    {
        int j = 0;
        #pragma unroll
        for (int dy = -2; dy <= 2; ++dy) {
            #pragma unroll
            for (int dx = -2; dx <= 2; ++dx) {
                int y2 = yy + dy, x2 = xx + dx;
                if (y2 >= 0 && y2 < HH && x2 >= 0 && x2 < WW) {
                    float a = corr[j];
                    const bf16* vp = V + cb + (dy * WW + dx);
                    #pragma unroll
                    for (int c = 0; c < DKH; ++c) o[c] += a * b2f(vp[(size_t)c * HW]);
                }
                ++j;
            }
        }
    }
    #pragma unroll
    for (int c = 0; c < DKH; ++c) T[cb + (size_t)c * HW] = f2b(o[c] * inv);
}

// ---------------------------------------------------------------------------
// LayerNorm over channels (biased var, eps 1e-6). S f32, gamma/beta f32.
// RESID_AFTER: out = LN(S) + resid (bf16 resid; FFN). OUTF32: final f32 out.
// out never aliases resid or S in any call (see liveness map below).
// ---------------------------------------------------------------------------
template<bool RESID_AFTER, bool OUTF32>
__global__ __launch_bounds__(256)
void ln_ch(const float* __restrict__ S, const float* __restrict__ gamma,
           const float* __restrict__ beta, const bf16* __restrict__ resid,
           void* __restrict__ outv)
{
    __shared__ float xl[CH][68];
    __shared__ float red[8][64];
    const int t = threadIdx.x;
    const int pb  = blockIdx.x * 64;
    const int b   = pb / HW;
    const int hw0 = pb % HW;
    const float* sb = S + (size_t)b * CH * HW + hw0;

    #pragma unroll
    for (int i = 0; i < 8; ++i) {
        int vi = t + 256 * i;
        int c  = vi >> 4;
        int p4 = (vi & 15) * 4;
        *reinterpret_cast<float4*>(&xl[c][p4]) =
            *reinterpret_cast<const float4*>(sb + (size_t)c * HW + p4);
    }
    __syncthreads();

    const int p = t & 63, part = t >> 6;
    float s = 0.f, s2 = 0.f;
    #pragma unroll
    for (int i = 0; i < 32; ++i) {
        float v = xl[part * 32 + i][p];
        s += v; s2 += v * v;
    }
    red[part][p] = s;
    red[4 + part][p] = s2;
    __syncthreads();
    const float st  = red[0][p] + red[1][p] + red[2][p] + red[3][p];
    const float st2 = red[4][p] + red[5][p] + red[6][p] + red[7][p];
    const float mu   = st * (1.f / 128.f);
    const float var  = st2 * (1.f / 128.f) - mu * mu;
    const float rstd = rsqrtf(var + 1e-6f);

    const size_t ob = (size_t)b * CH * HW + hw0 + p;
    #pragma unroll
    for (int i = 0; i < 32; ++i) {
        const int c = part * 32 + i;
        float v = (xl[c][p] - mu) * rstd * gamma[c] + beta[c];
        if (RESID_AFTER) v += b2f(resid[ob + (size_t)c * HW]);
        if (OUTF32) ((float*)outv)[ob + (size_t)c * HW] = v;
        else        ((bf16*)outv)[ob + (size_t)c * HW]  = f2b(v);
    }
}

// ---------------------------------------------------------------------------
// Memory plan. Stage quarter = NPIX*CH bf16 = 9,437,184 B (BUFB).
// ws (37.75 MB): W0,W1 = K,V (Sf f32 overlays W0+W1 after attn);
//                W2 = X1 -> later Y2; W3 = Y1.
// d_out (f32, 37.75 MB = 4 quarters D0..D3): D0 = Q/T scratch + FFN1 hidden,
//   D2 = X2 -> FFN2 hidden. out1 f32 = D0+D1 bytes, out2 f32 = D2+D3 bytes —
//   written only by the final ffn LNs, after D0/D2 bf16 contents are dead
//   (stream-ordered; no kernel writes f32 over bytes another pending kernel
//   still reads). All regions written before read in every call.
// ---------------------------------------------------------------------------
extern "C" void kernel_launch(void* const* d_in, const int* in_sizes, int n_in,
                              void* d_out, int out_size, void* d_ws, size_t ws_size,
                              hipStream_t stream)
{
    (void)in_sizes; (void)n_in; (void)out_size; (void)ws_size;
    const float* in1  = (const float*)d_in[0];
    const float* in2  = (const float*)d_in[1];
    const float* wq_s = (const float*)d_in[2];
    const float* wk_s = (const float*)d_in[3];
    const float* wv_s = (const float*)d_in[4];
    const float* fc_s = (const float*)d_in[5];
    const float* lnw_s= (const float*)d_in[6];
    const float* lnb_s= (const float*)d_in[7];
    const float* wq_c = (const float*)d_in[8];
    const float* wk_c = (const float*)d_in[9];
    const float* wv_c = (const float*)d_in[10];
    const float* fc_c = (const float*)d_in[11];
    const float* lnw_c= (const float*)d_in[12];
    const float* lnb_c= (const float*)d_in[13];
    const float* w1   = (const float*)d_in[14];
    const float* b1   = (const float*)d_in[15];
    const float* w2   = (const float*)d_in[16];
    const float* b2   = (const float*)d_in[17];
    const float* lnw_f= (const float*)d_in[18];
    const float* lnb_f= (const float*)d_in[19];

    const size_t BUF  = (size_t)NPIX * CH;     // elements per stage tensor
    const size_t BUFB = BUF * 2;               // bf16 bytes per stage tensor
    char* ws = (char*)d_ws;
    bf16*  W0 = (bf16*)(ws + 0 * BUFB);        // K
    bf16*  W1 = (bf16*)(ws + 1 * BUFB);        // V
    bf16*  W2 = (bf16*)(ws + 2 * BUFB);        // X1, later Y2
    bf16*  W3 = (bf16*)(ws + 3 * BUFB);        // Y1
    float* Sf = (float*)ws;                    // f32 pre-LN, spans W0+W1

    bf16*  D0   = (bf16*)d_out;                            // Q/T, FFN1 hidden
    bf16*  D2   = (bf16*)((char*)d_out + 2 * BUFB);        // X2, FFN2 hidden
    float* out1 = (float*)d_out;
    float* out2 = (float*)d_out + BUF;

    const dim3 cg(NPIX / 64), cb(256);
    const dim3 ag(NPIX / 256, 4);

    // ---- slf1: mha(in1,in1) -> X1 = W2
    conv1x1<true,false,false,false,false,false><<<cg, cb, 0, stream>>>(in1, wq_s, nullptr, nullptr, D0);
    conv1x1<true,false,false,false,false,false><<<cg, cb, 0, stream>>>(in1, wk_s, nullptr, nullptr, W0);
    conv1x1<true,false,false,false,false,false><<<cg, cb, 0, stream>>>(in1, wv_s, nullptr, nullptr, W1);
    attn5<<<ag, cb, 0, stream>>>(D0, W0, W1, D0);
    conv1x1<false,true,false,false,true,true><<<cg, cb, 0, stream>>>(D0, fc_s, nullptr, in1, Sf);
    ln_ch<false,false><<<cg, cb, 0, stream>>>(Sf, lnw_s, lnb_s, nullptr, W2);

    // ---- slf2: mha(in2,in2) -> X2 = D2
    conv1x1<true,false,false,false,false,false><<<cg, cb, 0, stream>>>(in2, wq_s, nullptr, nullptr, D0);
    conv1x1<true,false,false,false,false,false><<<cg, cb, 0, stream>>>(in2, wk_s, nullptr, nullptr, W0);
    conv1x1<true,false,false,false,false,false><<<cg, cb, 0, stream>>>(in2, wv_s, nullptr, nullptr, W1);
    attn5<<<ag, cb, 0, stream>>>(D0, W0, W1, D0);
    conv1x1<false,true,false,false,true,true><<<cg, cb, 0, stream>>>(D0, fc_s, nullptr, in2, Sf);
    ln_ch<false,false><<<cg, cb, 0, stream>>>(Sf, lnw_s, lnb_s, nullptr, D2);

    // ---- crs1: mha(q=X1, kv=X2) -> Y1 = W3
    conv1x1<false,false,false,false,false,false><<<cg, cb, 0, stream>>>(W2, wq_c, nullptr, nullptr, D0);
    conv1x1<false,false,false,false,false,false><<<cg, cb, 0, stream>>>(D2, wk_c, nullptr, nullptr, W0);
    conv1x1<false,false,false,false,false,false><<<cg, cb, 0, stream>>>(D2, wv_c, nullptr, nullptr, W1);
    attn5<<<ag, cb, 0, stream>>>(D0, W0, W1, D0);
    conv1x1<false,false,false,false,true,true><<<cg, cb, 0, stream>>>(D0, fc_c, nullptr, W2, Sf);
    ln_ch<false,false><<<cg, cb, 0, stream>>>(Sf, lnw_c, lnb_c, nullptr, W3);

    // ---- crs2: mha(q=X2, kv=X1) -> Y2 = W2 (X1 dead after V conv)
    conv1x1<false,false,false,false,false,false><<<cg, cb, 0, stream>>>(D2, wq_c, nullptr, nullptr, D0);
    conv1x1<false,false,false,false,false,false><<<cg, cb, 0, stream>>>(W2, wk_c, nullptr, nullptr, W0);
    conv1x1<false,false,false,false,false,false><<<cg, cb, 0, stream>>>(W2, wv_c, nullptr, nullptr, W1);
    attn5<<<ag, cb, 0, stream>>>(D0, W0, W1, D0);
    conv1x1<false,false,false,false,true,true><<<cg, cb, 0, stream>>>(D0, fc_c, nullptr, D2, Sf);
    ln_ch<false,false><<<cg, cb, 0, stream>>>(Sf, lnw_c, lnb_c, nullptr, W2);

    // ---- ffn1: Y1=W3 -> out1 (f32, D0+D1 bytes; D0 hidden dead by then)
    conv1x1<false,false,true,true,false,false><<<cg, cb, 0, stream>>>(W3, w1, b1, nullptr, D0);
    conv1x1<false,false,true,false,false,true><<<cg, cb, 0, stream>>>(D0, w2, b2, nullptr, Sf);
    ln_ch<true,true><<<cg, cb, 0, stream>>>(Sf, lnw_f, lnb_f, W3, out1);

    // ---- ffn2: Y2=W2 -> out2 (f32, D2+D3 bytes; D2 hidden dead by then)
    conv1x1<false,false,true,true,false,false><<<cg, cb, 0, stream>>>(W2, w1, b1, nullptr, D2);
    conv1x1<false,false,true,false,false,true><<<cg, cb, 0, stream>>>(D2, w2, b2, nullptr, Sf);
    ln_ch<true,true><<<cg, cb, 0, stream>>>(Sf, lnw_f, lnb_f, W2, out2);
}

// Round 4
// 319.747 us; speedup vs baseline: 2.4512x; 2.4512x over previous
//
#include <hip/hip_runtime.h>
#include <hip/hip_bf16.h>

typedef __hip_bfloat16 bf16;
typedef __attribute__((ext_vector_type(8))) short short8v;   // 8 bf16 (4 VGPR)
typedef __attribute__((ext_vector_type(4))) float f32x4;     // MFMA acc
#define DI __device__ __forceinline__

constexpr int CH = 128;
constexpr int HH = 96, WW = 96;
constexpr int HW = HH * WW;          // 9216
constexpr int NB = 4;
constexpr int NPIX = NB * HW;        // 36864
constexpr int LDT = 136;             // LDS row stride (bf16): pad 128->136 keeps 16B align, breaks bank aliasing
constexpr int LDQ = 384;             // QKV row stride (elements)

struct __attribute__((aligned(16))) bf16x8 { bf16 h[8]; };

DI float b2f(bf16 x) { return __bfloat162float(x); }
DI bf16  f2b(float x) { return __float2bfloat16(x); }

// ---- GEMM building blocks -------------------------------------------------
// Tile: 64 px x 128 out, K=128. 4 waves; wave w = px [16w,16w+16) x all 128 o.
// A[16px][32c] lane: row=l&15 (px), k=(l>>4)*8+i  -> contiguous bf16x8 in x row
// B[32c][16o]  lane: col=l&15 (o),  k=(l>>4)*8+i  -> contiguous bf16x8 in W row
// D lane: col(o)=l&15, row(px)=(l>>4)*4+reg   [m89-verified]

DI void stage_x(const bf16* __restrict__ src, int ldx, bf16* xl, int t) {
    // 64 rows x 128 cols bf16 = 1024 chunks of 8
    #pragma unroll
    for (int i = 0; i < 4; ++i) {
        int id = t + 256 * i, px = id >> 4, cc = (id & 15) * 8;
        *reinterpret_cast<short8v*>(&xl[px * LDT + cc]) =
            *reinterpret_cast<const short8v*>(&src[(size_t)px * ldx + cc]);
    }
}

DI void stage_w(const float* __restrict__ w, bf16* wl, int t) {
    // 128x128 f32 -> bf16, 2048 chunks of 8
    #pragma unroll
    for (int i = 0; i < 8; ++i) {
        int id = t + 256 * i, o = id >> 4, cc = (id & 15) * 8;
        float4 a = *reinterpret_cast<const float4*>(&w[o * CH + cc]);
        float4 b = *reinterpret_cast<const float4*>(&w[o * CH + cc + 4]);
        bf16x8 tmp;
        tmp.h[0] = f2b(a.x); tmp.h[1] = f2b(a.y); tmp.h[2] = f2b(a.z); tmp.h[3] = f2b(a.w);
        tmp.h[4] = f2b(b.x); tmp.h[5] = f2b(b.y); tmp.h[6] = f2b(b.z); tmp.h[7] = f2b(b.w);
        *reinterpret_cast<short8v*>(&wl[o * LDT + cc]) = *reinterpret_cast<const short8v*>(&tmp);
    }
}

DI void gemm64(const bf16* xl, const bf16* wl, int w, int l, f32x4* acc) {
    const int s = l & 15, g = l >> 4;
    #pragma unroll
    for (int ks = 0; ks < 4; ++ks) {
        short8v a = *reinterpret_cast<const short8v*>(&xl[(16 * w + s) * LDT + ks * 32 + g * 8]);
        #pragma unroll
        for (int n = 0; n < 8; ++n) {
            short8v b = *reinterpret_cast<const short8v*>(&wl[(16 * n + s) * LDT + ks * 32 + g * 8]);
            acc[n] = __builtin_amdgcn_mfma_f32_16x16x32_bf16(a, b, acc[n], 0, 0, 0);
        }
    }
}

// ---- planar f32 -> channel-last bf16 --------------------------------------
__global__ __launch_bounds__(256)
void transpose_in(const float* __restrict__ in, bf16* __restrict__ out) {
    __shared__ float xl[CH * 65];
    const int t = threadIdx.x, p0 = blockIdx.x * 64, b = p0 / HW, hw0 = p0 % HW;
    #pragma unroll
    for (int i = 0; i < 8; ++i) {
        int id = t + 256 * i, c = id >> 4, p4 = (id & 15) * 4;
        *reinterpret_cast<float4*>(&xl[c * 65 + p4]) =
            *reinterpret_cast<const float4*>(&in[(size_t)b * CH * HW + (size_t)c * HW + hw0 + p4]);
    }
    __syncthreads();
    #pragma unroll
    for (int i = 0; i < 4; ++i) {
        int id = t + 256 * i, px = id >> 4, c8 = (id & 15) * 8;
        bf16x8 o8;
        #pragma unroll
        for (int j = 0; j < 8; ++j) o8.h[j] = f2b(xl[(c8 + j) * 65 + px]);
        *reinterpret_cast<bf16x8*>(&out[(size_t)(p0 + px) * CH + c8]) = o8;
    }
}

// ---- QKV projection(s): 1..3 matrices from one x --------------------------
template<int NMAT>
__global__ __launch_bounds__(256, 2)
void conv_qkv(const bf16* __restrict__ x, int ldx,
              const float* __restrict__ w0, const float* __restrict__ w1_,
              const float* __restrict__ w2_, bf16* __restrict__ out, int obase) {
    __shared__ bf16 xl[64 * LDT];
    __shared__ bf16 wl[CH * LDT];
    const int t = threadIdx.x, p0 = blockIdx.x * 64;
    stage_x(x + (size_t)p0 * ldx, ldx, xl, t);
    const int w = t >> 6, l = t & 63, s = l & 15, g = l >> 4;
    #pragma unroll
    for (int m = 0; m < NMAT; ++m) {
        const float* wm = (m == 0) ? w0 : ((m == 1) ? w1_ : w2_);
        __syncthreads();                 // prev-mat MFMAs done (and xl staged, 1st iter)
        stage_w(wm, wl, t);
        __syncthreads();
        f32x4 acc[8];
        #pragma unroll
        for (int n = 0; n < 8; ++n) acc[n] = {0.f, 0.f, 0.f, 0.f};
        gemm64(xl, wl, w, l, acc);
        #pragma unroll
        for (int n = 0; n < 8; ++n) {
            #pragma unroll
            for (int j = 0; j < 4; ++j) {
                int px = 16 * w + 4 * g + j, o = 16 * n + s;
                out[(size_t)(p0 + px) * LDQ + obase + 128 * m + o] = f2b(acc[n][j]);
            }
        }
    }
}

// ---- 5x5 local attention, channel-last, in-place T over Q region ----------
// Each thread owns (pixel p, head n): reads only ITS Q slice before writing T
// over the same bytes -> in-place safe. OOB shifts keep logit exactly 0.
__global__ __launch_bounds__(256)
void attn5(bf16* qkv) {
    const int gid = blockIdx.x * 256 + threadIdx.x;
    const int p = gid >> 2, n = gid & 3;
    const int hw = p % HW, yy = hw / WW, xx = hw % WW;
    bf16* qp = qkv + (size_t)p * LDQ + n * 32;

    float q[32];
    #pragma unroll
    for (int i = 0; i < 4; ++i) {
        bf16x8 v = *reinterpret_cast<const bf16x8*>(qp + 8 * i);
        #pragma unroll
        for (int e = 0; e < 8; ++e) q[8 * i + e] = b2f(v.h[e]);
    }

    float corr[25];
    {
        int j = 0;
        #pragma unroll
        for (int dy = -2; dy <= 2; ++dy) {
            #pragma unroll
            for (int dx = -2; dx <= 2; ++dx) {
                float s = 0.f;
                int y2 = yy + dy, x2 = xx + dx;
                if (y2 >= 0 && y2 < HH && x2 >= 0 && x2 < WW) {
                    const bf16* kp = qkv + (size_t)(p + dy * WW + dx) * LDQ + 128 + n * 32;
                    #pragma unroll
                    for (int i = 0; i < 4; ++i) {
                        bf16x8 v = *reinterpret_cast<const bf16x8*>(kp + 8 * i);
                        #pragma unroll
                        for (int e = 0; e < 8; ++e) s += q[8 * i + e] * b2f(v.h[e]);
                    }
                }
                corr[j++] = s;
            }
        }
    }

    float m = corr[0];
    #pragma unroll
    for (int j = 1; j < 25; ++j) m = fmaxf(m, corr[j]);
    const float sc = 0.17677669529663689f;               // 1/sqrt(32)
    float sum = 0.f;
    #pragma unroll
    for (int j = 0; j < 25; ++j) {
        float e = __expf((corr[j] - m) * sc);
        corr[j] = e; sum += e;
    }
    const float inv = 1.f / sum;

    float o[32];
    #pragma unroll
    for (int i = 0; i < 32; ++i) o[i] = 0.f;
    {
        int j = 0;
        #pragma unroll
        for (int dy = -2; dy <= 2; ++dy) {
            #pragma unroll
            for (int dx = -2; dx <= 2; ++dx) {
                int y2 = yy + dy, x2 = xx + dx;
                if (y2 >= 0 && y2 < HH && x2 >= 0 && x2 < WW) {
                    float a = corr[j];
                    const bf16* vp = qkv + (size_t)(p + dy * WW + dx) * LDQ + 256 + n * 32;
                    #pragma unroll
                    for (int i = 0; i < 4; ++i) {
                        bf16x8 v = *reinterpret_cast<const bf16x8*>(vp + 8 * i);
                        #pragma unroll
                        for (int e = 0; e < 8; ++e) o[8 * i + e] += a * b2f(v.h[e]);
                    }
                }
                ++j;
            }
        }
    }
    #pragma unroll
    for (int i = 0; i < 4; ++i) {
        bf16x8 st;
        #pragma unroll
        for (int e = 0; e < 8; ++e) st.h[e] = f2b(o[8 * i + e] * inv);
        *reinterpret_cast<bf16x8*>(qp + 8 * i) = st;
    }
}

// ---- fc conv + resid(pre-LN) + LayerNorm -> bf16 channel-last -------------
// LN over channels is in-wave: lanes sharing (l>>4) hold all 128 o's of the
// same 4 pixels -> shfl_xor{1,2,4,8} reduction, no LDS, no extra sync.
template<bool RPLANAR>
__global__ __launch_bounds__(256, 2)
void conv_fc_ln(const bf16* __restrict__ tin, const float* __restrict__ wfc,
                const void* __restrict__ residv, const float* __restrict__ gamma,
                const float* __restrict__ beta, bf16* __restrict__ out) {
    __shared__ bf16 xl[64 * LDT];
    __shared__ bf16 wl[CH * LDT];
    const int t = threadIdx.x, p0 = blockIdx.x * 64;
    stage_x(tin + (size_t)p0 * LDQ, LDQ, xl, t);
    stage_w(wfc, wl, t);
    __syncthreads();
    const int w = t >> 6, l = t & 63, s = l & 15, g = l >> 4;
    f32x4 acc[8];
    #pragma unroll
    for (int n = 0; n < 8; ++n) acc[n] = {0.f, 0.f, 0.f, 0.f};
    gemm64(xl, wl, w, l, acc);

    const int b = p0 / HW, hw0 = p0 % HW;
    float r[8][4];
    #pragma unroll
    for (int n = 0; n < 8; ++n) {
        const int o = 16 * n + s;
        #pragma unroll
        for (int j = 0; j < 4; ++j) {
            const int px = 16 * w + 4 * g + j;
            float rv;
            if (RPLANAR)
                rv = ((const float*)residv)[(size_t)b * CH * HW + (size_t)o * HW + hw0 + px];
            else
                rv = b2f(((const bf16*)residv)[(size_t)(p0 + px) * CH + o]);
            r[n][j] = acc[n][j] + rv;
        }
    }
    float gm[8], bt[8];
    #pragma unroll
    for (int n = 0; n < 8; ++n) { gm[n] = gamma[16 * n + s]; bt[n] = beta[16 * n + s]; }
    #pragma unroll
    for (int j = 0; j < 4; ++j) {
        float sm = 0.f, sq = 0.f;
        #pragma unroll
        for (int n = 0; n < 8; ++n) { float v = r[n][j]; sm += v; sq += v * v; }
        sm += __shfl_xor(sm, 1); sq += __shfl_xor(sq, 1);
        sm += __shfl_xor(sm, 2); sq += __shfl_xor(sq, 2);
        sm += __shfl_xor(sm, 4); sq += __shfl_xor(sq, 4);
        sm += __shfl_xor(sm, 8); sq += __shfl_xor(sq, 8);
        const float mu = sm * (1.f / 128.f);
        const float var = sq * (1.f / 128.f) - mu * mu;
        const float rs = rsqrtf(var + 1e-6f);
        const int px = 16 * w + 4 * g + j;
        #pragma unroll
        for (int n = 0; n < 8; ++n) {
            const int o = 16 * n + s;
            out[(size_t)(p0 + px) * CH + o] = f2b(gm[n] * (r[n][j] - mu) * rs + bt[n]);
        }
    }
}

// ---- FFN conv1: bias + ReLU -> bf16 channel-last --------------------------
__global__ __launch_bounds__(256, 2)
void conv_relu(const bf16* __restrict__ x, const float* __restrict__ wm,
               const float* __restrict__ bias, bf16* __restrict__ out) {
    __shared__ bf16 xl[64 * LDT];
    __shared__ bf16 wl[CH * LDT];
    const int t = threadIdx.x, p0 = blockIdx.x * 64;
    stage_x(x + (size_t)p0 * CH, CH, xl, t);
    stage_w(wm, wl, t);
    __syncthreads();
    const int w = t >> 6, l = t & 63, s = l & 15, g = l >> 4;
    f32x4 acc[8];
    #pragma unroll
    for (int n = 0; n < 8; ++n) acc[n] = {0.f, 0.f, 0.f, 0.f};
    gemm64(xl, wl, w, l, acc);
    float bv[8];
    #pragma unroll
    for (int n = 0; n < 8; ++n) bv[n] = bias[16 * n + s];
    #pragma unroll
    for (int n = 0; n < 8; ++n) {
        const int o = 16 * n + s;
        #pragma unroll
        for (int j = 0; j < 4; ++j) {
            const int px = 16 * w + 4 * g + j;
            out[(size_t)(p0 + px) * CH + o] = f2b(fmaxf(acc[n][j] + bv[n], 0.f));
        }
    }
}

// ---- FFN conv2: bias + LN + resid(post-LN) -> PLANAR f32 output -----------
// Planar store via padded-LDS transpose bounce (aliases xl/wl after a sync).
__global__ __launch_bounds__(256, 2)
void conv_ln_out(const bf16* __restrict__ h, const float* __restrict__ wm,
                 const float* __restrict__ bias, const float* __restrict__ gamma,
                 const float* __restrict__ beta, const bf16* __restrict__ resid,
                 float* __restrict__ outp) {
    __shared__ __align__(16) char smem[64 * LDT * 2 + CH * LDT * 2];  // 52224 B
    bf16*  xl = (bf16*)smem;
    bf16*  wl = (bf16*)(smem + 64 * LDT * 2);
    float* ll = (float*)smem;                                          // 128*65*4 = 33280 B, aliased after sync
    const int t = threadIdx.x, p0 = blockIdx.x * 64;
    stage_x(h + (size_t)p0 * CH, CH, xl, t);
    stage_w(wm, wl, t);
    __syncthreads();
    const int w = t >> 6, l = t & 63, s = l & 15, g = l >> 4;
    f32x4 acc[8];
    #pragma unroll
    for (int n = 0; n < 8; ++n) acc[n] = {0.f, 0.f, 0.f, 0.f};
    gemm64(xl, wl, w, l, acc);

    float bv[8], gm[8], bt[8];
    #pragma unroll
    for (int n = 0; n < 8; ++n) {
        bv[n] = bias[16 * n + s]; gm[n] = gamma[16 * n + s]; bt[n] = beta[16 * n + s];
    }
    float r[8][4];
    #pragma unroll
    for (int n = 0; n < 8; ++n)
        #pragma unroll
        for (int j = 0; j < 4; ++j) r[n][j] = acc[n][j] + bv[n];

    float val[8][4];
    #pragma unroll
    for (int j = 0; j < 4; ++j) {
        float sm = 0.f, sq = 0.f;
        #pragma unroll
        for (int n = 0; n < 8; ++n) { float v = r[n][j]; sm += v; sq += v * v; }
        sm += __shfl_xor(sm, 1); sq += __shfl_xor(sq, 1);
        sm += __shfl_xor(sm, 2); sq += __shfl_xor(sq, 2);
        sm += __shfl_xor(sm, 4); sq += __shfl_xor(sq, 4);
        sm += __shfl_xor(sm, 8); sq += __shfl_xor(sq, 8);
        const float mu = sm * (1.f / 128.f);
        const float var = sq * (1.f / 128.f) - mu * mu;
        const float rs = rsqrtf(var + 1e-6f);
        const int px = 16 * w + 4 * g + j;
        #pragma unroll
        for (int n = 0; n < 8; ++n) {
            const int o = 16 * n + s;
            val[n][j] = gm[n] * (r[n][j] - mu) * rs + bt[n]
                      + b2f(resid[(size_t)(p0 + px) * CH + o]);
        }
    }
    __syncthreads();                                  // xl/wl dead for all waves
    #pragma unroll
    for (int n = 0; n < 8; ++n) {
        const int o = 16 * n + s;
        #pragma unroll
        for (int j = 0; j < 4; ++j) ll[o * 65 + 16 * w + 4 * g + j] = val[n][j];
    }
    __syncthreads();
    const int b = p0 / HW, hw0 = p0 % HW;
    #pragma unroll
    for (int i = 0; i < 8; ++i) {
        int id = t + 256 * i, c = id >> 4, p4 = (id & 15) * 4;
        float4 v = { ll[c * 65 + p4], ll[c * 65 + p4 + 1],
                     ll[c * 65 + p4 + 2], ll[c * 65 + p4 + 3] };
        *reinterpret_cast<float4*>(&outp[(size_t)b * CH * HW + (size_t)c * HW + hw0 + p4]) = v;
    }
}

// ---------------------------------------------------------------------------
// Liveness plan (quarter = NPIX*128 bf16 = 9,437,184 B):
//   ws:  Q0..Q2 = QKV [p][384] (28.3MB; T aliases Q-slice in-place; later Q0 = FFN hidden H)
//        Q3     = X1 (slf1 out) -> Y2 (crs2 out)
//   d_out quarters: D0 = X0_1 (dead after slf1 qkv), D1 = X0_2 (dead after slf2 qkv),
//        D2 = Y1 (dead after ffn1), D3 = X2 (dead after crs2 fc)
//   out1 f32 = D0+D1 bytes (written by ffn1's conv_ln_out, reads H@Q0 + resid Y1@D2)
//   out2 f32 = D2+D3 bytes (written by ffn2's conv_ln_out, reads H@Q0 + resid Y2@Q3)
// All regions written before read; all reuse stream-ordered. ws use = 37.75 MB
// (identical to the passing round-3 footprint).
// ---------------------------------------------------------------------------
extern "C" void kernel_launch(void* const* d_in, const int* in_sizes, int n_in,
                              void* d_out, int out_size, void* d_ws, size_t ws_size,
                              hipStream_t stream) {
    (void)in_sizes; (void)n_in; (void)out_size; (void)ws_size;
    const float* in1  = (const float*)d_in[0];
    const float* in2  = (const float*)d_in[1];
    const float* wq_s = (const float*)d_in[2];
    const float* wk_s = (const float*)d_in[3];
    const float* wv_s = (const float*)d_in[4];
    const float* fc_s = (const float*)d_in[5];
    const float* lnw_s= (const float*)d_in[6];
    const float* lnb_s= (const float*)d_in[7];
    const float* wq_c = (const float*)d_in[8];
    const float* wk_c = (const float*)d_in[9];
    const float* wv_c = (const float*)d_in[10];
    const float* fc_c = (const float*)d_in[11];
    const float* lnw_c= (const float*)d_in[12];
    const float* lnb_c= (const float*)d_in[13];
    const float* w1   = (const float*)d_in[14];
    const float* b1   = (const float*)d_in[15];
    const float* w2   = (const float*)d_in[16];
    const float* b2   = (const float*)d_in[17];
    const float* lnw_f= (const float*)d_in[18];
    const float* lnb_f= (const float*)d_in[19];

    const size_t BUF  = (size_t)NPIX * CH;
    const size_t BUFB = BUF * 2;
    char* ws = (char*)d_ws;
    bf16* QKV = (bf16*)ws;                       // 3 quarters
    bf16* Q3  = (bf16*)(ws + 3 * BUFB);          // X1 -> Y2
    bf16* Hb  = (bf16*)ws;                       // FFN hidden (QKV dead by then)
    bf16* D0 = (bf16*)d_out;
    bf16* D1 = (bf16*)((char*)d_out + 1 * BUFB);
    bf16* D2 = (bf16*)((char*)d_out + 2 * BUFB);
    bf16* D3 = (bf16*)((char*)d_out + 3 * BUFB);
    float* out1 = (float*)d_out;
    float* out2 = (float*)d_out + BUF;

    const dim3 G(NPIX / 64), B(256);

    transpose_in<<<G, B, 0, stream>>>(in1, D0);
    transpose_in<<<G, B, 0, stream>>>(in2, D1);

    // slf1 -> X1@Q3 (resid = in1 planar f32)
    conv_qkv<3><<<G, B, 0, stream>>>(D0, CH, wq_s, wk_s, wv_s, QKV, 0);
    attn5<<<G, B, 0, stream>>>(QKV);
    conv_fc_ln<true><<<G, B, 0, stream>>>(QKV, fc_s, in1, lnw_s, lnb_s, Q3);

    // slf2 -> X2@D3
    conv_qkv<3><<<G, B, 0, stream>>>(D1, CH, wq_s, wk_s, wv_s, QKV, 0);
    attn5<<<G, B, 0, stream>>>(QKV);
    conv_fc_ln<true><<<G, B, 0, stream>>>(QKV, fc_s, in2, lnw_s, lnb_s, D3);

    // crs1: q=X1@Q3, kv=X2@D3 -> Y1@D2 (resid = X1@Q3, bf16 cl)
    conv_qkv<1><<<G, B, 0, stream>>>(Q3, CH, wq_c, nullptr, nullptr, QKV, 0);
    conv_qkv<2><<<G, B, 0, stream>>>(D3, CH, wk_c, wv_c, nullptr, QKV, 128);
    attn5<<<G, B, 0, stream>>>(QKV);
    conv_fc_ln<false><<<G, B, 0, stream>>>(QKV, fc_c, Q3, lnw_c, lnb_c, D2);

    // crs2: q=X2@D3, kv=X1@Q3 -> Y2@Q3 (X1 dead after kv conv; resid = X2@D3)
    conv_qkv<1><<<G, B, 0, stream>>>(D3, CH, wq_c, nullptr, nullptr, QKV, 0);
    conv_qkv<2><<<G, B, 0, stream>>>(Q3, CH, wk_c, wv_c, nullptr, QKV, 128);
    attn5<<<G, B, 0, stream>>>(QKV);
    conv_fc_ln<false><<<G, B, 0, stream>>>(QKV, fc_c, D3, lnw_c, lnb_c, Q3);

    // ffn1: Y1@D2 -> out1 (@D0+D1)
    conv_relu<<<G, B, 0, stream>>>(D2, w1, b1, Hb);
    conv_ln_out<<<G, B, 0, stream>>>(Hb, w2, b2, lnw_f, lnb_f, D2, out1);

    // ffn2: Y2@Q3 -> out2 (@D2+D3)
    conv_relu<<<G, B, 0, stream>>>(Q3, w1, b1, Hb);
    conv_ln_out<<<G, B, 0, stream>>>(Hb, w2, b2, lnw_f, lnb_f, Q3, out2);
}

// Round 5
// 319.172 us; speedup vs baseline: 2.4556x; 1.0018x over previous
//
#include <hip/hip_runtime.h>
#include <hip/hip_bf16.h>

typedef __hip_bfloat16 bf16;
typedef __attribute__((ext_vector_type(8))) short short8v;   // 8 bf16 (4 VGPR)
typedef __attribute__((ext_vector_type(4))) float f32x4;     // MFMA acc
#define DI __device__ __forceinline__

constexpr int CH = 128;
constexpr int HH = 96, WW = 96;
constexpr int HW = HH * WW;          // 9216
constexpr int NB = 4;
constexpr int NPIX = NB * HW;        // 36864
constexpr int LDT = 136;             // LDS row stride (bf16); %8==0 keeps b128 align; read conflicts 2-way (free)
constexpr int LDQ = 384;             // QKV row stride (elements)

struct __attribute__((aligned(16))) bf16x8 { bf16 h[8]; };

DI float b2f(bf16 x) { return __bfloat162float(x); }
DI bf16  f2b(float x) { return __float2bfloat16(x); }

// ---- GEMM building blocks -------------------------------------------------
// Tile: 64 px x 128 out, K=128. 4 waves; wave w = px [16w,16w+16) x all 128 o.
// A[16px][32c] lane: row=l&15 (px), k=(l>>4)*8+i  -> contiguous bf16x8 in x row
// B[32c][16o]  lane: col=l&15 (o),  k=(l>>4)*8+i  -> contiguous bf16x8 in W row
// D lane: col(o)=l&15, row(px)=(l>>4)*4+reg   [m89-verified]

DI void stage_x_cl(const bf16* __restrict__ src, int ldx, bf16* xl, int t) {
    #pragma unroll
    for (int i = 0; i < 4; ++i) {
        int id = t + 256 * i, px = id >> 4, cc = (id & 15) * 8;
        *reinterpret_cast<short8v*>(&xl[px * LDT + cc]) =
            *reinterpret_cast<const short8v*>(&src[(size_t)px * ldx + cc]);
    }
}

// planar f32 [c][HW] -> LDS tile [px][c] bf16 (transposing scatter; once/block)
DI void stage_x_pl(const float* __restrict__ src, bf16* xl, int t) {
    #pragma unroll
    for (int i = 0; i < 8; ++i) {
        int id = t + 256 * i, c = id >> 4, p4 = (id & 15) * 4;
        float4 v = *reinterpret_cast<const float4*>(&src[(size_t)c * HW + p4]);
        xl[(p4 + 0) * LDT + c] = f2b(v.x);
        xl[(p4 + 1) * LDT + c] = f2b(v.y);
        xl[(p4 + 2) * LDT + c] = f2b(v.z);
        xl[(p4 + 3) * LDT + c] = f2b(v.w);
    }
}

DI void stage_w(const float* __restrict__ w, bf16* wl, int t) {
    #pragma unroll
    for (int i = 0; i < 8; ++i) {
        int id = t + 256 * i, o = id >> 4, cc = (id & 15) * 8;
        float4 a = *reinterpret_cast<const float4*>(&w[o * CH + cc]);
        float4 b = *reinterpret_cast<const float4*>(&w[o * CH + cc + 4]);
        bf16x8 tmp;
        tmp.h[0] = f2b(a.x); tmp.h[1] = f2b(a.y); tmp.h[2] = f2b(a.z); tmp.h[3] = f2b(a.w);
        tmp.h[4] = f2b(b.x); tmp.h[5] = f2b(b.y); tmp.h[6] = f2b(b.z); tmp.h[7] = f2b(b.w);
        *reinterpret_cast<short8v*>(&wl[o * LDT + cc]) = *reinterpret_cast<const short8v*>(&tmp);
    }
}

DI void gemm64(const bf16* xl, const bf16* wl, int w, int l, f32x4* acc) {
    const int s = l & 15, g = l >> 4;
    #pragma unroll
    for (int ks = 0; ks < 4; ++ks) {
        short8v a = *reinterpret_cast<const short8v*>(&xl[(16 * w + s) * LDT + ks * 32 + g * 8]);
        #pragma unroll
        for (int n = 0; n < 8; ++n) {
            short8v b = *reinterpret_cast<const short8v*>(&wl[(16 * n + s) * LDT + ks * 32 + g * 8]);
            acc[n] = __builtin_amdgcn_mfma_f32_16x16x32_bf16(a, b, acc[n], 0, 0, 0);
        }
    }
}

DI void qkv_epilogue(const f32x4* acc, bf16* __restrict__ out, int p0,
                     int obase, int w, int l) {
    const int s = l & 15, g = l >> 4;
    #pragma unroll
    for (int n = 0; n < 8; ++n) {
        #pragma unroll
        for (int j = 0; j < 4; ++j) {
            int px = 16 * w + 4 * g + j, o = 16 * n + s;
            out[(size_t)(p0 + px) * LDQ + obase + o] = f2b(acc[n][j]);
        }
    }
}

// ---- QKV projection: 3 matrices from one x (self-attn; planar f32 x) ------
template<bool XPLANAR>
__global__ __launch_bounds__(256, 2)
void conv_qkv(const void* __restrict__ xv,
              const float* __restrict__ w0, const float* __restrict__ w1_,
              const float* __restrict__ w2_, bf16* __restrict__ out) {
    __shared__ bf16 xl[64 * LDT];
    __shared__ bf16 wl[CH * LDT];
    const int t = threadIdx.x, p0 = blockIdx.x * 64;
    if (XPLANAR) {
        const int b = p0 / HW, hw0 = p0 % HW;
        stage_x_pl((const float*)xv + (size_t)b * CH * HW + hw0, xl, t);
    } else {
        stage_x_cl((const bf16*)xv + (size_t)p0 * CH, CH, xl, t);
    }
    const int w = t >> 6, l = t & 63;
    #pragma unroll
    for (int m = 0; m < 3; ++m) {
        const float* wm = (m == 0) ? w0 : ((m == 1) ? w1_ : w2_);
        __syncthreads();                 // prev-mat MFMAs done (xl staged, 1st iter)
        stage_w(wm, wl, t);
        __syncthreads();
        f32x4 acc[8];
        #pragma unroll
        for (int n = 0; n < 8; ++n) acc[n] = {0.f, 0.f, 0.f, 0.f};
        gemm64(xl, wl, w, l, acc);
        qkv_epilogue(acc, out, p0, 128 * m, w, l);
    }
}

// ---- cross-attn QKV: Q from xq, K+V from xkv, one dispatch ---------------
__global__ __launch_bounds__(256, 2)
void conv_qkv_cross(const bf16* __restrict__ xq, const bf16* __restrict__ xkv,
                    const float* __restrict__ wq, const float* __restrict__ wk,
                    const float* __restrict__ wv, bf16* __restrict__ out) {
    __shared__ bf16 xl[64 * LDT];
    __shared__ bf16 wl[CH * LDT];
    const int t = threadIdx.x, p0 = blockIdx.x * 64;
    const int w = t >> 6, l = t & 63;

    stage_x_cl(xq + (size_t)p0 * CH, CH, xl, t);
    stage_w(wq, wl, t);
    __syncthreads();
    {
        f32x4 acc[8];
        #pragma unroll
        for (int n = 0; n < 8; ++n) acc[n] = {0.f, 0.f, 0.f, 0.f};
        gemm64(xl, wl, w, l, acc);
        qkv_epilogue(acc, out, p0, 0, w, l);
    }
    __syncthreads();                       // xl/wl free
    stage_x_cl(xkv + (size_t)p0 * CH, CH, xl, t);
    stage_w(wk, wl, t);
    __syncthreads();
    {
        f32x4 acc[8];
        #pragma unroll
        for (int n = 0; n < 8; ++n) acc[n] = {0.f, 0.f, 0.f, 0.f};
        gemm64(xl, wl, w, l, acc);
        qkv_epilogue(acc, out, p0, 128, w, l);
    }
    __syncthreads();                       // wl free (xl reused for V)
    stage_w(wv, wl, t);
    __syncthreads();
    {
        f32x4 acc[8];
        #pragma unroll
        for (int n = 0; n < 8; ++n) acc[n] = {0.f, 0.f, 0.f, 0.f};
        gemm64(xl, wl, w, l, acc);
        qkv_epilogue(acc, out, p0, 256, w, l);
    }
}

// ---- 5x5 local attention, channel-last, in-place T over Q region ----------
// 4 threads per (pixel, head), 8 channels each. Lanes 4k..4k+3 share one
// (p,n): uniform bounds -> no divergence; QK partials summed via shfl_xor.
// Each thread reads only ITS Q slice before writing T over the same bytes.
// OOB shifts keep logit exactly 0 (all partials 0).
__global__ __launch_bounds__(256)
void attn5(bf16* qkv) {
    const int gid = blockIdx.x * 256 + threadIdx.x;
    const int qtr = gid & 3;               // channel quarter within head
    const int n   = (gid >> 2) & 3;        // head
    const int p   = gid >> 4;              // pixel
    const int hw = p % HW, yy = hw / WW, xx = hw % WW;
    bf16* qp = qkv + (size_t)p * LDQ + n * 32 + qtr * 8;

    float q[8];
    {
        bf16x8 v = *reinterpret_cast<const bf16x8*>(qp);
        #pragma unroll
        for (int e = 0; e < 8; ++e) q[e] = b2f(v.h[e]);
    }

    float corr[25];
    {
        int j = 0;
        #pragma unroll
        for (int dy = -2; dy <= 2; ++dy) {
            #pragma unroll
            for (int dx = -2; dx <= 2; ++dx) {
                float s = 0.f;
                int y2 = yy + dy, x2 = xx + dx;
                if (y2 >= 0 && y2 < HH && x2 >= 0 && x2 < WW) {
                    const bf16* kp = qkv + (size_t)(p + dy * WW + dx) * LDQ + 128 + n * 32 + qtr * 8;
                    bf16x8 v = *reinterpret_cast<const bf16x8*>(kp);
                    #pragma unroll
                    for (int e = 0; e < 8; ++e) s += q[e] * b2f(v.h[e]);
                }
                s += __shfl_xor(s, 1);
                s += __shfl_xor(s, 2);
                corr[j++] = s;
            }
        }
    }

    float m = corr[0];
    #pragma unroll
    for (int j = 1; j < 25; ++j) m = fmaxf(m, corr[j]);
    const float sc = 0.17677669529663689f;               // 1/sqrt(32)
    float sum = 0.f;
    #pragma unroll
    for (int j = 0; j < 25; ++j) {
        float e = __expf((corr[j] - m) * sc);
        corr[j] = e; sum += e;
    }
    const float inv = 1.f / sum;

    float o[8];
    #pragma unroll
    for (int e = 0; e < 8; ++e) o[e] = 0.f;
    {
        int j = 0;
        #pragma unroll
        for (int dy = -2; dy <= 2; ++dy) {
            #pragma unroll
            for (int dx = -2; dx <= 2; ++dx) {
                int y2 = yy + dy, x2 = xx + dx;
                if (y2 >= 0 && y2 < HH && x2 >= 0 && x2 < WW) {
                    float a = corr[j];
                    const bf16* vp = qkv + (size_t)(p + dy * WW + dx) * LDQ + 256 + n * 32 + qtr * 8;
                    bf16x8 v = *reinterpret_cast<const bf16x8*>(vp);
                    #pragma unroll
                    for (int e = 0; e < 8; ++e) o[e] += a * b2f(v.h[e]);
                }
                ++j;
            }
        }
    }
    bf16x8 st;
    #pragma unroll
    for (int e = 0; e < 8; ++e) st.h[e] = f2b(o[e] * inv);
    *reinterpret_cast<bf16x8*>(qp) = st;
}

// ---- fc conv + resid(pre-LN) + LayerNorm -> bf16 channel-last -------------
template<bool RPLANAR>
__global__ __launch_bounds__(256, 2)
void conv_fc_ln(const bf16* __restrict__ tin, const float* __restrict__ wfc,
                const void* __restrict__ residv, const float* __restrict__ gamma,
                const float* __restrict__ beta, bf16* __restrict__ out) {
    __shared__ bf16 xl[64 * LDT];
    __shared__ bf16 wl[CH * LDT];
    const int t = threadIdx.x, p0 = blockIdx.x * 64;
    stage_x_cl(tin + (size_t)p0 * LDQ, LDQ, xl, t);
    stage_w(wfc, wl, t);
    __syncthreads();
    const int w = t >> 6, l = t & 63, s = l & 15, g = l >> 4;
    f32x4 acc[8];
    #pragma unroll
    for (int n = 0; n < 8; ++n) acc[n] = {0.f, 0.f, 0.f, 0.f};
    gemm64(xl, wl, w, l, acc);

    const int b = p0 / HW, hw0 = p0 % HW;
    float r[8][4];
    #pragma unroll
    for (int n = 0; n < 8; ++n) {
        const int o = 16 * n + s;
        #pragma unroll
        for (int j = 0; j < 4; ++j) {
            const int px = 16 * w + 4 * g + j;
            float rv;
            if (RPLANAR)
                rv = ((const float*)residv)[(size_t)b * CH * HW + (size_t)o * HW + hw0 + px];
            else
                rv = b2f(((const bf16*)residv)[(size_t)(p0 + px) * CH + o]);
            r[n][j] = acc[n][j] + rv;
        }
    }
    float gm[8], bt[8];
    #pragma unroll
    for (int n = 0; n < 8; ++n) { gm[n] = gamma[16 * n + s]; bt[n] = beta[16 * n + s]; }
    #pragma unroll
    for (int j = 0; j < 4; ++j) {
        float sm = 0.f, sq = 0.f;
        #pragma unroll
        for (int n = 0; n < 8; ++n) { float v = r[n][j]; sm += v; sq += v * v; }
        sm += __shfl_xor(sm, 1); sq += __shfl_xor(sq, 1);
        sm += __shfl_xor(sm, 2); sq += __shfl_xor(sq, 2);
        sm += __shfl_xor(sm, 4); sq += __shfl_xor(sq, 4);
        sm += __shfl_xor(sm, 8); sq += __shfl_xor(sq, 8);
        const float mu = sm * (1.f / 128.f);
        const float var = sq * (1.f / 128.f) - mu * mu;
        const float rs = rsqrtf(var + 1e-6f);
        const int px = 16 * w + 4 * g + j;
        #pragma unroll
        for (int n = 0; n < 8; ++n) {
            const int o = 16 * n + s;
            out[(size_t)(p0 + px) * CH + o] = f2b(gm[n] * (r[n][j] - mu) * rs + bt[n]);
        }
    }
}

// ---- FFN conv1: bias + ReLU -> bf16 channel-last --------------------------
__global__ __launch_bounds__(256, 2)
void conv_relu(const bf16* __restrict__ x, const float* __restrict__ wm,
               const float* __restrict__ bias, bf16* __restrict__ out) {
    __shared__ bf16 xl[64 * LDT];
    __shared__ bf16 wl[CH * LDT];
    const int t = threadIdx.x, p0 = blockIdx.x * 64;
    stage_x_cl(x + (size_t)p0 * CH, CH, xl, t);
    stage_w(wm, wl, t);
    __syncthreads();
    const int w = t >> 6, l = t & 63, s = l & 15, g = l >> 4;
    f32x4 acc[8];
    #pragma unroll
    for (int n = 0; n < 8; ++n) acc[n] = {0.f, 0.f, 0.f, 0.f};
    gemm64(xl, wl, w, l, acc);
    float bv[8];
    #pragma unroll
    for (int n = 0; n < 8; ++n) bv[n] = bias[16 * n + s];
    #pragma unroll
    for (int n = 0; n < 8; ++n) {
        const int o = 16 * n + s;
        #pragma unroll
        for (int j = 0; j < 4; ++j) {
            const int px = 16 * w + 4 * g + j;
            out[(size_t)(p0 + px) * CH + o] = f2b(fmaxf(acc[n][j] + bv[n], 0.f));
        }
    }
}

// ---- FFN conv2: bias + LN + resid(post-LN) -> PLANAR f32 output -----------
__global__ __launch_bounds__(256, 2)
void conv_ln_out(const bf16* __restrict__ h, const float* __restrict__ wm,
                 const float* __restrict__ bias, const float* __restrict__ gamma,
                 const float* __restrict__ beta, const bf16* __restrict__ resid,
                 float* __restrict__ outp) {
    __shared__ __align__(16) char smem[64 * LDT * 2 + CH * LDT * 2];  // 52224 B
    bf16*  xl = (bf16*)smem;
    bf16*  wl = (bf16*)(smem + 64 * LDT * 2);
    float* ll = (float*)smem;                       // 128*65*4 = 33280 B, aliased after sync
    const int t = threadIdx.x, p0 = blockIdx.x * 64;
    stage_x_cl(h + (size_t)p0 * CH, CH, xl, t);
    stage_w(wm, wl, t);
    __syncthreads();
    const int w = t >> 6, l = t & 63, s = l & 15, g = l >> 4;
    f32x4 acc[8];
    #pragma unroll
    for (int n = 0; n < 8; ++n) acc[n] = {0.f, 0.f, 0.f, 0.f};
    gemm64(xl, wl, w, l, acc);

    float bv[8], gm[8], bt[8];
    #pragma unroll
    for (int n = 0; n < 8; ++n) {
        bv[n] = bias[16 * n + s]; gm[n] = gamma[16 * n + s]; bt[n] = beta[16 * n + s];
    }
    float r[8][4];
    #pragma unroll
    for (int n = 0; n < 8; ++n)
        #pragma unroll
        for (int j = 0; j < 4; ++j) r[n][j] = acc[n][j] + bv[n];

    float val[8][4];
    #pragma unroll
    for (int j = 0; j < 4; ++j) {
        float sm = 0.f, sq = 0.f;
        #pragma unroll
        for (int n = 0; n < 8; ++n) { float v = r[n][j]; sm += v; sq += v * v; }
        sm += __shfl_xor(sm, 1); sq += __shfl_xor(sq, 1);
        sm += __shfl_xor(sm, 2); sq += __shfl_xor(sq, 2);
        sm += __shfl_xor(sm, 4); sq += __shfl_xor(sq, 4);
        sm += __shfl_xor(sm, 8); sq += __shfl_xor(sq, 8);
        const float mu = sm * (1.f / 128.f);
        const float var = sq * (1.f / 128.f) - mu * mu;
        const float rs = rsqrtf(var + 1e-6f);
        const int px = 16 * w + 4 * g + j;
        #pragma unroll
        for (int n = 0; n < 8; ++n) {
            const int o = 16 * n + s;
            val[n][j] = gm[n] * (r[n][j] - mu) * rs + bt[n]
                      + b2f(resid[(size_t)(p0 + px) * CH + o]);
        }
    }
    __syncthreads();                                  // xl/wl dead for all waves
    #pragma unroll
    for (int n = 0; n < 8; ++n) {
        const int o = 16 * n + s;
        #pragma unroll
        for (int j = 0; j < 4; ++j) ll[o * 65 + 16 * w + 4 * g + j] = val[n][j];
    }
    __syncthreads();
    const int b = p0 / HW, hw0 = p0 % HW;
    #pragma unroll
    for (int i = 0; i < 8; ++i) {
        int id = t + 256 * i, c = id >> 4, p4 = (id & 15) * 4;
        float4 v = { ll[c * 65 + p4], ll[c * 65 + p4 + 1],
                     ll[c * 65 + p4 + 2], ll[c * 65 + p4 + 3] };
        *reinterpret_cast<float4*>(&outp[(size_t)b * CH * HW + (size_t)c * HW + hw0 + p4]) = v;
    }
}

// ---------------------------------------------------------------------------
// Liveness (quarter = NPIX*128 bf16 = 9,437,184 B):
//   ws: Q0..Q2 = QKV [p][384]; after crs2 QKV dead -> Hb (FFN hidden) = Q0.
//       Q3 = X1 (slf1 out) -> Y2 (crs2 out)
//   d_out quarters: D2 = Y1; D3 = X2. out1 f32 = D0+D1 (fresh), out2 = D2+D3
//   (written after D2/D3 bf16 contents are dead). All stream-ordered.
// ---------------------------------------------------------------------------
extern "C" void kernel_launch(void* const* d_in, const int* in_sizes, int n_in,
                              void* d_out, int out_size, void* d_ws, size_t ws_size,
                              hipStream_t stream) {
    (void)in_sizes; (void)n_in; (void)out_size; (void)ws_size;
    const float* in1  = (const float*)d_in[0];
    const float* in2  = (const float*)d_in[1];
    const float* wq_s = (const float*)d_in[2];
    const float* wk_s = (const float*)d_in[3];
    const float* wv_s = (const float*)d_in[4];
    const float* fc_s = (const float*)d_in[5];
    const float* lnw_s= (const float*)d_in[6];
    const float* lnb_s= (const float*)d_in[7];
    const float* wq_c = (const float*)d_in[8];
    const float* wk_c = (const float*)d_in[9];
    const float* wv_c = (const float*)d_in[10];
    const float* fc_c = (const float*)d_in[11];
    const float* lnw_c= (const float*)d_in[12];
    const float* lnb_c= (const float*)d_in[13];
    const float* w1   = (const float*)d_in[14];
    const float* b1   = (const float*)d_in[15];
    const float* w2   = (const float*)d_in[16];
    const float* b2   = (const float*)d_in[17];
    const float* lnw_f= (const float*)d_in[18];
    const float* lnb_f= (const float*)d_in[19];

    const size_t BUF  = (size_t)NPIX * CH;
    const size_t BUFB = BUF * 2;
    char* ws = (char*)d_ws;
    bf16* QKV = (bf16*)ws;                       // 3 quarters
    bf16* Q3  = (bf16*)(ws + 3 * BUFB);          // X1 -> Y2
    bf16* Hb  = (bf16*)ws;                       // FFN hidden (QKV dead by then)
    bf16* D2 = (bf16*)((char*)d_out + 2 * BUFB);
    bf16* D3 = (bf16*)((char*)d_out + 3 * BUFB);
    float* out1 = (float*)d_out;
    float* out2 = (float*)d_out + BUF;

    const dim3 G(NPIX / 64), B(256);
    const dim3 GA(NPIX * 16 / 256);

    // slf1 -> X1@Q3 (resid = in1 planar f32)
    conv_qkv<true><<<G, B, 0, stream>>>(in1, wq_s, wk_s, wv_s, QKV);
    attn5<<<GA, B, 0, stream>>>(QKV);
    conv_fc_ln<true><<<G, B, 0, stream>>>(QKV, fc_s, in1, lnw_s, lnb_s, Q3);

    // slf2 -> X2@D3
    conv_qkv<true><<<G, B, 0, stream>>>(in2, wq_s, wk_s, wv_s, QKV);
    attn5<<<GA, B, 0, stream>>>(QKV);
    conv_fc_ln<true><<<G, B, 0, stream>>>(QKV, fc_s, in2, lnw_s, lnb_s, D3);

    // crs1: q=X1@Q3, kv=X2@D3 -> Y1@D2 (resid = X1@Q3)
    conv_qkv_cross<<<G, B, 0, stream>>>(Q3, D3, wq_c, wk_c, wv_c, QKV);
    attn5<<<GA, B, 0, stream>>>(QKV);
    conv_fc_ln<false><<<G, B, 0, stream>>>(QKV, fc_c, Q3, lnw_c, lnb_c, D2);

    // crs2: q=X2@D3, kv=X1@Q3 -> Y2@Q3 (X1 dead after QKV conv; resid = X2@D3)
    conv_qkv_cross<<<G, B, 0, stream>>>(D3, Q3, wq_c, wk_c, wv_c, QKV);
    attn5<<<GA, B, 0, stream>>>(QKV);
    conv_fc_ln<false><<<G, B, 0, stream>>>(QKV, fc_c, D3, lnw_c, lnb_c, Q3);

    // ffn1: Y1@D2 -> out1 (@D0+D1)
    conv_relu<<<G, B, 0, stream>>>(D2, w1, b1, Hb);
    conv_ln_out<<<G, B, 0, stream>>>(Hb, w2, b2, lnw_f, lnb_f, D2, out1);

    // ffn2: Y2@Q3 -> out2 (@D2+D3)
    conv_relu<<<G, B, 0, stream>>>(Q3, w1, b1, Hb);
    conv_ln_out<<<G, B, 0, stream>>>(Hb, w2, b2, lnw_f, lnb_f, Q3, out2);
}

// Round 6
// 306.550 us; speedup vs baseline: 2.5567x; 1.0412x over previous
//
#include <hip/hip_runtime.h>
#include <hip/hip_bf16.h>

typedef __hip_bfloat16 bf16;
typedef __attribute__((ext_vector_type(8))) short short8v;   // 8 bf16 (4 VGPR)
typedef __attribute__((ext_vector_type(4))) float f32x4;     // MFMA acc
#define DI __device__ __forceinline__

constexpr int CH = 128;
constexpr int HH = 96, WW = 96;
constexpr int HW = HH * WW;          // 9216
constexpr int NB = 4;
constexpr int NPIX = NB * HW;        // 36864
constexpr int LDT = 136;             // conv LDS row stride (bf16)
constexpr size_t HP = (size_t)NPIX * 32;   // head-plane elements (one comp, one head)
// attention tile geometry
constexpr int TY = 4, TX = 32;       // tile pixels (4 rows x 32 cols)
constexpr int HYH = TY + 4, HXH = TX + 4;  // halo 8 x 36
constexpr int LDC = 40;              // LDS ch stride: 80B rows, 16B-aligned, bank-friendly

struct __attribute__((aligned(16))) bf16x8 { bf16 h[8]; };

DI float b2f(bf16 x) { return __bfloat162float(x); }
DI bf16  f2b(float x) { return __float2bfloat16(x); }

// ---- GEMM building blocks (unchanged core) --------------------------------
// Tile: 64 px x 128 out, K=128. 4 waves; wave w = px [16w,16w+16) x all 128 o.
// D lane: col(o)=l&15, row(px)=(l>>4)*4+reg   [m89-verified]

DI void stage_x_cl(const bf16* __restrict__ src, int ldx, bf16* xl, int t) {
    #pragma unroll
    for (int i = 0; i < 4; ++i) {
        int id = t + 256 * i, px = id >> 4, cc = (id & 15) * 8;
        *reinterpret_cast<short8v*>(&xl[px * LDT + cc]) =
            *reinterpret_cast<const short8v*>(&src[(size_t)px * ldx + cc]);
    }
}

// planar f32 [c][HW] -> LDS tile [px][c] bf16 (transposing scatter)
DI void stage_x_pl(const float* __restrict__ src, bf16* xl, int t) {
    #pragma unroll
    for (int i = 0; i < 8; ++i) {
        int id = t + 256 * i, c = id >> 4, p4 = (id & 15) * 4;
        float4 v = *reinterpret_cast<const float4*>(&src[(size_t)c * HW + p4]);
        xl[(p4 + 0) * LDT + c] = f2b(v.x);
        xl[(p4 + 1) * LDT + c] = f2b(v.y);
        xl[(p4 + 2) * LDT + c] = f2b(v.z);
        xl[(p4 + 3) * LDT + c] = f2b(v.w);
    }
}

// head-major T [h][p][32] -> LDS tile [px][128]
DI void stage_x_hm(const bf16* __restrict__ Tq, bf16* xl, int p0, int t) {
    const int px = t >> 2, c8 = (t & 3) * 8;
    #pragma unroll
    for (int h = 0; h < 4; ++h)
        *reinterpret_cast<short8v*>(&xl[px * LDT + h * 32 + c8]) =
            *reinterpret_cast<const short8v*>(&Tq[(size_t)h * HP + (size_t)(p0 + px) * 32 + c8]);
}

DI void stage_w_f32(const float* __restrict__ w, bf16* wl, int t) {
    #pragma unroll
    for (int i = 0; i < 8; ++i) {
        int id = t + 256 * i, o = id >> 4, cc = (id & 15) * 8;
        float4 a = *reinterpret_cast<const float4*>(&w[o * CH + cc]);
        float4 b = *reinterpret_cast<const float4*>(&w[o * CH + cc + 4]);
        bf16x8 tmp;
        tmp.h[0] = f2b(a.x); tmp.h[1] = f2b(a.y); tmp.h[2] = f2b(a.z); tmp.h[3] = f2b(a.w);
        tmp.h[4] = f2b(b.x); tmp.h[5] = f2b(b.y); tmp.h[6] = f2b(b.z); tmp.h[7] = f2b(b.w);
        *reinterpret_cast<short8v*>(&wl[o * LDT + cc]) = *reinterpret_cast<const short8v*>(&tmp);
    }
}

DI void stage_w_bf(const bf16* __restrict__ w, bf16* wl, int t) {
    #pragma unroll
    for (int i = 0; i < 8; ++i) {
        int id = t + 256 * i, o = id >> 4, cc = (id & 15) * 8;
        *reinterpret_cast<short8v*>(&wl[o * LDT + cc]) =
            *reinterpret_cast<const short8v*>(&w[o * CH + cc]);
    }
}

DI void gemm64(const bf16* xl, const bf16* wl, int w, int l, f32x4* acc) {
    const int s = l & 15, g = l >> 4;
    #pragma unroll
    for (int ks = 0; ks < 4; ++ks) {
        short8v a = *reinterpret_cast<const short8v*>(&xl[(16 * w + s) * LDT + ks * 32 + g * 8]);
        #pragma unroll
        for (int n = 0; n < 8; ++n) {
            short8v b = *reinterpret_cast<const short8v*>(&wl[(16 * n + s) * LDT + ks * 32 + g * 8]);
            acc[n] = __builtin_amdgcn_mfma_f32_16x16x32_bf16(a, b, acc[n], 0, 0, 0);
        }
    }
}

// epilogue into head-major comp plane [head][p][32]
DI void qkv_epi(const f32x4* acc, bf16* comp, int p0, int w, int l) {
    const int s = l & 15, g = l >> 4;
    #pragma unroll
    for (int n = 0; n < 8; ++n) {
        const int o = 16 * n + s, head = o >> 5, ch = o & 31;
        bf16* pl = comp + (size_t)head * HP;
        #pragma unroll
        for (int j = 0; j < 4; ++j) {
            int px = 16 * w + 4 * g + j;
            pl[(size_t)(p0 + px) * 32 + ch] = f2b(acc[n][j]);
        }
    }
}

// ---- one-shot f32->bf16 weight conversion (8 attention-path matrices) -----
struct WPtrs { const float* p[8]; };
__global__ __launch_bounds__(256)
void wcvt(WPtrs wp, bf16* __restrict__ dst) {
    const int mat = blockIdx.x >> 4;
    const int off = ((blockIdx.x & 15) * 256 + threadIdx.x) * 4;
    float4 v = *reinterpret_cast<const float4*>(wp.p[mat] + off);
    bf16* d = dst + mat * (CH * CH) + off;
    d[0] = f2b(v.x); d[1] = f2b(v.y); d[2] = f2b(v.z); d[3] = f2b(v.w);
}

// ---- QKV projection: 3 matrices from one x (self-attn) --------------------
template<bool XPLANAR>
__global__ __launch_bounds__(256, 2)
void conv_qkv(const void* __restrict__ xv,
              const bf16* __restrict__ w0, const bf16* __restrict__ w1_,
              const bf16* __restrict__ w2_, bf16* __restrict__ out) {
    __shared__ bf16 xl[64 * LDT];
    __shared__ bf16 wl[CH * LDT];
    const int t = threadIdx.x, p0 = blockIdx.x * 64;
    if (XPLANAR) {
        const int b = p0 / HW, hw0 = p0 % HW;
        stage_x_pl((const float*)xv + (size_t)b * CH * HW + hw0, xl, t);
    } else {
        stage_x_cl((const bf16*)xv + (size_t)p0 * CH, CH, xl, t);
    }
    const int w = t >> 6, l = t & 63;
    #pragma unroll
    for (int m = 0; m < 3; ++m) {
        const bf16* wm = (m == 0) ? w0 : ((m == 1) ? w1_ : w2_);
        __syncthreads();
        stage_w_bf(wm, wl, t);
        __syncthreads();
        f32x4 acc[8];
        #pragma unroll
        for (int n = 0; n < 8; ++n) acc[n] = {0.f, 0.f, 0.f, 0.f};
        gemm64(xl, wl, w, l, acc);
        qkv_epi(acc, out + (size_t)m * 4 * HP, p0, w, l);
    }
}

// ---- cross-attn QKV: Q from xq, K+V from xkv ------------------------------
__global__ __launch_bounds__(256, 2)
void conv_qkv_cross(const bf16* __restrict__ xq, const bf16* __restrict__ xkv,
                    const bf16* __restrict__ wq, const bf16* __restrict__ wk,
                    const bf16* __restrict__ wv, bf16* __restrict__ out) {
    __shared__ bf16 xl[64 * LDT];
    __shared__ bf16 wl[CH * LDT];
    const int t = threadIdx.x, p0 = blockIdx.x * 64;
    const int w = t >> 6, l = t & 63;

    stage_x_cl(xq + (size_t)p0 * CH, CH, xl, t);
    stage_w_bf(wq, wl, t);
    __syncthreads();
    {
        f32x4 acc[8];
        #pragma unroll
        for (int n = 0; n < 8; ++n) acc[n] = {0.f, 0.f, 0.f, 0.f};
        gemm64(xl, wl, w, l, acc);
        qkv_epi(acc, out, p0, w, l);
    }
    __syncthreads();
    stage_x_cl(xkv + (size_t)p0 * CH, CH, xl, t);
    stage_w_bf(wk, wl, t);
    __syncthreads();
    {
        f32x4 acc[8];
        #pragma unroll
        for (int n = 0; n < 8; ++n) acc[n] = {0.f, 0.f, 0.f, 0.f};
        gemm64(xl, wl, w, l, acc);
        qkv_epi(acc, out + 4 * HP, p0, w, l);
    }
    __syncthreads();
    stage_w_bf(wv, wl, t);
    __syncthreads();
    {
        f32x4 acc[8];
        #pragma unroll
        for (int n = 0; n < 8; ++n) acc[n] = {0.f, 0.f, 0.f, 0.f};
        gemm64(xl, wl, w, l, acc);
        qkv_epi(acc, out + 8 * HP, p0, w, l);
    }
}

// ---- 5x5 local attention, LDS-tiled, two-phase K/V reuse ------------------
// Block = (4x32 px tile, head n), 128 threads, thread = 1 px x 32 ch.
// Halo 8x36 staged with zero-fill (OOB logits exactly 0, divergence-free
// compute). K staged -> QK+softmax -> V staged into SAME buffer -> PV.
// T written in-place over own Q slice (each px's Q read only by its thread;
// K/V planes never written).
__global__ __launch_bounds__(128)
void attn5(bf16* qkv) {
    __shared__ bf16 kv[HYH * HXH * LDC];          // 23 KB, reused K then V
    const int bid = blockIdx.x, n = bid & 3, tile = bid >> 2;
    const int img = tile / 72, rem = tile % 72, tr = rem / 3, tc = rem % 3;
    const int y0 = tr * TY, x0 = tc * TX;
    const int t = threadIdx.x, ty = t >> 5, tx = t & 31;
    bf16* Qh = qkv + (size_t)n * HP;
    const bf16* Kh = qkv + 4 * HP + (size_t)n * HP;
    const bf16* Vh = qkv + 8 * HP + (size_t)n * HP;
    const int gp = img * HW + (y0 + ty) * WW + (x0 + tx);
    bf16* qp = Qh + (size_t)gp * 32;

    // stage K tile (8 rows x 36 px x 32 ch = 1152 b128-chunks, 9 per thread)
    #pragma unroll
    for (int i = 0; i < 9; ++i) {
        int id = t + 128 * i;
        int r = id / 144, c = id - r * 144, px = c >> 2, ch8 = (c & 3) * 8;
        int y = y0 + r - 2, x = x0 + px - 2;
        short8v v = {0, 0, 0, 0, 0, 0, 0, 0};
        if ((unsigned)y < (unsigned)HH && (unsigned)x < (unsigned)WW)
            v = *reinterpret_cast<const short8v*>(&Kh[((size_t)(img * HW + y * WW + x)) * 32 + ch8]);
        *reinterpret_cast<short8v*>(&kv[(r * HXH + px) * LDC + ch8]) = v;
    }
    float q[32];
    #pragma unroll
    for (int i = 0; i < 4; ++i) {
        bf16x8 v = *reinterpret_cast<const bf16x8*>(qp + 8 * i);
        #pragma unroll
        for (int e = 0; e < 8; ++e) q[8 * i + e] = b2f(v.h[e]) * 0.17677669529663689f;
    }
    __syncthreads();

    float corr[25];
    #pragma unroll
    for (int dy = 0; dy < 5; ++dy)
        #pragma unroll
        for (int dx = 0; dx < 5; ++dx) {
            const bf16* kp = &kv[((ty + dy) * HXH + tx + dx) * LDC];
            float s = 0.f;
            #pragma unroll
            for (int i = 0; i < 4; ++i) {
                bf16x8 v = *reinterpret_cast<const bf16x8*>(kp + 8 * i);
                #pragma unroll
                for (int e = 0; e < 8; ++e) s += q[8 * i + e] * b2f(v.h[e]);
            }
            corr[dy * 5 + dx] = s;
        }

    float m = corr[0];
    #pragma unroll
    for (int j = 1; j < 25; ++j) m = fmaxf(m, corr[j]);
    float sum = 0.f;
    #pragma unroll
    for (int j = 0; j < 25; ++j) {
        float e = __expf(corr[j] - m);
        corr[j] = e; sum += e;
    }
    const float inv = 1.f / sum;

    __syncthreads();                               // all K reads done
    // stage V tile into same LDS
    #pragma unroll
    for (int i = 0; i < 9; ++i) {
        int id = t + 128 * i;
        int r = id / 144, c = id - r * 144, px = c >> 2, ch8 = (c & 3) * 8;
        int y = y0 + r - 2, x = x0 + px - 2;
        short8v v = {0, 0, 0, 0, 0, 0, 0, 0};
        if ((unsigned)y < (unsigned)HH && (unsigned)x < (unsigned)WW)
            v = *reinterpret_cast<const short8v*>(&Vh[((size_t)(img * HW + y * WW + x)) * 32 + ch8]);
        *reinterpret_cast<short8v*>(&kv[(r * HXH + px) * LDC + ch8]) = v;
    }
    __syncthreads();

    float o[32];
    #pragma unroll
    for (int e = 0; e < 32; ++e) o[e] = 0.f;
    #pragma unroll
    for (int dy = 0; dy < 5; ++dy)
        #pragma unroll
        for (int dx = 0; dx < 5; ++dx) {
            const float a = corr[dy * 5 + dx];
            const bf16* vp = &kv[((ty + dy) * HXH + tx + dx) * LDC];
            #pragma unroll
            for (int i = 0; i < 4; ++i) {
                bf16x8 v = *reinterpret_cast<const bf16x8*>(vp + 8 * i);
                #pragma unroll
                for (int e = 0; e < 8; ++e) o[8 * i + e] += a * b2f(v.h[e]);
            }
        }
    #pragma unroll
    for (int i = 0; i < 4; ++i) {
        bf16x8 st;
        #pragma unroll
        for (int e = 0; e < 8; ++e) st.h[e] = f2b(o[8 * i + e] * inv);
        *reinterpret_cast<bf16x8*>(qp + 8 * i) = st;
    }
}

// ---- fc conv + resid(pre-LN) + LayerNorm -> bf16 pixel-major --------------
template<bool RPLANAR>
__global__ __launch_bounds__(256, 2)
void conv_fc_ln(const bf16* __restrict__ tin /*head-major T = Q comp*/,
                const bf16* __restrict__ wfc, const void* __restrict__ residv,
                const float* __restrict__ gamma, const float* __restrict__ beta,
                bf16* __restrict__ out) {
    __shared__ bf16 xl[64 * LDT];
    __shared__ bf16 wl[CH * LDT];
    const int t = threadIdx.x, p0 = blockIdx.x * 64;
    stage_x_hm(tin, xl, p0, t);
    stage_w_bf(wfc, wl, t);
    __syncthreads();
    const int w = t >> 6, l = t & 63, s = l & 15, g = l >> 4;
    f32x4 acc[8];
    #pragma unroll
    for (int n = 0; n < 8; ++n) acc[n] = {0.f, 0.f, 0.f, 0.f};
    gemm64(xl, wl, w, l, acc);

    const int b = p0 / HW, hw0 = p0 % HW;
    float r[8][4];
    #pragma unroll
    for (int n = 0; n < 8; ++n) {
        const int o = 16 * n + s;
        #pragma unroll
        for (int j = 0; j < 4; ++j) {
            const int px = 16 * w + 4 * g + j;
            float rv;
            if (RPLANAR)
                rv = ((const float*)residv)[(size_t)b * CH * HW + (size_t)o * HW + hw0 + px];
            else
                rv = b2f(((const bf16*)residv)[(size_t)(p0 + px) * CH + o]);
            r[n][j] = acc[n][j] + rv;
        }
    }
    float gm[8], bt[8];
    #pragma unroll
    for (int n = 0; n < 8; ++n) { gm[n] = gamma[16 * n + s]; bt[n] = beta[16 * n + s]; }
    #pragma unroll
    for (int j = 0; j < 4; ++j) {
        float sm = 0.f, sq = 0.f;
        #pragma unroll
        for (int n = 0; n < 8; ++n) { float v = r[n][j]; sm += v; sq += v * v; }
        sm += __shfl_xor(sm, 1); sq += __shfl_xor(sq, 1);
        sm += __shfl_xor(sm, 2); sq += __shfl_xor(sq, 2);
        sm += __shfl_xor(sm, 4); sq += __shfl_xor(sq, 4);
        sm += __shfl_xor(sm, 8); sq += __shfl_xor(sq, 8);
        const float mu = sm * (1.f / 128.f);
        const float var = sq * (1.f / 128.f) - mu * mu;
        const float rs = rsqrtf(var + 1e-6f);
        const int px = 16 * w + 4 * g + j;
        #pragma unroll
        for (int n = 0; n < 8; ++n) {
            const int o = 16 * n + s;
            out[(size_t)(p0 + px) * CH + o] = f2b(gm[n] * (r[n][j] - mu) * rs + bt[n]);
        }
    }
}

// ---- FFN conv1: bias + ReLU (f32 W path) ----------------------------------
__global__ __launch_bounds__(256, 2)
void conv_relu(const bf16* __restrict__ x, const float* __restrict__ wm,
               const float* __restrict__ bias, bf16* __restrict__ out) {
    __shared__ bf16 xl[64 * LDT];
    __shared__ bf16 wl[CH * LDT];
    const int t = threadIdx.x, p0 = blockIdx.x * 64;
    stage_x_cl(x + (size_t)p0 * CH, CH, xl, t);
    stage_w_f32(wm, wl, t);
    __syncthreads();
    const int w = t >> 6, l = t & 63, s = l & 15, g = l >> 4;
    f32x4 acc[8];
    #pragma unroll
    for (int n = 0; n < 8; ++n) acc[n] = {0.f, 0.f, 0.f, 0.f};
    gemm64(xl, wl, w, l, acc);
    float bv[8];
    #pragma unroll
    for (int n = 0; n < 8; ++n) bv[n] = bias[16 * n + s];
    #pragma unroll
    for (int n = 0; n < 8; ++n) {
        const int o = 16 * n + s;
        #pragma unroll
        for (int j = 0; j < 4; ++j) {
            const int px = 16 * w + 4 * g + j;
            out[(size_t)(p0 + px) * CH + o] = f2b(fmaxf(acc[n][j] + bv[n], 0.f));
        }
    }
}

// ---- FFN conv2: bias + LN + resid(post-LN) -> PLANAR f32 output -----------
__global__ __launch_bounds__(256, 2)
void conv_ln_out(const bf16* __restrict__ h, const float* __restrict__ wm,
                 const float* __restrict__ bias, const float* __restrict__ gamma,
                 const float* __restrict__ beta, const bf16* __restrict__ resid,
                 float* __restrict__ outp) {
    __shared__ __align__(16) char smem[64 * LDT * 2 + CH * LDT * 2];  // 52224 B
    bf16*  xl = (bf16*)smem;
    bf16*  wl = (bf16*)(smem + 64 * LDT * 2);
    float* ll = (float*)smem;                       // aliased after sync
    const int t = threadIdx.x, p0 = blockIdx.x * 64;
    stage_x_cl(h + (size_t)p0 * CH, CH, xl, t);
    stage_w_f32(wm, wl, t);
    __syncthreads();
    const int w = t >> 6, l = t & 63, s = l & 15, g = l >> 4;
    f32x4 acc[8];
    #pragma unroll
    for (int n = 0; n < 8; ++n) acc[n] = {0.f, 0.f, 0.f, 0.f};
    gemm64(xl, wl, w, l, acc);

    float bv[8], gm[8], bt[8];
    #pragma unroll
    for (int n = 0; n < 8; ++n) {
        bv[n] = bias[16 * n + s]; gm[n] = gamma[16 * n + s]; bt[n] = beta[16 * n + s];
    }
    float r[8][4];
    #pragma unroll
    for (int n = 0; n < 8; ++n)
        #pragma unroll
        for (int j = 0; j < 4; ++j) r[n][j] = acc[n][j] + bv[n];

    float val[8][4];
    #pragma unroll
    for (int j = 0; j < 4; ++j) {
        float sm = 0.f, sq = 0.f;
        #pragma unroll
        for (int n = 0; n < 8; ++n) { float v = r[n][j]; sm += v; sq += v * v; }
        sm += __shfl_xor(sm, 1); sq += __shfl_xor(sq, 1);
        sm += __shfl_xor(sm, 2); sq += __shfl_xor(sq, 2);
        sm += __shfl_xor(sm, 4); sq += __shfl_xor(sq, 4);
        sm += __shfl_xor(sm, 8); sq += __shfl_xor(sq, 8);
        const float mu = sm * (1.f / 128.f);
        const float var = sq * (1.f / 128.f) - mu * mu;
        const float rs = rsqrtf(var + 1e-6f);
        const int px = 16 * w + 4 * g + j;
        #pragma unroll
        for (int n = 0; n < 8; ++n) {
            const int o = 16 * n + s;
            val[n][j] = gm[n] * (r[n][j] - mu) * rs + bt[n]
                      + b2f(resid[(size_t)(p0 + px) * CH + o]);
        }
    }
    __syncthreads();
    #pragma unroll
    for (int n = 0; n < 8; ++n) {
        const int o = 16 * n + s;
        #pragma unroll
        for (int j = 0; j < 4; ++j) ll[o * 65 + 16 * w + 4 * g + j] = val[n][j];
    }
    __syncthreads();
    const int b = p0 / HW, hw0 = p0 % HW;
    #pragma unroll
    for (int i = 0; i < 8; ++i) {
        int id = t + 256 * i, c = id >> 4, p4 = (id & 15) * 4;
        float4 v = { ll[c * 65 + p4], ll[c * 65 + p4 + 1],
                     ll[c * 65 + p4 + 2], ll[c * 65 + p4 + 3] };
        *reinterpret_cast<float4*>(&outp[(size_t)b * CH * HW + (size_t)c * HW + hw0 + p4]) = v;
    }
}

// ---------------------------------------------------------------------------
// Liveness (quarter = NPIX*128 bf16 = 9,437,184 B):
//   ws: Q0..Q2 = QKV head-major [comp][head][p][32]; after crs2 -> Hb = Q0.
//       Q3 = X1 -> Y2
//   d_out: D1 head = Wb (8 bf16 matrices, 256KB; wcvt at start; dead before
//          out1 write). D2 = Y1; D3 = X2 -> (resid only). out1 = D0+D1,
//          out2 = D2+D3, written last. FFN convs use original f32 W (Wb dead).
// ---------------------------------------------------------------------------
extern "C" void kernel_launch(void* const* d_in, const int* in_sizes, int n_in,
                              void* d_out, int out_size, void* d_ws, size_t ws_size,
                              hipStream_t stream) {
    (void)in_sizes; (void)n_in; (void)out_size; (void)ws_size;
    const float* in1  = (const float*)d_in[0];
    const float* in2  = (const float*)d_in[1];
    const float* lnw_s= (const float*)d_in[6];
    const float* lnb_s= (const float*)d_in[7];
    const float* lnw_c= (const float*)d_in[12];
    const float* lnb_c= (const float*)d_in[13];
    const float* w1   = (const float*)d_in[14];
    const float* b1   = (const float*)d_in[15];
    const float* w2   = (const float*)d_in[16];
    const float* b2   = (const float*)d_in[17];
    const float* lnw_f= (const float*)d_in[18];
    const float* lnb_f= (const float*)d_in[19];

    const size_t BUF  = (size_t)NPIX * CH;
    const size_t BUFB = BUF * 2;
    char* ws = (char*)d_ws;
    bf16* QKV = (bf16*)ws;                       // 3 quarters, head-major
    bf16* Q3  = (bf16*)(ws + 3 * BUFB);          // X1 -> Y2
    bf16* Hb  = (bf16*)ws;                       // FFN hidden (QKV dead by then)
    bf16* D2 = (bf16*)((char*)d_out + 2 * BUFB);
    bf16* D3 = (bf16*)((char*)d_out + 3 * BUFB);
    bf16* Wb = (bf16*)((char*)d_out + 1 * BUFB); // converted weights @ D1
    float* out1 = (float*)d_out;
    float* out2 = (float*)d_out + BUF;

    const dim3 G(NPIX / 64), B(256);
    const dim3 GA(NPIX / (TY * TX) * 4), BA(128);

    // one-shot weight conversion for the attention path
    WPtrs wp;
    wp.p[0] = (const float*)d_in[2];  wp.p[1] = (const float*)d_in[3];
    wp.p[2] = (const float*)d_in[4];  wp.p[3] = (const float*)d_in[5];
    wp.p[4] = (const float*)d_in[8];  wp.p[5] = (const float*)d_in[9];
    wp.p[6] = (const float*)d_in[10]; wp.p[7] = (const float*)d_in[11];
    wcvt<<<dim3(128), B, 0, stream>>>(wp, Wb);
    const bf16 *bq_s = Wb, *bk_s = Wb + 16384, *bv_s = Wb + 2 * 16384,
               *bf_s = Wb + 3 * 16384, *bq_c = Wb + 4 * 16384,
               *bk_c = Wb + 5 * 16384, *bv_c = Wb + 6 * 16384,
               *bf_c = Wb + 7 * 16384;

    // slf1 -> X1@Q3 (resid = in1 planar f32)
    conv_qkv<true><<<G, B, 0, stream>>>(in1, bq_s, bk_s, bv_s, QKV);
    attn5<<<GA, BA, 0, stream>>>(QKV);
    conv_fc_ln<true><<<G, B, 0, stream>>>(QKV, bf_s, in1, lnw_s, lnb_s, Q3);

    // slf2 -> X2@D3
    conv_qkv<true><<<G, B, 0, stream>>>(in2, bq_s, bk_s, bv_s, QKV);
    attn5<<<GA, BA, 0, stream>>>(QKV);
    conv_fc_ln<true><<<G, B, 0, stream>>>(QKV, bf_s, in2, lnw_s, lnb_s, D3);

    // crs1: q=X1@Q3, kv=X2@D3 -> Y1@D2 (resid = X1@Q3)
    conv_qkv_cross<<<G, B, 0, stream>>>(Q3, D3, bq_c, bk_c, bv_c, QKV);
    attn5<<<GA, BA, 0, stream>>>(QKV);
    conv_fc_ln<false><<<G, B, 0, stream>>>(QKV, bf_c, Q3, lnw_c, lnb_c, D2);

    // crs2: q=X2@D3, kv=X1@Q3 -> Y2@Q3 (X1 dead after QKV conv; resid=X2@D3)
    conv_qkv_cross<<<G, B, 0, stream>>>(D3, Q3, bq_c, bk_c, bv_c, QKV);
    attn5<<<GA, BA, 0, stream>>>(QKV);
    conv_fc_ln<false><<<G, B, 0, stream>>>(QKV, bf_c, D3, lnw_c, lnb_c, Q3);

    // ffn1: Y1@D2 -> out1 (@D0+D1; Wb dead from here on)
    conv_relu<<<G, B, 0, stream>>>(D2, w1, b1, Hb);
    conv_ln_out<<<G, B, 0, stream>>>(Hb, w2, b2, lnw_f, lnb_f, D2, out1);

    // ffn2: Y2@Q3 -> out2 (@D2+D3)
    conv_relu<<<G, B, 0, stream>>>(Q3, w1, b1, Hb);
    conv_ln_out<<<G, B, 0, stream>>>(Hb, w2, b2, lnw_f, lnb_f, Q3, out2);
}

// Round 7
// 233.629 us; speedup vs baseline: 3.3547x; 1.3121x over previous
//
#include <hip/hip_runtime.h>
#include <hip/hip_bf16.h>

typedef __hip_bfloat16 bf16;
typedef __attribute__((ext_vector_type(8))) short short8v;   // 8 bf16 (4 VGPR)
typedef __attribute__((ext_vector_type(4))) float f32x4;     // MFMA acc
#define DI __device__ __forceinline__

constexpr int CH = 128;
constexpr int HH = 96, WW = 96;
constexpr int HW = HH * WW;          // 9216
constexpr int NB = 4;
constexpr int NPIX = NB * HW;        // 36864
constexpr int LDT = 136;             // conv LDS row stride (bf16)
constexpr size_t HP = (size_t)NPIX * 32;   // head-plane elements (one comp, one head)
// attention tile geometry
constexpr int TY = 4, TX = 32;       // tile pixels (4 rows x 32 cols)
constexpr int HYH = TY + 4, HXH = TX + 4;  // halo 8 x 36
constexpr int LDC = 40;              // LDS ch stride: 80B px rows, 16B-aligned

struct __attribute__((aligned(16))) bf16x8 { bf16 h[8]; };

DI float b2f(bf16 x) { return __bfloat162float(x); }
DI bf16  f2b(float x) { return __float2bfloat16(x); }

// ---- GEMM building blocks -------------------------------------------------
// Tile: 64 px x 128 out, K=128. 4 waves; wave w = px [16w,16w+16) x all 128 o.
// D lane: col(o)=l&15, row(px)=(l>>4)*4+reg   [m89-verified]

DI void stage_x_cl(const bf16* __restrict__ src, int ldx, bf16* xl, int t) {
    #pragma unroll
    for (int i = 0; i < 4; ++i) {
        int id = t + 256 * i, px = id >> 4, cc = (id & 15) * 8;
        *reinterpret_cast<short8v*>(&xl[px * LDT + cc]) =
            *reinterpret_cast<const short8v*>(&src[(size_t)px * ldx + cc]);
    }
}

// planar f32 [c][HW] -> LDS tile [px][c] bf16 (transposing scatter)
DI void stage_x_pl(const float* __restrict__ src, bf16* xl, int t) {
    #pragma unroll
    for (int i = 0; i < 8; ++i) {
        int id = t + 256 * i, c = id >> 4, p4 = (id & 15) * 4;
        float4 v = *reinterpret_cast<const float4*>(&src[(size_t)c * HW + p4]);
        xl[(p4 + 0) * LDT + c] = f2b(v.x);
        xl[(p4 + 1) * LDT + c] = f2b(v.y);
        xl[(p4 + 2) * LDT + c] = f2b(v.z);
        xl[(p4 + 3) * LDT + c] = f2b(v.w);
    }
}

// head-major T [h][p][32] -> LDS tile [px][128]
DI void stage_x_hm(const bf16* __restrict__ Tq, bf16* xl, int p0, int t) {
    const int px = t >> 2, c8 = (t & 3) * 8;
    #pragma unroll
    for (int h = 0; h < 4; ++h)
        *reinterpret_cast<short8v*>(&xl[px * LDT + h * 32 + c8]) =
            *reinterpret_cast<const short8v*>(&Tq[(size_t)h * HP + (size_t)(p0 + px) * 32 + c8]);
}

DI void stage_w_f32(const float* __restrict__ w, bf16* wl, int t) {
    #pragma unroll
    for (int i = 0; i < 8; ++i) {
        int id = t + 256 * i, o = id >> 4, cc = (id & 15) * 8;
        float4 a = *reinterpret_cast<const float4*>(&w[o * CH + cc]);
        float4 b = *reinterpret_cast<const float4*>(&w[o * CH + cc + 4]);
        bf16x8 tmp;
        tmp.h[0] = f2b(a.x); tmp.h[1] = f2b(a.y); tmp.h[2] = f2b(a.z); tmp.h[3] = f2b(a.w);
        tmp.h[4] = f2b(b.x); tmp.h[5] = f2b(b.y); tmp.h[6] = f2b(b.z); tmp.h[7] = f2b(b.w);
        *reinterpret_cast<short8v*>(&wl[o * LDT + cc]) = *reinterpret_cast<const short8v*>(&tmp);
    }
}

DI void stage_w_bf(const bf16* __restrict__ w, bf16* wl, int t) {
    #pragma unroll
    for (int i = 0; i < 8; ++i) {
        int id = t + 256 * i, o = id >> 4, cc = (id & 15) * 8;
        *reinterpret_cast<short8v*>(&wl[o * LDT + cc]) =
            *reinterpret_cast<const short8v*>(&w[o * CH + cc]);
    }
}

DI void gemm64(const bf16* xl, const bf16* wl, int w, int l, f32x4* acc) {
    const int s = l & 15, g = l >> 4;
    #pragma unroll
    for (int ks = 0; ks < 4; ++ks) {
        short8v a = *reinterpret_cast<const short8v*>(&xl[(16 * w + s) * LDT + ks * 32 + g * 8]);
        #pragma unroll
        for (int n = 0; n < 8; ++n) {
            short8v b = *reinterpret_cast<const short8v*>(&wl[(16 * n + s) * LDT + ks * 32 + g * 8]);
            acc[n] = __builtin_amdgcn_mfma_f32_16x16x32_bf16(a, b, acc[n], 0, 0, 0);
        }
    }
}

// epilogue into head-major comp plane [head][p][32]
DI void qkv_epi(const f32x4* acc, bf16* comp, int p0, int w, int l) {
    const int s = l & 15, g = l >> 4;
    #pragma unroll
    for (int n = 0; n < 8; ++n) {
        const int o = 16 * n + s, head = o >> 5, ch = o & 31;
        bf16* pl = comp + (size_t)head * HP;
        #pragma unroll
        for (int j = 0; j < 4; ++j) {
            int px = 16 * w + 4 * g + j;
            pl[(size_t)(p0 + px) * 32 + ch] = f2b(acc[n][j]);
        }
    }
}

// ---- one-shot f32->bf16 weight conversion (8 attention-path matrices) -----
struct WPtrs { const float* p[8]; };
__global__ __launch_bounds__(256)
void wcvt(WPtrs wp, bf16* __restrict__ dst) {
    const int mat = blockIdx.x >> 4;
    const int off = ((blockIdx.x & 15) * 256 + threadIdx.x) * 4;
    float4 v = *reinterpret_cast<const float4*>(wp.p[mat] + off);
    bf16* d = dst + mat * (CH * CH) + off;
    d[0] = f2b(v.x); d[1] = f2b(v.y); d[2] = f2b(v.z); d[3] = f2b(v.w);
}

// ---- QKV projection: 3 matrices from one x (self-attn) --------------------
template<bool XPLANAR>
__global__ __launch_bounds__(256, 2)
void conv_qkv(const void* __restrict__ xv,
              const bf16* __restrict__ w0, const bf16* __restrict__ w1_,
              const bf16* __restrict__ w2_, bf16* __restrict__ out) {
    __shared__ bf16 xl[64 * LDT];
    __shared__ bf16 wl[CH * LDT];
    const int t = threadIdx.x, p0 = blockIdx.x * 64;
    if (XPLANAR) {
        const int b = p0 / HW, hw0 = p0 % HW;
        stage_x_pl((const float*)xv + (size_t)b * CH * HW + hw0, xl, t);
    } else {
        stage_x_cl((const bf16*)xv + (size_t)p0 * CH, CH, xl, t);
    }
    const int w = t >> 6, l = t & 63;
    #pragma unroll
    for (int m = 0; m < 3; ++m) {
        const bf16* wm = (m == 0) ? w0 : ((m == 1) ? w1_ : w2_);
        __syncthreads();
        stage_w_bf(wm, wl, t);
        __syncthreads();
        f32x4 acc[8];
        #pragma unroll
        for (int n = 0; n < 8; ++n) acc[n] = {0.f, 0.f, 0.f, 0.f};
        gemm64(xl, wl, w, l, acc);
        qkv_epi(acc, out + (size_t)m * 4 * HP, p0, w, l);
    }
}

// ---- cross-attn QKV: Q from xq, K+V from xkv ------------------------------
__global__ __launch_bounds__(256, 2)
void conv_qkv_cross(const bf16* __restrict__ xq, const bf16* __restrict__ xkv,
                    const bf16* __restrict__ wq, const bf16* __restrict__ wk,
                    const bf16* __restrict__ wv, bf16* __restrict__ out) {
    __shared__ bf16 xl[64 * LDT];
    __shared__ bf16 wl[CH * LDT];
    const int t = threadIdx.x, p0 = blockIdx.x * 64;
    const int w = t >> 6, l = t & 63;

    stage_x_cl(xq + (size_t)p0 * CH, CH, xl, t);
    stage_w_bf(wq, wl, t);
    __syncthreads();
    {
        f32x4 acc[8];
        #pragma unroll
        for (int n = 0; n < 8; ++n) acc[n] = {0.f, 0.f, 0.f, 0.f};
        gemm64(xl, wl, w, l, acc);
        qkv_epi(acc, out, p0, w, l);
    }
    __syncthreads();
    stage_x_cl(xkv + (size_t)p0 * CH, CH, xl, t);
    stage_w_bf(wk, wl, t);
    __syncthreads();
    {
        f32x4 acc[8];
        #pragma unroll
        for (int n = 0; n < 8; ++n) acc[n] = {0.f, 0.f, 0.f, 0.f};
        gemm64(xl, wl, w, l, acc);
        qkv_epi(acc, out + 4 * HP, p0, w, l);
    }
    __syncthreads();
    stage_w_bf(wv, wl, t);
    __syncthreads();
    {
        f32x4 acc[8];
        #pragma unroll
        for (int n = 0; n < 8; ++n) acc[n] = {0.f, 0.f, 0.f, 0.f};
        gemm64(xl, wl, w, l, acc);
        qkv_epi(acc, out + 8 * HP, p0, w, l);
    }
}

// ---- 5x5 local attention: LDS halo tiling + 4 threads per (px,head) -------
// Block = (4x32 px tile, head), 512 threads; thread = (px, 8-ch quarter).
// 9216 waves total (round 6 had 2304 -> latency-bound). K staged -> QK
// (partials over 8 ch, combined via shfl_xor 1,2 within the 4-lane group)
// -> softmax (redundant per lane) -> V staged into SAME buffer -> PV (no
// shuffles). Zero-filled halo keeps OOB logits exactly 0, divergence-free.
// T written in-place over own Q slice (each 16B slice touched by exactly
// its owner thread; K/V planes never written).
__global__ __launch_bounds__(512)
void attn5(bf16* qkv) {
    __shared__ bf16 kv[HYH * HXH * LDC];          // 23 KB, reused K then V
    const int bid = blockIdx.x, n = bid & 3, tile = bid >> 2;
    const int img = tile / 72, rem = tile % 72, tr = rem / 3, tc = rem % 3;
    const int y0 = tr * TY, x0 = tc * TX;
    const int t = threadIdx.x;
    const int p = t >> 2, qtr = t & 3, ch8 = qtr * 8;
    const int ty = p >> 5, tx = p & 31;
    bf16* Qh = qkv + (size_t)n * HP;
    const bf16* Kh = qkv + 4 * HP + (size_t)n * HP;
    const bf16* Vh = qkv + 8 * HP + (size_t)n * HP;
    const int gp = img * HW + (y0 + ty) * WW + (x0 + tx);
    bf16* qp = Qh + (size_t)gp * 32 + ch8;

    // own Q slice, pre-scaled by 1/sqrt(32)
    float q[8];
    {
        bf16x8 v = *reinterpret_cast<const bf16x8*>(qp);
        #pragma unroll
        for (int e = 0; e < 8; ++e) q[e] = b2f(v.h[e]) * 0.17677669529663689f;
    }

    // stage K halo: 8 x 36 px x 4 ch8-chunks = 1152 chunks over 512 threads
    #pragma unroll
    for (int i = 0; i < 3; ++i) {
        int id = t + 512 * i;
        if (id < 1152) {
            int r = id / 144, c = id - r * 144, px = c >> 2, c8 = (c & 3) * 8;
            int y = y0 + r - 2, x = x0 + px - 2;
            short8v v = {0, 0, 0, 0, 0, 0, 0, 0};
            if ((unsigned)y < (unsigned)HH && (unsigned)x < (unsigned)WW)
                v = *reinterpret_cast<const short8v*>(&Kh[((size_t)(img * HW + y * WW + x)) * 32 + c8]);
            *reinterpret_cast<short8v*>(&kv[(r * HXH + px) * LDC + c8]) = v;
        }
    }
    __syncthreads();

    float corr[25];
    #pragma unroll
    for (int dy = 0; dy < 5; ++dy)
        #pragma unroll
        for (int dx = 0; dx < 5; ++dx) {
            const bf16* kp = &kv[((ty + dy) * HXH + tx + dx) * LDC + ch8];
            bf16x8 v = *reinterpret_cast<const bf16x8*>(kp);
            float s = 0.f;
            #pragma unroll
            for (int e = 0; e < 8; ++e) s += q[e] * b2f(v.h[e]);
            s += __shfl_xor(s, 1);
            s += __shfl_xor(s, 2);
            corr[dy * 5 + dx] = s;
        }

    float m = corr[0];
    #pragma unroll
    for (int j = 1; j < 25; ++j) m = fmaxf(m, corr[j]);
    float sum = 0.f;
    #pragma unroll
    for (int j = 0; j < 25; ++j) {
        float e = __expf(corr[j] - m);
        corr[j] = e; sum += e;
    }
    const float inv = 1.f / sum;

    __syncthreads();                               // all K reads done
    #pragma unroll
    for (int i = 0; i < 3; ++i) {
        int id = t + 512 * i;
        if (id < 1152) {
            int r = id / 144, c = id - r * 144, px = c >> 2, c8 = (c & 3) * 8;
            int y = y0 + r - 2, x = x0 + px - 2;
            short8v v = {0, 0, 0, 0, 0, 0, 0, 0};
            if ((unsigned)y < (unsigned)HH && (unsigned)x < (unsigned)WW)
                v = *reinterpret_cast<const short8v*>(&Vh[((size_t)(img * HW + y * WW + x)) * 32 + c8]);
            *reinterpret_cast<short8v*>(&kv[(r * HXH + px) * LDC + c8]) = v;
        }
    }
    __syncthreads();

    float o[8];
    #pragma unroll
    for (int e = 0; e < 8; ++e) o[e] = 0.f;
    #pragma unroll
    for (int dy = 0; dy < 5; ++dy)
        #pragma unroll
        for (int dx = 0; dx < 5; ++dx) {
            const float a = corr[dy * 5 + dx];
            const bf16* vp = &kv[((ty + dy) * HXH + tx + dx) * LDC + ch8];
            bf16x8 v = *reinterpret_cast<const bf16x8*>(vp);
            #pragma unroll
            for (int e = 0; e < 8; ++e) o[e] += a * b2f(v.h[e]);
        }
    bf16x8 st;
    #pragma unroll
    for (int e = 0; e < 8; ++e) st.h[e] = f2b(o[e] * inv);
    *reinterpret_cast<bf16x8*>(qp) = st;
}

// ---- fc conv + resid(pre-LN) + LayerNorm -> bf16 pixel-major --------------
template<bool RPLANAR>
__global__ __launch_bounds__(256, 2)
void conv_fc_ln(const bf16* __restrict__ tin /*head-major T = Q comp*/,
                const bf16* __restrict__ wfc, const void* __restrict__ residv,
                const float* __restrict__ gamma, const float* __restrict__ beta,
                bf16* __restrict__ out) {
    __shared__ bf16 xl[64 * LDT];
    __shared__ bf16 wl[CH * LDT];
    const int t = threadIdx.x, p0 = blockIdx.x * 64;
    stage_x_hm(tin, xl, p0, t);
    stage_w_bf(wfc, wl, t);
    __syncthreads();
    const int w = t >> 6, l = t & 63, s = l & 15, g = l >> 4;
    f32x4 acc[8];
    #pragma unroll
    for (int n = 0; n < 8; ++n) acc[n] = {0.f, 0.f, 0.f, 0.f};
    gemm64(xl, wl, w, l, acc);

    const int b = p0 / HW, hw0 = p0 % HW;
    float r[8][4];
    #pragma unroll
    for (int n = 0; n < 8; ++n) {
        const int o = 16 * n + s;
        #pragma unroll
        for (int j = 0; j < 4; ++j) {
            const int px = 16 * w + 4 * g + j;
            float rv;
            if (RPLANAR)
                rv = ((const float*)residv)[(size_t)b * CH * HW + (size_t)o * HW + hw0 + px];
            else
                rv = b2f(((const bf16*)residv)[(size_t)(p0 + px) * CH + o]);
            r[n][j] = acc[n][j] + rv;
        }
    }
    float gm[8], bt[8];
    #pragma unroll
    for (int n = 0; n < 8; ++n) { gm[n] = gamma[16 * n + s]; bt[n] = beta[16 * n + s]; }
    #pragma unroll
    for (int j = 0; j < 4; ++j) {
        float sm = 0.f, sq = 0.f;
        #pragma unroll
        for (int n = 0; n < 8; ++n) { float v = r[n][j]; sm += v; sq += v * v; }
        sm += __shfl_xor(sm, 1); sq += __shfl_xor(sq, 1);
        sm += __shfl_xor(sm, 2); sq += __shfl_xor(sq, 2);
        sm += __shfl_xor(sm, 4); sq += __shfl_xor(sq, 4);
        sm += __shfl_xor(sm, 8); sq += __shfl_xor(sq, 8);
        const float mu = sm * (1.f / 128.f);
        const float var = sq * (1.f / 128.f) - mu * mu;
        const float rs = rsqrtf(var + 1e-6f);
        const int px = 16 * w + 4 * g + j;
        #pragma unroll
        for (int n = 0; n < 8; ++n) {
            const int o = 16 * n + s;
            out[(size_t)(p0 + px) * CH + o] = f2b(gm[n] * (r[n][j] - mu) * rs + bt[n]);
        }
    }
}

// ---- FFN conv1: bias + ReLU (f32 W path) ----------------------------------
__global__ __launch_bounds__(256, 2)
void conv_relu(const bf16* __restrict__ x, const float* __restrict__ wm,
               const float* __restrict__ bias, bf16* __restrict__ out) {
    __shared__ bf16 xl[64 * LDT];
    __shared__ bf16 wl[CH * LDT];
    const int t = threadIdx.x, p0 = blockIdx.x * 64;
    stage_x_cl(x + (size_t)p0 * CH, CH, xl, t);
    stage_w_f32(wm, wl, t);
    __syncthreads();
    const int w = t >> 6, l = t & 63, s = l & 15, g = l >> 4;
    f32x4 acc[8];
    #pragma unroll
    for (int n = 0; n < 8; ++n) acc[n] = {0.f, 0.f, 0.f, 0.f};
    gemm64(xl, wl, w, l, acc);
    float bv[8];
    #pragma unroll
    for (int n = 0; n < 8; ++n) bv[n] = bias[16 * n + s];
    #pragma unroll
    for (int n = 0; n < 8; ++n) {
        const int o = 16 * n + s;
        #pragma unroll
        for (int j = 0; j < 4; ++j) {
            const int px = 16 * w + 4 * g + j;
            out[(size_t)(p0 + px) * CH + o] = f2b(fmaxf(acc[n][j] + bv[n], 0.f));
        }
    }
}

// ---- FFN conv2: bias + LN + resid(post-LN) -> PLANAR f32 output -----------
__global__ __launch_bounds__(256, 2)
void conv_ln_out(const bf16* __restrict__ h, const float* __restrict__ wm,
                 const float* __restrict__ bias, const float* __restrict__ gamma,
                 const float* __restrict__ beta, const bf16* __restrict__ resid,
                 float* __restrict__ outp) {
    __shared__ __align__(16) char smem[64 * LDT * 2 + CH * LDT * 2];  // 52224 B
    bf16*  xl = (bf16*)smem;
    bf16*  wl = (bf16*)(smem + 64 * LDT * 2);
    float* ll = (float*)smem;                       // aliased after sync
    const int t = threadIdx.x, p0 = blockIdx.x * 64;
    stage_x_cl(h + (size_t)p0 * CH, CH, xl, t);
    stage_w_f32(wm, wl, t);
    __syncthreads();
    const int w = t >> 6, l = t & 63, s = l & 15, g = l >> 4;
    f32x4 acc[8];
    #pragma unroll
    for (int n = 0; n < 8; ++n) acc[n] = {0.f, 0.f, 0.f, 0.f};
    gemm64(xl, wl, w, l, acc);

    float bv[8], gm[8], bt[8];
    #pragma unroll
    for (int n = 0; n < 8; ++n) {
        bv[n] = bias[16 * n + s]; gm[n] = gamma[16 * n + s]; bt[n] = beta[16 * n + s];
    }
    float r[8][4];
    #pragma unroll
    for (int n = 0; n < 8; ++n)
        #pragma unroll
        for (int j = 0; j < 4; ++j) r[n][j] = acc[n][j] + bv[n];

    float val[8][4];
    #pragma unroll
    for (int j = 0; j < 4; ++j) {
        float sm = 0.f, sq = 0.f;
        #pragma unroll
        for (int n = 0; n < 8; ++n) { float v = r[n][j]; sm += v; sq += v * v; }
        sm += __shfl_xor(sm, 1); sq += __shfl_xor(sq, 1);
        sm += __shfl_xor(sm, 2); sq += __shfl_xor(sq, 2);
        sm += __shfl_xor(sm, 4); sq += __shfl_xor(sq, 4);
        sm += __shfl_xor(sm, 8); sq += __shfl_xor(sq, 8);
        const float mu = sm * (1.f / 128.f);
        const float var = sq * (1.f / 128.f) - mu * mu;
        const float rs = rsqrtf(var + 1e-6f);
        const int px = 16 * w + 4 * g + j;
        #pragma unroll
        for (int n = 0; n < 8; ++n) {
            const int o = 16 * n + s;
            val[n][j] = gm[n] * (r[n][j] - mu) * rs + bt[n]
                      + b2f(resid[(size_t)(p0 + px) * CH + o]);
        }
    }
    __syncthreads();
    #pragma unroll
    for (int n = 0; n < 8; ++n) {
        const int o = 16 * n + s;
        #pragma unroll
        for (int j = 0; j < 4; ++j) ll[o * 65 + 16 * w + 4 * g + j] = val[n][j];
    }
    __syncthreads();
    const int b = p0 / HW, hw0 = p0 % HW;
    #pragma unroll
    for (int i = 0; i < 8; ++i) {
        int id = t + 256 * i, c = id >> 4, p4 = (id & 15) * 4;
        float4 v = { ll[c * 65 + p4], ll[c * 65 + p4 + 1],
                     ll[c * 65 + p4 + 2], ll[c * 65 + p4 + 3] };
        *reinterpret_cast<float4*>(&outp[(size_t)b * CH * HW + (size_t)c * HW + hw0 + p4]) = v;
    }
}

// ---------------------------------------------------------------------------
// Liveness (quarter = NPIX*128 bf16 = 9,437,184 B):
//   ws: Q0..Q2 = QKV head-major [comp][head][p][32]; after crs2 -> Hb = Q0.
//       Q3 = X1 -> Y2
//   d_out: D1 head = Wb (8 bf16 matrices, 256KB; wcvt at start; dead before
//          out1 write). D2 = Y1; D3 = X2 -> (resid only). out1 = D0+D1,
//          out2 = D2+D3, written last. FFN convs use original f32 W (Wb dead).
// ---------------------------------------------------------------------------
extern "C" void kernel_launch(void* const* d_in, const int* in_sizes, int n_in,
                              void* d_out, int out_size, void* d_ws, size_t ws_size,
                              hipStream_t stream) {
    (void)in_sizes; (void)n_in; (void)out_size; (void)ws_size;
    const float* in1  = (const float*)d_in[0];
    const float* in2  = (const float*)d_in[1];
    const float* lnw_s= (const float*)d_in[6];
    const float* lnb_s= (const float*)d_in[7];
    const float* lnw_c= (const float*)d_in[12];
    const float* lnb_c= (const float*)d_in[13];
    const float* w1   = (const float*)d_in[14];
    const float* b1   = (const float*)d_in[15];
    const float* w2   = (const float*)d_in[16];
    const float* b2   = (const float*)d_in[17];
    const float* lnw_f= (const float*)d_in[18];
    const float* lnb_f= (const float*)d_in[19];

    const size_t BUF  = (size_t)NPIX * CH;
    const size_t BUFB = BUF * 2;
    char* ws = (char*)d_ws;
    bf16* QKV = (bf16*)ws;                       // 3 quarters, head-major
    bf16* Q3  = (bf16*)(ws + 3 * BUFB);          // X1 -> Y2
    bf16* Hb  = (bf16*)ws;                       // FFN hidden (QKV dead by then)
    bf16* D2 = (bf16*)((char*)d_out + 2 * BUFB);
    bf16* D3 = (bf16*)((char*)d_out + 3 * BUFB);
    bf16* Wb = (bf16*)((char*)d_out + 1 * BUFB); // converted weights @ D1
    float* out1 = (float*)d_out;
    float* out2 = (float*)d_out + BUF;

    const dim3 G(NPIX / 64), B(256);
    const dim3 GA(NPIX / (TY * TX) * 4), BA(512);

    // one-shot weight conversion for the attention path
    WPtrs wp;
    wp.p[0] = (const float*)d_in[2];  wp.p[1] = (const float*)d_in[3];
    wp.p[2] = (const float*)d_in[4];  wp.p[3] = (const float*)d_in[5];
    wp.p[4] = (const float*)d_in[8];  wp.p[5] = (const float*)d_in[9];
    wp.p[6] = (const float*)d_in[10]; wp.p[7] = (const float*)d_in[11];
    wcvt<<<dim3(128), B, 0, stream>>>(wp, Wb);
    const bf16 *bq_s = Wb, *bk_s = Wb + 16384, *bv_s = Wb + 2 * 16384,
               *bf_s = Wb + 3 * 16384, *bq_c = Wb + 4 * 16384,
               *bk_c = Wb + 5 * 16384, *bv_c = Wb + 6 * 16384,
               *bf_c = Wb + 7 * 16384;

    // slf1 -> X1@Q3 (resid = in1 planar f32)
    conv_qkv<true><<<G, B, 0, stream>>>(in1, bq_s, bk_s, bv_s, QKV);
    attn5<<<GA, BA, 0, stream>>>(QKV);
    conv_fc_ln<true><<<G, B, 0, stream>>>(QKV, bf_s, in1, lnw_s, lnb_s, Q3);

    // slf2 -> X2@D3
    conv_qkv<true><<<G, B, 0, stream>>>(in2, bq_s, bk_s, bv_s, QKV);
    attn5<<<GA, BA, 0, stream>>>(QKV);
    conv_fc_ln<true><<<G, B, 0, stream>>>(QKV, bf_s, in2, lnw_s, lnb_s, D3);

    // crs1: q=X1@Q3, kv=X2@D3 -> Y1@D2 (resid = X1@Q3)
    conv_qkv_cross<<<G, B, 0, stream>>>(Q3, D3, bq_c, bk_c, bv_c, QKV);
    attn5<<<GA, BA, 0, stream>>>(QKV);
    conv_fc_ln<false><<<G, B, 0, stream>>>(QKV, bf_c, Q3, lnw_c, lnb_c, D2);

    // crs2: q=X2@D3, kv=X1@Q3 -> Y2@Q3 (X1 dead after QKV conv; resid=X2@D3)
    conv_qkv_cross<<<G, B, 0, stream>>>(D3, Q3, bq_c, bk_c, bv_c, QKV);
    attn5<<<GA, BA, 0, stream>>>(QKV);
    conv_fc_ln<false><<<G, B, 0, stream>>>(QKV, bf_c, D3, lnw_c, lnb_c, Q3);

    // ffn1: Y1@D2 -> out1 (@D0+D1; Wb dead from here on)
    conv_relu<<<G, B, 0, stream>>>(D2, w1, b1, Hb);
    conv_ln_out<<<G, B, 0, stream>>>(Hb, w2, b2, lnw_f, lnb_f, D2, out1);

    // ffn2: Y2@Q3 -> out2 (@D2+D3)
    conv_relu<<<G, B, 0, stream>>>(Q3, w1, b1, Hb);
    conv_ln_out<<<G, B, 0, stream>>>(Hb, w2, b2, lnw_f, lnb_f, Q3, out2);
}

// Round 8
// 199.912 us; speedup vs baseline: 3.9205x; 1.1687x over previous
//
#include <hip/hip_runtime.h>
#include <hip/hip_bf16.h>

typedef __hip_bfloat16 bf16;
typedef __attribute__((ext_vector_type(8))) short short8v;   // 8 bf16 (4 VGPR)
typedef __attribute__((ext_vector_type(4))) float f32x4;     // MFMA acc
#define DI __device__ __forceinline__

constexpr int CH = 128;
constexpr int HH = 96, WW = 96;
constexpr int HW = HH * WW;          // 9216
constexpr int NB = 4;
constexpr int NPIX = NB * HW;        // 36864
constexpr int LDT = 136;             // conv LDS row stride (bf16)
constexpr size_t HP = (size_t)NPIX * 32;   // head-plane elements
constexpr int GH = NPIX / 64;        // 576 blocks per tensor for convs
// attention tile geometry
constexpr int TY = 4, TX = 32;       // tile pixels (4 rows x 32 cols)
constexpr int HYH = TY + 4, HXH = TX + 4;  // halo 8 x 36
constexpr int LDC = 40;              // LDS ch stride
constexpr int ATB = NPIX / (TY * TX) * 4;  // 1152 attn blocks per set

struct __attribute__((aligned(16))) bf16x8 { bf16 h[8]; };
struct Set { bf16 *q, *k, *v; };     // comp-plane bases, each [4][NPIX][32]

DI float b2f(bf16 x) { return __bfloat162float(x); }
DI bf16  f2b(float x) { return __float2bfloat16(x); }

// ---- GEMM building blocks -------------------------------------------------
// Tile: 64 px x 128 out, K=128. 4 waves. D lane: col(o)=l&15, row=(l>>4)*4+reg.

DI void stage_x_cl(const bf16* __restrict__ src, int ldx, bf16* xl, int t) {
    #pragma unroll
    for (int i = 0; i < 4; ++i) {
        int id = t + 256 * i, px = id >> 4, cc = (id & 15) * 8;
        *reinterpret_cast<short8v*>(&xl[px * LDT + cc]) =
            *reinterpret_cast<const short8v*>(&src[(size_t)px * ldx + cc]);
    }
}

// planar f32 [c][HW] -> LDS tile [px][c] bf16
DI void stage_x_pl(const float* __restrict__ src, bf16* xl, int t) {
    #pragma unroll
    for (int i = 0; i < 8; ++i) {
        int id = t + 256 * i, c = id >> 4, p4 = (id & 15) * 4;
        float4 v = *reinterpret_cast<const float4*>(&src[(size_t)c * HW + p4]);
        xl[(p4 + 0) * LDT + c] = f2b(v.x);
        xl[(p4 + 1) * LDT + c] = f2b(v.y);
        xl[(p4 + 2) * LDT + c] = f2b(v.z);
        xl[(p4 + 3) * LDT + c] = f2b(v.w);
    }
}

// head-major T [h][p][32] -> LDS tile [px][128]
DI void stage_x_hm(const bf16* __restrict__ Tq, bf16* xl, int p0, int t) {
    const int px = t >> 2, c8 = (t & 3) * 8;
    #pragma unroll
    for (int h = 0; h < 4; ++h)
        *reinterpret_cast<short8v*>(&xl[px * LDT + h * 32 + c8]) =
            *reinterpret_cast<const short8v*>(&Tq[(size_t)h * HP + (size_t)(p0 + px) * 32 + c8]);
}

DI void stage_w_f32(const float* __restrict__ w, bf16* wl, int t) {
    #pragma unroll
    for (int i = 0; i < 8; ++i) {
        int id = t + 256 * i, o = id >> 4, cc = (id & 15) * 8;
        float4 a = *reinterpret_cast<const float4*>(&w[o * CH + cc]);
        float4 b = *reinterpret_cast<const float4*>(&w[o * CH + cc + 4]);
        bf16x8 tmp;
        tmp.h[0] = f2b(a.x); tmp.h[1] = f2b(a.y); tmp.h[2] = f2b(a.z); tmp.h[3] = f2b(a.w);
        tmp.h[4] = f2b(b.x); tmp.h[5] = f2b(b.y); tmp.h[6] = f2b(b.z); tmp.h[7] = f2b(b.w);
        *reinterpret_cast<short8v*>(&wl[o * LDT + cc]) = *reinterpret_cast<const short8v*>(&tmp);
    }
}

DI void stage_w_bf(const bf16* __restrict__ w, bf16* wl, int t) {
    #pragma unroll
    for (int i = 0; i < 8; ++i) {
        int id = t + 256 * i, o = id >> 4, cc = (id & 15) * 8;
        *reinterpret_cast<short8v*>(&wl[o * LDT + cc]) =
            *reinterpret_cast<const short8v*>(&w[o * CH + cc]);
    }
}

DI void gemm64(const bf16* xl, const bf16* wl, int w, int l, f32x4* acc) {
    const int s = l & 15, g = l >> 4;
    #pragma unroll
    for (int ks = 0; ks < 4; ++ks) {
        short8v a = *reinterpret_cast<const short8v*>(&xl[(16 * w + s) * LDT + ks * 32 + g * 8]);
        #pragma unroll
        for (int n = 0; n < 8; ++n) {
            short8v b = *reinterpret_cast<const short8v*>(&wl[(16 * n + s) * LDT + ks * 32 + g * 8]);
            acc[n] = __builtin_amdgcn_mfma_f32_16x16x32_bf16(a, b, acc[n], 0, 0, 0);
        }
    }
}

// epilogue into head-major comp plane [head][p][32]
DI void qkv_epi(const f32x4* acc, bf16* comp, int p0, int w, int l) {
    const int s = l & 15, g = l >> 4;
    #pragma unroll
    for (int n = 0; n < 8; ++n) {
        const int o = 16 * n + s, head = o >> 5, ch = o & 31;
        bf16* pl = comp + (size_t)head * HP;
        #pragma unroll
        for (int j = 0; j < 4; ++j) {
            int px = 16 * w + 4 * g + j;
            pl[(size_t)(p0 + px) * 32 + ch] = f2b(acc[n][j]);
        }
    }
}

// ---- one-shot f32->bf16 weight conversion (8 attention-path matrices) -----
struct WPtrs { const float* p[8]; };
__global__ __launch_bounds__(256)
void wcvt(WPtrs wp, bf16* __restrict__ dst) {
    const int mat = blockIdx.x >> 4;
    const int off = ((blockIdx.x & 15) * 256 + threadIdx.x) * 4;
    float4 v = *reinterpret_cast<const float4*>(wp.p[mat] + off);
    bf16* d = dst + mat * (CH * CH) + off;
    d[0] = f2b(v.x); d[1] = f2b(v.y); d[2] = f2b(v.z); d[3] = f2b(v.w);
}

// ---- batched self-attn QKV: half0 x0->setA, half1 x1->setB (planar f32) ---
__global__ __launch_bounds__(256, 2)
void qkv_self_b(const float* __restrict__ x0, const float* __restrict__ x1,
                const bf16* __restrict__ w0, const bf16* __restrict__ w1_,
                const bf16* __restrict__ w2_, Set sA, Set sB) {
    __shared__ bf16 xl[64 * LDT];
    __shared__ bf16 wl[CH * LDT];
    const int bid = blockIdx.x, half = bid / GH, p0 = (bid % GH) * 64;
    const float* xv = half ? x1 : x0;
    Set S = half ? sB : sA;
    const int t = threadIdx.x;
    const int b = p0 / HW, hw0 = p0 % HW;
    stage_x_pl(xv + (size_t)b * CH * HW + hw0, xl, t);
    const int w = t >> 6, l = t & 63;
    #pragma unroll
    for (int m = 0; m < 3; ++m) {
        const bf16* wm = (m == 0) ? w0 : ((m == 1) ? w1_ : w2_);
        bf16* comp = (m == 0) ? S.q : ((m == 1) ? S.k : S.v);
        __syncthreads();
        stage_w_bf(wm, wl, t);
        __syncthreads();
        f32x4 acc[8];
        #pragma unroll
        for (int n = 0; n < 8; ++n) acc[n] = {0.f, 0.f, 0.f, 0.f};
        gemm64(xl, wl, w, l, acc);
        qkv_epi(acc, comp, p0, w, l);
    }
}

// ---- cross-attn QKV: Q from xq, K+V from xkv (one set) --------------------
__global__ __launch_bounds__(256, 2)
void qkv_cross(const bf16* __restrict__ xq, const bf16* __restrict__ xkv,
               const bf16* __restrict__ wq, const bf16* __restrict__ wk,
               const bf16* __restrict__ wv, Set S) {
    __shared__ bf16 xl[64 * LDT];
    __shared__ bf16 wl[CH * LDT];
    const int t = threadIdx.x, p0 = blockIdx.x * 64;
    const int w = t >> 6, l = t & 63;

    stage_x_cl(xq + (size_t)p0 * CH, CH, xl, t);
    stage_w_bf(wq, wl, t);
    __syncthreads();
    {
        f32x4 acc[8];
        #pragma unroll
        for (int n = 0; n < 8; ++n) acc[n] = {0.f, 0.f, 0.f, 0.f};
        gemm64(xl, wl, w, l, acc);
        qkv_epi(acc, S.q, p0, w, l);
    }
    __syncthreads();
    stage_x_cl(xkv + (size_t)p0 * CH, CH, xl, t);
    stage_w_bf(wk, wl, t);
    __syncthreads();
    {
        f32x4 acc[8];
        #pragma unroll
        for (int n = 0; n < 8; ++n) acc[n] = {0.f, 0.f, 0.f, 0.f};
        gemm64(xl, wl, w, l, acc);
        qkv_epi(acc, S.k, p0, w, l);
    }
    __syncthreads();
    stage_w_bf(wv, wl, t);
    __syncthreads();
    {
        f32x4 acc[8];
        #pragma unroll
        for (int n = 0; n < 8; ++n) acc[n] = {0.f, 0.f, 0.f, 0.f};
        gemm64(xl, wl, w, l, acc);
        qkv_epi(acc, S.v, p0, w, l);
    }
}

// ---- 5x5 local attention (batch-capable over 2 sets) ----------------------
// Block = (4x32 px tile, head), 512 threads, thread = (px, 8-ch quarter).
// K staged in 23KB halo tile -> QK (shfl_xor combine) -> softmax -> V staged
// into SAME buffer -> PV. T written in-place over own Q slice.
__global__ __launch_bounds__(512)
void attn5b(Set s0, Set s1) {
    __shared__ bf16 kv[HYH * HXH * LDC];          // 23 KB, reused K then V
    const int bid = blockIdx.x, setId = bid / ATB, id = bid - setId * ATB;
    Set S = setId ? s1 : s0;
    const int n = id & 3, tile = id >> 2;
    const int img = tile / 72, rem = tile % 72, tr = rem / 3, tc = rem % 3;
    const int y0 = tr * TY, x0 = tc * TX;
    const int t = threadIdx.x;
    const int p = t >> 2, qtr = t & 3, ch8 = qtr * 8;
    const int ty = p >> 5, tx = p & 31;
    bf16* Qh = S.q + (size_t)n * HP;
    const bf16* Kh = S.k + (size_t)n * HP;
    const bf16* Vh = S.v + (size_t)n * HP;
    const int gp = img * HW + (y0 + ty) * WW + (x0 + tx);
    bf16* qp = Qh + (size_t)gp * 32 + ch8;

    float q[8];
    {
        bf16x8 v = *reinterpret_cast<const bf16x8*>(qp);
        #pragma unroll
        for (int e = 0; e < 8; ++e) q[e] = b2f(v.h[e]) * 0.17677669529663689f;
    }

    #pragma unroll
    for (int i = 0; i < 3; ++i) {
        int id2 = t + 512 * i;
        if (id2 < 1152) {
            int r = id2 / 144, c = id2 - r * 144, px = c >> 2, c8 = (c & 3) * 8;
            int y = y0 + r - 2, x = x0 + px - 2;
            short8v v = {0, 0, 0, 0, 0, 0, 0, 0};
            if ((unsigned)y < (unsigned)HH && (unsigned)x < (unsigned)WW)
                v = *reinterpret_cast<const short8v*>(&Kh[((size_t)(img * HW + y * WW + x)) * 32 + c8]);
            *reinterpret_cast<short8v*>(&kv[(r * HXH + px) * LDC + c8]) = v;
        }
    }
    __syncthreads();

    float corr[25];
    #pragma unroll
    for (int dy = 0; dy < 5; ++dy)
        #pragma unroll
        for (int dx = 0; dx < 5; ++dx) {
            const bf16* kp = &kv[((ty + dy) * HXH + tx + dx) * LDC + ch8];
            bf16x8 v = *reinterpret_cast<const bf16x8*>(kp);
            float s = 0.f;
            #pragma unroll
            for (int e = 0; e < 8; ++e) s += q[e] * b2f(v.h[e]);
            s += __shfl_xor(s, 1);
            s += __shfl_xor(s, 2);
            corr[dy * 5 + dx] = s;
        }

    float m = corr[0];
    #pragma unroll
    for (int j = 1; j < 25; ++j) m = fmaxf(m, corr[j]);
    float sum = 0.f;
    #pragma unroll
    for (int j = 0; j < 25; ++j) {
        float e = __expf(corr[j] - m);
        corr[j] = e; sum += e;
    }
    const float inv = 1.f / sum;

    __syncthreads();
    #pragma unroll
    for (int i = 0; i < 3; ++i) {
        int id2 = t + 512 * i;
        if (id2 < 1152) {
            int r = id2 / 144, c = id2 - r * 144, px = c >> 2, c8 = (c & 3) * 8;
            int y = y0 + r - 2, x = x0 + px - 2;
            short8v v = {0, 0, 0, 0, 0, 0, 0, 0};
            if ((unsigned)y < (unsigned)HH && (unsigned)x < (unsigned)WW)
                v = *reinterpret_cast<const short8v*>(&Vh[((size_t)(img * HW + y * WW + x)) * 32 + c8]);
            *reinterpret_cast<short8v*>(&kv[(r * HXH + px) * LDC + c8]) = v;
        }
    }
    __syncthreads();

    float o[8];
    #pragma unroll
    for (int e = 0; e < 8; ++e) o[e] = 0.f;
    #pragma unroll
    for (int dy = 0; dy < 5; ++dy)
        #pragma unroll
        for (int dx = 0; dx < 5; ++dx) {
            const float a = corr[dy * 5 + dx];
            const bf16* vp = &kv[((ty + dy) * HXH + tx + dx) * LDC + ch8];
            bf16x8 v = *reinterpret_cast<const bf16x8*>(vp);
            #pragma unroll
            for (int e = 0; e < 8; ++e) o[e] += a * b2f(v.h[e]);
        }
    bf16x8 st;
    #pragma unroll
    for (int e = 0; e < 8; ++e) st.h[e] = f2b(o[e] * inv);
    *reinterpret_cast<bf16x8*>(qp) = st;
}

// ---- batched fc conv + resid(pre-LN) + LayerNorm -> bf16 pixel-major ------
template<bool RPLANAR>
__global__ __launch_bounds__(256, 2)
void fcln_b(const bf16* __restrict__ t0, const bf16* __restrict__ t1,
            const void* __restrict__ r0, const void* __restrict__ r1,
            const bf16* __restrict__ wfc, const float* __restrict__ gamma,
            const float* __restrict__ beta, bf16* __restrict__ o0,
            bf16* __restrict__ o1) {
    __shared__ bf16 xl[64 * LDT];
    __shared__ bf16 wl[CH * LDT];
    const int bid = blockIdx.x, half = bid / GH, p0 = (bid % GH) * 64;
    const bf16* tin = half ? t1 : t0;
    const void* residv = half ? r1 : r0;
    bf16* out = half ? o1 : o0;
    const int t = threadIdx.x;
    stage_x_hm(tin, xl, p0, t);
    stage_w_bf(wfc, wl, t);
    __syncthreads();
    const int w = t >> 6, l = t & 63, s = l & 15, g = l >> 4;
    f32x4 acc[8];
    #pragma unroll
    for (int n = 0; n < 8; ++n) acc[n] = {0.f, 0.f, 0.f, 0.f};
    gemm64(xl, wl, w, l, acc);

    const int b = p0 / HW, hw0 = p0 % HW;
    float r[8][4];
    #pragma unroll
    for (int n = 0; n < 8; ++n) {
        const int o = 16 * n + s;
        #pragma unroll
        for (int j = 0; j < 4; ++j) {
            const int px = 16 * w + 4 * g + j;
            float rv;
            if (RPLANAR)
                rv = ((const float*)residv)[(size_t)b * CH * HW + (size_t)o * HW + hw0 + px];
            else
                rv = b2f(((const bf16*)residv)[(size_t)(p0 + px) * CH + o]);
            r[n][j] = acc[n][j] + rv;
        }
    }
    float gm[8], bt[8];
    #pragma unroll
    for (int n = 0; n < 8; ++n) { gm[n] = gamma[16 * n + s]; bt[n] = beta[16 * n + s]; }
    #pragma unroll
    for (int j = 0; j < 4; ++j) {
        float sm = 0.f, sq = 0.f;
        #pragma unroll
        for (int n = 0; n < 8; ++n) { float v = r[n][j]; sm += v; sq += v * v; }
        sm += __shfl_xor(sm, 1); sq += __shfl_xor(sq, 1);
        sm += __shfl_xor(sm, 2); sq += __shfl_xor(sq, 2);
        sm += __shfl_xor(sm, 4); sq += __shfl_xor(sq, 4);
        sm += __shfl_xor(sm, 8); sq += __shfl_xor(sq, 8);
        const float mu = sm * (1.f / 128.f);
        const float var = sq * (1.f / 128.f) - mu * mu;
        const float rs = rsqrtf(var + 1e-6f);
        const int px = 16 * w + 4 * g + j;
        #pragma unroll
        for (int n = 0; n < 8; ++n) {
            const int o = 16 * n + s;
            out[(size_t)(p0 + px) * CH + o] = f2b(gm[n] * (r[n][j] - mu) * rs + bt[n]);
        }
    }
}

// ---- fused FFN (both convs + LN + resid), batched over both tensors -------
// y -> h = relu(W1 y + b1) (LDS) -> y2 = LN(W2 h + b2) + y -> planar f32 out.
// Resid read from the already-staged xl tile; h never leaves the CU.
__global__ __launch_bounds__(256, 2)
void ffn_fused(const bf16* __restrict__ y0, const bf16* __restrict__ y1,
               const float* __restrict__ w1m, const float* __restrict__ b1v,
               const float* __restrict__ w2m, const float* __restrict__ b2v,
               const float* __restrict__ gamma, const float* __restrict__ beta,
               float* __restrict__ o0, float* __restrict__ o1) {
    __shared__ __align__(16) char smem[64 * LDT * 2 * 2 + CH * LDT * 2]; // 69632 B
    bf16*  xl = (bf16*)smem;                          // y tile (kept for resid)
    bf16*  hl = (bf16*)(smem + 64 * LDT * 2);         // hidden tile
    bf16*  wl = (bf16*)(smem + 64 * LDT * 2 * 2);     // W1 then W2
    float* ll = (float*)(smem + 64 * LDT * 2 * 2);    // out bounce (aliases wl)
    const int bid = blockIdx.x, half = bid / GH, p0 = (bid % GH) * 64;
    const bf16* y = half ? y1 : y0;
    float* outp = half ? o1 : o0;
    const int t = threadIdx.x;
    stage_x_cl(y + (size_t)p0 * CH, CH, xl, t);
    stage_w_f32(w1m, wl, t);
    __syncthreads();
    const int w = t >> 6, l = t & 63, s = l & 15, g = l >> 4;
    f32x4 acc[8];
    #pragma unroll
    for (int n = 0; n < 8; ++n) acc[n] = {0.f, 0.f, 0.f, 0.f};
    gemm64(xl, wl, w, l, acc);
    // h = relu(acc + b1) -> hl
    #pragma unroll
    for (int n = 0; n < 8; ++n) {
        const int o = 16 * n + s;
        const float bv = b1v[o];
        #pragma unroll
        for (int j = 0; j < 4; ++j) {
            const int px = 16 * w + 4 * g + j;
            hl[px * LDT + o] = f2b(fmaxf(acc[n][j] + bv, 0.f));
        }
    }
    __syncthreads();                    // gemm1 wl reads + hl writes done
    stage_w_f32(w2m, wl, t);
    __syncthreads();
    f32x4 acc2[8];
    #pragma unroll
    for (int n = 0; n < 8; ++n) acc2[n] = {0.f, 0.f, 0.f, 0.f};
    gemm64(hl, wl, w, l, acc2);

    float gm[8], bt[8], r[8][4];
    #pragma unroll
    for (int n = 0; n < 8; ++n) {
        const int o = 16 * n + s;
        gm[n] = gamma[o]; bt[n] = beta[o];
        const float bv = b2v[o];
        #pragma unroll
        for (int j = 0; j < 4; ++j) r[n][j] = acc2[n][j] + bv;
    }
    float val[8][4];
    #pragma unroll
    for (int j = 0; j < 4; ++j) {
        float sm = 0.f, sq = 0.f;
        #pragma unroll
        for (int n = 0; n < 8; ++n) { float v = r[n][j]; sm += v; sq += v * v; }
        sm += __shfl_xor(sm, 1); sq += __shfl_xor(sq, 1);
        sm += __shfl_xor(sm, 2); sq += __shfl_xor(sq, 2);
        sm += __shfl_xor(sm, 4); sq += __shfl_xor(sq, 4);
        sm += __shfl_xor(sm, 8); sq += __shfl_xor(sq, 8);
        const float mu = sm * (1.f / 128.f);
        const float var = sq * (1.f / 128.f) - mu * mu;
        const float rs = rsqrtf(var + 1e-6f);
        const int px = 16 * w + 4 * g + j;
        #pragma unroll
        for (int n = 0; n < 8; ++n) {
            const int o = 16 * n + s;
            val[n][j] = gm[n] * (r[n][j] - mu) * rs + bt[n]
                      + b2f(xl[px * LDT + o]);        // resid from staged y
        }
    }
    __syncthreads();                    // gemm2 wl reads done -> ll may alias
    #pragma unroll
    for (int n = 0; n < 8; ++n) {
        const int o = 16 * n + s;
        #pragma unroll
        for (int j = 0; j < 4; ++j) ll[o * 65 + 16 * w + 4 * g + j] = val[n][j];
    }
    __syncthreads();
    const int b = p0 / HW, hw0 = p0 % HW;
    #pragma unroll
    for (int i = 0; i < 8; ++i) {
        int id = t + 256 * i, c = id >> 4, p4 = (id & 15) * 4;
        float4 v = { ll[c * 65 + p4], ll[c * 65 + p4 + 1],
                     ll[c * 65 + p4 + 2], ll[c * 65 + p4 + 3] };
        *reinterpret_cast<float4*>(&outp[(size_t)b * CH * HW + (size_t)c * HW + hw0 + p4]) = v;
    }
}

// ---------------------------------------------------------------------------
// Liveness (quarter = 9,437,184 B). ws: W0..W3. d_out: D0..D3 (D1 = Wb 256KB).
//  1 wcvt -> Wb@D1
//  2 qkv_self_b: in1->SA{W0,W1,W2}; in2->SB{D0,D2,D3}
//  3 attn5b(SA,SB): T_A@W0, T_B@D0 (in-place over Q)
//  4 fcln_b<planar>: (T_A,in1)->X1@W3 ; (T_B,in2)->X2@D3 (V_B dead)
//  5 qkv_cross crs1: q=X1@W3, kv=X2@D3 -> C1{W0,W1,W2} (T_A/K_A/V_A dead)
//  6 attn5b(C1,C1) grid ATB: T@W0
//  7 fcln_b<bf16> grid GH: (T@W0, X1@W3) -> Y1@W1 (K dead)
//  8 qkv_cross crs2: q=X2@D3, kv=X1@W3 -> C2{W0,W2,D0} (T/V crs1, T_B dead)
//  9 attn5b(C2,C2): T@W0
// 10 fcln_b<bf16>: (T@W0, X2@D3) -> Y2@W3 (X1 dead after step 8)
// 11 ffn_fused: (Y1@W1 -> out1@D0+D1) ; (Y2@W3 -> out2@D2+D3)
//    No overlap: Y1/Y2 in ws; all d_out quarters dead (Wb last used step 8).
// ---------------------------------------------------------------------------
extern "C" void kernel_launch(void* const* d_in, const int* in_sizes, int n_in,
                              void* d_out, int out_size, void* d_ws, size_t ws_size,
                              hipStream_t stream) {
    (void)in_sizes; (void)n_in; (void)out_size; (void)ws_size;
    const float* in1  = (const float*)d_in[0];
    const float* in2  = (const float*)d_in[1];
    const float* lnw_s= (const float*)d_in[6];
    const float* lnb_s= (const float*)d_in[7];
    const float* lnw_c= (const float*)d_in[12];
    const float* lnb_c= (const float*)d_in[13];
    const float* w1   = (const float*)d_in[14];
    const float* b1   = (const float*)d_in[15];
    const float* w2   = (const float*)d_in[16];
    const float* b2   = (const float*)d_in[17];
    const float* lnw_f= (const float*)d_in[18];
    const float* lnb_f= (const float*)d_in[19];

    const size_t BUF  = (size_t)NPIX * CH;
    const size_t BUFB = BUF * 2;
    char* ws = (char*)d_ws;
    bf16* W0 = (bf16*)(ws + 0 * BUFB);
    bf16* W1 = (bf16*)(ws + 1 * BUFB);
    bf16* W2 = (bf16*)(ws + 2 * BUFB);
    bf16* W3 = (bf16*)(ws + 3 * BUFB);
    bf16* D0 = (bf16*)d_out;
    bf16* D2 = (bf16*)((char*)d_out + 2 * BUFB);
    bf16* D3 = (bf16*)((char*)d_out + 3 * BUFB);
    bf16* Wb = (bf16*)((char*)d_out + 1 * BUFB);   // converted weights @ D1
    float* out1 = (float*)d_out;
    float* out2 = (float*)d_out + BUF;

    const dim3 B(256), BA(512);

    WPtrs wp;
    wp.p[0] = (const float*)d_in[2];  wp.p[1] = (const float*)d_in[3];
    wp.p[2] = (const float*)d_in[4];  wp.p[3] = (const float*)d_in[5];
    wp.p[4] = (const float*)d_in[8];  wp.p[5] = (const float*)d_in[9];
    wp.p[6] = (const float*)d_in[10]; wp.p[7] = (const float*)d_in[11];
    wcvt<<<dim3(128), B, 0, stream>>>(wp, Wb);
    const bf16 *bq_s = Wb, *bk_s = Wb + 16384, *bv_s = Wb + 2 * 16384,
               *bf_s = Wb + 3 * 16384, *bq_c = Wb + 4 * 16384,
               *bk_c = Wb + 5 * 16384, *bv_c = Wb + 6 * 16384,
               *bf_c = Wb + 7 * 16384;

    Set SA = {W0, W1, W2};
    Set SB = {D0, D2, D3};
    bf16* X1 = W3;
    bf16* X2 = D3;

    // self stage (batched)
    qkv_self_b<<<dim3(2 * GH), B, 0, stream>>>(in1, in2, bq_s, bk_s, bv_s, SA, SB);
    attn5b<<<dim3(2 * ATB), BA, 0, stream>>>(SA, SB);
    fcln_b<true><<<dim3(2 * GH), B, 0, stream>>>(SA.q, SB.q, in1, in2,
                                                 bf_s, lnw_s, lnb_s, X1, X2);

    // crs1
    Set C1 = {W0, W1, W2};
    qkv_cross<<<dim3(GH), B, 0, stream>>>(X1, X2, bq_c, bk_c, bv_c, C1);
    attn5b<<<dim3(ATB), BA, 0, stream>>>(C1, C1);
    bf16* Y1 = W1;
    fcln_b<false><<<dim3(GH), B, 0, stream>>>(C1.q, C1.q, X1, X1,
                                              bf_c, lnw_c, lnb_c, Y1, Y1);

    // crs2
    Set C2 = {W0, W2, D0};
    qkv_cross<<<dim3(GH), B, 0, stream>>>(X2, X1, bq_c, bk_c, bv_c, C2);
    attn5b<<<dim3(ATB), BA, 0, stream>>>(C2, C2);
    bf16* Y2 = W3;                                  // X1 dead after crs2 qkv
    fcln_b<false><<<dim3(GH), B, 0, stream>>>(C2.q, C2.q, X2, X2,
                                              bf_c, lnw_c, lnb_c, Y2, Y2);

    // FFNs (batched, fused)
    ffn_fused<<<dim3(2 * GH), B, 0, stream>>>(Y1, Y2, w1, b1, w2, b2,
                                              lnw_f, lnb_f, out1, out2);
}

// Round 9
// 183.612 us; speedup vs baseline: 4.2686x; 1.0888x over previous
//
#include <hip/hip_runtime.h>
#include <hip/hip_bf16.h>

typedef _Float16 h16;
typedef __attribute__((ext_vector_type(8))) _Float16 f16x8v;   // 8 f16 (4 VGPR)
typedef __attribute__((ext_vector_type(2))) _Float16 h2v;      // packed pair
typedef __attribute__((ext_vector_type(4))) float f32x4;       // MFMA acc
#define DI __device__ __forceinline__

constexpr int CH = 128;
constexpr int HH = 96, WW = 96;
constexpr int HW = HH * WW;          // 9216
constexpr int NB = 4;
constexpr int NPIX = NB * HW;        // 36864
constexpr int LDT = 136;             // conv LDS row stride (elems)
constexpr size_t HP = (size_t)NPIX * 32;   // head-plane elements
constexpr int GH = NPIX / 64;        // 576 conv blocks per tensor
// attention tile geometry
constexpr int TY = 4, TX = 32;       // tile pixels
constexpr int HYH = TY + 4, HXH = TX + 4;  // halo 8 x 36
constexpr int LDC = 40;              // LDS ch stride
constexpr int ATB = NPIX / (TY * TX) * 4;  // 1152 attn blocks per set

struct __attribute__((aligned(16))) h16x8 { h16 h[8]; };
struct Set { h16 *q, *k, *v; };      // comp-plane bases, each [4][NPIX][32]

DI float h2f(h16 x) { return (float)x; }
DI h16   f2h(float x) { return (h16)x; }

// ---- GEMM building blocks -------------------------------------------------
// Tile: 64 px x 128 out, K=128. 4 waves. D lane: col(o)=l&15, row=(l>>4)*4+reg.

DI void stage_x_cl(const h16* __restrict__ src, int ldx, h16* xl, int t) {
    #pragma unroll
    for (int i = 0; i < 4; ++i) {
        int id = t + 256 * i, px = id >> 4, cc = (id & 15) * 8;
        *reinterpret_cast<f16x8v*>(&xl[px * LDT + cc]) =
            *reinterpret_cast<const f16x8v*>(&src[(size_t)px * ldx + cc]);
    }
}

// planar f32 [c][HW] -> LDS tile [px][c] f16
DI void stage_x_pl(const float* __restrict__ src, h16* xl, int t) {
    #pragma unroll
    for (int i = 0; i < 8; ++i) {
        int id = t + 256 * i, c = id >> 4, p4 = (id & 15) * 4;
        float4 v = *reinterpret_cast<const float4*>(&src[(size_t)c * HW + p4]);
        xl[(p4 + 0) * LDT + c] = f2h(v.x);
        xl[(p4 + 1) * LDT + c] = f2h(v.y);
        xl[(p4 + 2) * LDT + c] = f2h(v.z);
        xl[(p4 + 3) * LDT + c] = f2h(v.w);
    }
}

// head-major T [h][p][32] -> LDS tile [px][128]
DI void stage_x_hm(const h16* __restrict__ Tq, h16* xl, int p0, int t) {
    const int px = t >> 2, c8 = (t & 3) * 8;
    #pragma unroll
    for (int h = 0; h < 4; ++h)
        *reinterpret_cast<f16x8v*>(&xl[px * LDT + h * 32 + c8]) =
            *reinterpret_cast<const f16x8v*>(&Tq[(size_t)h * HP + (size_t)(p0 + px) * 32 + c8]);
}

DI void stage_w(const float* __restrict__ w, h16* wl, int t) {
    #pragma unroll
    for (int i = 0; i < 8; ++i) {
        int id = t + 256 * i, o = id >> 4, cc = (id & 15) * 8;
        float4 a = *reinterpret_cast<const float4*>(&w[o * CH + cc]);
        float4 b = *reinterpret_cast<const float4*>(&w[o * CH + cc + 4]);
        h16x8 tmp;
        tmp.h[0] = f2h(a.x); tmp.h[1] = f2h(a.y); tmp.h[2] = f2h(a.z); tmp.h[3] = f2h(a.w);
        tmp.h[4] = f2h(b.x); tmp.h[5] = f2h(b.y); tmp.h[6] = f2h(b.z); tmp.h[7] = f2h(b.w);
        *reinterpret_cast<f16x8v*>(&wl[o * LDT + cc]) = *reinterpret_cast<const f16x8v*>(&tmp);
    }
}

DI void gemm64(const h16* xl, const h16* wl, int w, int l, f32x4* acc) {
    const int s = l & 15, g = l >> 4;
    #pragma unroll
    for (int ks = 0; ks < 4; ++ks) {
        f16x8v a = *reinterpret_cast<const f16x8v*>(&xl[(16 * w + s) * LDT + ks * 32 + g * 8]);
        #pragma unroll
        for (int n = 0; n < 8; ++n) {
            f16x8v b = *reinterpret_cast<const f16x8v*>(&wl[(16 * n + s) * LDT + ks * 32 + g * 8]);
            acc[n] = __builtin_amdgcn_mfma_f32_16x16x32_f16(a, b, acc[n], 0, 0, 0);
        }
    }
}

// epilogue into head-major comp plane [head][p][32]
DI void qkv_epi(const f32x4* acc, h16* comp, int p0, int w, int l) {
    const int s = l & 15, g = l >> 4;
    #pragma unroll
    for (int n = 0; n < 8; ++n) {
        const int o = 16 * n + s, head = o >> 5, ch = o & 31;
        h16* pl = comp + (size_t)head * HP;
        #pragma unroll
        for (int j = 0; j < 4; ++j) {
            int px = 16 * w + 4 * g + j;
            pl[(size_t)(p0 + px) * 32 + ch] = f2h(acc[n][j]);
        }
    }
}

// ---- batched self-attn QKV: half0 x0->setA, half1 x1->setB (planar f32) ---
__global__ __launch_bounds__(256, 2)
void qkv_self_b(const float* __restrict__ x0, const float* __restrict__ x1,
                const float* __restrict__ w0, const float* __restrict__ w1_,
                const float* __restrict__ w2_, Set sA, Set sB) {
    __shared__ h16 xl[64 * LDT];
    __shared__ h16 wl[CH * LDT];
    const int bid = blockIdx.x, half = bid / GH, p0 = (bid % GH) * 64;
    const float* xv = half ? x1 : x0;
    Set S = half ? sB : sA;
    const int t = threadIdx.x;
    const int b = p0 / HW, hw0 = p0 % HW;
    stage_x_pl(xv + (size_t)b * CH * HW + hw0, xl, t);
    const int w = t >> 6, l = t & 63;
    #pragma unroll
    for (int m = 0; m < 3; ++m) {
        const float* wm = (m == 0) ? w0 : ((m == 1) ? w1_ : w2_);
        h16* comp = (m == 0) ? S.q : ((m == 1) ? S.k : S.v);
        __syncthreads();
        stage_w(wm, wl, t);
        __syncthreads();
        f32x4 acc[8];
        #pragma unroll
        for (int n = 0; n < 8; ++n) acc[n] = {0.f, 0.f, 0.f, 0.f};
        gemm64(xl, wl, w, l, acc);
        qkv_epi(acc, comp, p0, w, l);
    }
}

// ---- batched cross QKV: half0 (q=xa,kv=xb)->C1, half1 (q=xb,kv=xa)->C2 ----
__global__ __launch_bounds__(256, 2)
void qkv_cross_b(const h16* __restrict__ xa, const h16* __restrict__ xb,
                 const float* __restrict__ wq, const float* __restrict__ wk,
                 const float* __restrict__ wv, Set c1, Set c2) {
    __shared__ h16 xl[64 * LDT];
    __shared__ h16 wl[CH * LDT];
    const int bid = blockIdx.x, half = bid / GH, p0 = (bid % GH) * 64;
    const h16* xq  = half ? xb : xa;
    const h16* xkv = half ? xa : xb;
    Set S = half ? c2 : c1;
    const int t = threadIdx.x;
    const int w = t >> 6, l = t & 63;

    stage_x_cl(xq + (size_t)p0 * CH, CH, xl, t);
    stage_w(wq, wl, t);
    __syncthreads();
    {
        f32x4 acc[8];
        #pragma unroll
        for (int n = 0; n < 8; ++n) acc[n] = {0.f, 0.f, 0.f, 0.f};
        gemm64(xl, wl, w, l, acc);
        qkv_epi(acc, S.q, p0, w, l);
    }
    __syncthreads();
    stage_x_cl(xkv + (size_t)p0 * CH, CH, xl, t);
    stage_w(wk, wl, t);
    __syncthreads();
    {
        f32x4 acc[8];
        #pragma unroll
        for (int n = 0; n < 8; ++n) acc[n] = {0.f, 0.f, 0.f, 0.f};
        gemm64(xl, wl, w, l, acc);
        qkv_epi(acc, S.k, p0, w, l);
    }
    __syncthreads();
    stage_w(wv, wl, t);
    __syncthreads();
    {
        f32x4 acc[8];
        #pragma unroll
        for (int n = 0; n < 8; ++n) acc[n] = {0.f, 0.f, 0.f, 0.f};
        gemm64(xl, wl, w, l, acc);
        qkv_epi(acc, S.v, p0, w, l);
    }
}

// ---- 5x5 local attention (batched over 2 sets), f16 + v_dot2 --------------
// Block = (4x32 px tile, head), 512 threads, thread = (px, 8-ch quarter).
// K staged in 23KB halo -> QK via fdot2 (4/window) + shfl_xor combine ->
// softmax (scale folded into exp arg) -> V staged into SAME buffer -> PV
// (fma_mix pattern). T written in-place over own Q slice.
__global__ __launch_bounds__(512)
void attn5b(Set s0, Set s1) {
    __shared__ h16 kv[HYH * HXH * LDC];          // 23 KB, reused K then V
    const int bid = blockIdx.x, setId = bid / ATB, id = bid - setId * ATB;
    Set S = setId ? s1 : s0;
    const int n = id & 3, tile = id >> 2;
    const int img = tile / 72, rem = tile % 72, tr = rem / 3, tc = rem % 3;
    const int y0 = tr * TY, x0 = tc * TX;
    const int t = threadIdx.x;
    const int p = t >> 2, qtr = t & 3, ch8 = qtr * 8;
    const int ty = p >> 5, tx = p & 31;
    h16* Qh = S.q + (size_t)n * HP;
    const h16* Kh = S.k + (size_t)n * HP;
    const h16* Vh = S.v + (size_t)n * HP;
    const int gp = img * HW + (y0 + ty) * WW + (x0 + tx);
    h16* qp = Qh + (size_t)gp * 32 + ch8;

    f16x8v qv = *reinterpret_cast<const f16x8v*>(qp);

    #pragma unroll
    for (int i = 0; i < 3; ++i) {
        int id2 = t + 512 * i;
        if (id2 < 1152) {
            int r = id2 / 144, c = id2 - r * 144, px = c >> 2, c8 = (c & 3) * 8;
            int y = y0 + r - 2, x = x0 + px - 2;
            f16x8v v = {0, 0, 0, 0, 0, 0, 0, 0};
            if ((unsigned)y < (unsigned)HH && (unsigned)x < (unsigned)WW)
                v = *reinterpret_cast<const f16x8v*>(&Kh[((size_t)(img * HW + y * WW + x)) * 32 + c8]);
            *reinterpret_cast<f16x8v*>(&kv[(r * HXH + px) * LDC + c8]) = v;
        }
    }
    __syncthreads();

    float corr[25];
    #pragma unroll
    for (int dy = 0; dy < 5; ++dy)
        #pragma unroll
        for (int dx = 0; dx < 5; ++dx) {
            f16x8v kvv = *reinterpret_cast<const f16x8v*>(
                &kv[((ty + dy) * HXH + tx + dx) * LDC + ch8]);
            float s;
#if __has_builtin(__builtin_amdgcn_fdot2)
            s = __builtin_amdgcn_fdot2(h2v{qv[0], qv[1]}, h2v{kvv[0], kvv[1]}, 0.f, false);
            s = __builtin_amdgcn_fdot2(h2v{qv[2], qv[3]}, h2v{kvv[2], kvv[3]}, s, false);
            s = __builtin_amdgcn_fdot2(h2v{qv[4], qv[5]}, h2v{kvv[4], kvv[5]}, s, false);
            s = __builtin_amdgcn_fdot2(h2v{qv[6], qv[7]}, h2v{kvv[6], kvv[7]}, s, false);
#else
            s = 0.f;
            #pragma unroll
            for (int e = 0; e < 8; ++e) s += h2f(qv[e]) * h2f(kvv[e]);
#endif
            s += __shfl_xor(s, 1);
            s += __shfl_xor(s, 2);
            corr[dy * 5 + dx] = s;
        }

    float m = corr[0];
    #pragma unroll
    for (int j = 1; j < 25; ++j) m = fmaxf(m, corr[j]);
    const float sc = 0.17677669529663689f;            // 1/sqrt(32)
    float sum = 0.f;
    #pragma unroll
    for (int j = 0; j < 25; ++j) {
        float e = __expf((corr[j] - m) * sc);
        corr[j] = e; sum += e;
    }
    const float inv = 1.f / sum;

    __syncthreads();
    #pragma unroll
    for (int i = 0; i < 3; ++i) {
        int id2 = t + 512 * i;
        if (id2 < 1152) {
            int r = id2 / 144, c = id2 - r * 144, px = c >> 2, c8 = (c & 3) * 8;
            int y = y0 + r - 2, x = x0 + px - 2;
            f16x8v v = {0, 0, 0, 0, 0, 0, 0, 0};
            if ((unsigned)y < (unsigned)HH && (unsigned)x < (unsigned)WW)
                v = *reinterpret_cast<const f16x8v*>(&Vh[((size_t)(img * HW + y * WW + x)) * 32 + c8]);
            *reinterpret_cast<f16x8v*>(&kv[(r * HXH + px) * LDC + c8]) = v;
        }
    }
    __syncthreads();

    float o[8];
    #pragma unroll
    for (int e = 0; e < 8; ++e) o[e] = 0.f;
    #pragma unroll
    for (int dy = 0; dy < 5; ++dy)
        #pragma unroll
        for (int dx = 0; dx < 5; ++dx) {
            const float a = corr[dy * 5 + dx];
            f16x8v v = *reinterpret_cast<const f16x8v*>(
                &kv[((ty + dy) * HXH + tx + dx) * LDC + ch8]);
            #pragma unroll
            for (int e = 0; e < 8; ++e) o[e] += a * h2f(v[e]);   // v_fma_mix
        }
    h16x8 st;
    #pragma unroll
    for (int e = 0; e < 8; ++e) st.h[e] = f2h(o[e] * inv);
    *reinterpret_cast<f16x8v*>(qp) = *reinterpret_cast<const f16x8v*>(&st);
}

// ---- batched fc conv + resid(pre-LN) + LayerNorm -> f16 pixel-major -------
template<bool RPLANAR>
__global__ __launch_bounds__(256, 2)
void fcln_b(const h16* __restrict__ t0, const h16* __restrict__ t1,
            const void* __restrict__ r0, const void* __restrict__ r1,
            const float* __restrict__ wfc, const float* __restrict__ gamma,
            const float* __restrict__ beta, h16* __restrict__ o0,
            h16* __restrict__ o1) {
    __shared__ h16 xl[64 * LDT];
    __shared__ h16 wl[CH * LDT];
    const int bid = blockIdx.x, half = bid / GH, p0 = (bid % GH) * 64;
    const h16* tin = half ? t1 : t0;
    const void* residv = half ? r1 : r0;
    h16* out = half ? o1 : o0;
    const int t = threadIdx.x;
    stage_x_hm(tin, xl, p0, t);
    stage_w(wfc, wl, t);
    __syncthreads();
    const int w = t >> 6, l = t & 63, s = l & 15, g = l >> 4;
    f32x4 acc[8];
    #pragma unroll
    for (int n = 0; n < 8; ++n) acc[n] = {0.f, 0.f, 0.f, 0.f};
    gemm64(xl, wl, w, l, acc);

    const int b = p0 / HW, hw0 = p0 % HW;
    float r[8][4];
    #pragma unroll
    for (int n = 0; n < 8; ++n) {
        const int o = 16 * n + s;
        #pragma unroll
        for (int j = 0; j < 4; ++j) {
            const int px = 16 * w + 4 * g + j;
            float rv;
            if (RPLANAR)
                rv = ((const float*)residv)[(size_t)b * CH * HW + (size_t)o * HW + hw0 + px];
            else
                rv = h2f(((const h16*)residv)[(size_t)(p0 + px) * CH + o]);
            r[n][j] = acc[n][j] + rv;
        }
    }
    float gm[8], bt[8];
    #pragma unroll
    for (int n = 0; n < 8; ++n) { gm[n] = gamma[16 * n + s]; bt[n] = beta[16 * n + s]; }
    #pragma unroll
    for (int j = 0; j < 4; ++j) {
        float sm = 0.f, sq = 0.f;
        #pragma unroll
        for (int n = 0; n < 8; ++n) { float v = r[n][j]; sm += v; sq += v * v; }
        sm += __shfl_xor(sm, 1); sq += __shfl_xor(sq, 1);
        sm += __shfl_xor(sm, 2); sq += __shfl_xor(sq, 2);
        sm += __shfl_xor(sm, 4); sq += __shfl_xor(sq, 4);
        sm += __shfl_xor(sm, 8); sq += __shfl_xor(sq, 8);
        const float mu = sm * (1.f / 128.f);
        const float var = sq * (1.f / 128.f) - mu * mu;
        const float rs = rsqrtf(var + 1e-6f);
        const int px = 16 * w + 4 * g + j;
        #pragma unroll
        for (int n = 0; n < 8; ++n) {
            const int o = 16 * n + s;
            out[(size_t)(p0 + px) * CH + o] = f2h(gm[n] * (r[n][j] - mu) * rs + bt[n]);
        }
    }
}

// ---- fused FFN (both convs + LN + resid), batched over both tensors -------
__global__ __launch_bounds__(256, 2)
void ffn_fused(const h16* __restrict__ y0, const h16* __restrict__ y1,
               const float* __restrict__ w1m, const float* __restrict__ b1v,
               const float* __restrict__ w2m, const float* __restrict__ b2v,
               const float* __restrict__ gamma, const float* __restrict__ beta,
               float* __restrict__ o0, float* __restrict__ o1) {
    __shared__ __align__(16) char smem[64 * LDT * 2 * 2 + CH * LDT * 2]; // 69632 B
    h16*   xl = (h16*)smem;                           // y tile (kept for resid)
    h16*   hl = (h16*)(smem + 64 * LDT * 2);          // hidden tile
    h16*   wl = (h16*)(smem + 64 * LDT * 2 * 2);      // W1 then W2
    float* ll = (float*)(smem + 64 * LDT * 2 * 2);    // out bounce (aliases wl)
    const int bid = blockIdx.x, half = bid / GH, p0 = (bid % GH) * 64;
    const h16* y = half ? y1 : y0;
    float* outp = half ? o1 : o0;
    const int t = threadIdx.x;
    stage_x_cl(y + (size_t)p0 * CH, CH, xl, t);
    stage_w(w1m, wl, t);
    __syncthreads();
    const int w = t >> 6, l = t & 63, s = l & 15, g = l >> 4;
    f32x4 acc[8];
    #pragma unroll
    for (int n = 0; n < 8; ++n) acc[n] = {0.f, 0.f, 0.f, 0.f};
    gemm64(xl, wl, w, l, acc);
    #pragma unroll
    for (int n = 0; n < 8; ++n) {
        const int o = 16 * n + s;
        const float bv = b1v[o];
        #pragma unroll
        for (int j = 0; j < 4; ++j) {
            const int px = 16 * w + 4 * g + j;
            hl[px * LDT + o] = f2h(fmaxf(acc[n][j] + bv, 0.f));
        }
    }
    __syncthreads();                    // gemm1 wl reads + hl writes done
    stage_w(w2m, wl, t);
    __syncthreads();
    f32x4 acc2[8];
    #pragma unroll
    for (int n = 0; n < 8; ++n) acc2[n] = {0.f, 0.f, 0.f, 0.f};
    gemm64(hl, wl, w, l, acc2);

    float gm[8], bt[8], r[8][4];
    #pragma unroll
    for (int n = 0; n < 8; ++n) {
        const int o = 16 * n + s;
        gm[n] = gamma[o]; bt[n] = beta[o];
        const float bv = b2v[o];
        #pragma unroll
        for (int j = 0; j < 4; ++j) r[n][j] = acc2[n][j] + bv;
    }
    float val[8][4];
    #pragma unroll
    for (int j = 0; j < 4; ++j) {
        float sm = 0.f, sq = 0.f;
        #pragma unroll
        for (int n = 0; n < 8; ++n) { float v = r[n][j]; sm += v; sq += v * v; }
        sm += __shfl_xor(sm, 1); sq += __shfl_xor(sq, 1);
        sm += __shfl_xor(sm, 2); sq += __shfl_xor(sq, 2);
        sm += __shfl_xor(sm, 4); sq += __shfl_xor(sq, 4);
        sm += __shfl_xor(sm, 8); sq += __shfl_xor(sq, 8);
        const float mu = sm * (1.f / 128.f);
        const float var = sq * (1.f / 128.f) - mu * mu;
        const float rs = rsqrtf(var + 1e-6f);
        const int px = 16 * w + 4 * g + j;
        #pragma unroll
        for (int n = 0; n < 8; ++n) {
            const int o = 16 * n + s;
            val[n][j] = gm[n] * (r[n][j] - mu) * rs + bt[n]
                      + h2f(xl[px * LDT + o]);        // resid from staged y
        }
    }
    __syncthreads();                    // gemm2 wl reads done -> ll may alias
    #pragma unroll
    for (int n = 0; n < 8; ++n) {
        const int o = 16 * n + s;
        #pragma unroll
        for (int j = 0; j < 4; ++j) ll[o * 65 + 16 * w + 4 * g + j] = val[n][j];
    }
    __syncthreads();
    const int b = p0 / HW, hw0 = p0 % HW;
    #pragma unroll
    for (int i = 0; i < 8; ++i) {
        int id = t + 256 * i, c = id >> 4, p4 = (id & 15) * 4;
        float4 v = { ll[c * 65 + p4], ll[c * 65 + p4 + 1],
                     ll[c * 65 + p4 + 2], ll[c * 65 + p4 + 3] };
        *reinterpret_cast<float4*>(&outp[(size_t)b * CH * HW + (size_t)c * HW + hw0 + p4]) = v;
    }
}

// ---------------------------------------------------------------------------
// 7 dispatches. Quarters: ws W0..W3, d_out D0..D3 (all f16 planes until the
// final f32 out writes).
//  1 qkv_self_b : in1->SA{W0,W1,W2}, in2->SB{W3,D0,D1}
//  2 attn5b(SA,SB): T_A@W0, T_B@W3 (in-place over Q)
//  3 fcln_b<planar>: (T_A,in1)->X1@D2 ; (T_B,in2)->X2@D3
//  4 qkv_cross_b(X1,X2): C1{W0,W1,W2} (q=X1,kv=X2) ; C2{W3,D0,D1} (q=X2,kv=X1)
//  5 attn5b(C1,C2): T1@W0, T2@W3
//  6 fcln_b<f16>: (T1, resid X1@D2)->Y1@W1 ; (T2, resid X2@D3)->Y2@W2
//  7 ffn_fused: Y1@W1->out1@(D0+D1) ; Y2@W2->out2@(D2+D3)
//    D0/D1 dead after step 5; D2/D3 (X1/X2) dead after step 6. Stream-ordered.
// ---------------------------------------------------------------------------
extern "C" void kernel_launch(void* const* d_in, const int* in_sizes, int n_in,
                              void* d_out, int out_size, void* d_ws, size_t ws_size,
                              hipStream_t stream) {
    (void)in_sizes; (void)n_in; (void)out_size; (void)ws_size;
    const float* in1  = (const float*)d_in[0];
    const float* in2  = (const float*)d_in[1];
    const float* wq_s = (const float*)d_in[2];
    const float* wk_s = (const float*)d_in[3];
    const float* wv_s = (const float*)d_in[4];
    const float* fc_s = (const float*)d_in[5];
    const float* lnw_s= (const float*)d_in[6];
    const float* lnb_s= (const float*)d_in[7];
    const float* wq_c = (const float*)d_in[8];
    const float* wk_c = (const float*)d_in[9];
    const float* wv_c = (const float*)d_in[10];
    const float* fc_c = (const float*)d_in[11];
    const float* lnw_c= (const float*)d_in[12];
    const float* lnb_c= (const float*)d_in[13];
    const float* w1   = (const float*)d_in[14];
    const float* b1   = (const float*)d_in[15];
    const float* w2   = (const float*)d_in[16];
    const float* b2   = (const float*)d_in[17];
    const float* lnw_f= (const float*)d_in[18];
    const float* lnb_f= (const float*)d_in[19];

    const size_t BUF  = (size_t)NPIX * CH;
    const size_t BUFB = BUF * 2;
    char* ws = (char*)d_ws;
    h16* W0 = (h16*)(ws + 0 * BUFB);
    h16* W1 = (h16*)(ws + 1 * BUFB);
    h16* W2 = (h16*)(ws + 2 * BUFB);
    h16* W3 = (h16*)(ws + 3 * BUFB);
    h16* D0 = (h16*)d_out;
    h16* D1 = (h16*)((char*)d_out + 1 * BUFB);
    h16* D2 = (h16*)((char*)d_out + 2 * BUFB);
    h16* D3 = (h16*)((char*)d_out + 3 * BUFB);
    float* out1 = (float*)d_out;
    float* out2 = (float*)d_out + BUF;

    const dim3 B(256), BA(512);

    Set SA = {W0, W1, W2};
    Set SB = {W3, D0, D1};
    h16* X1 = D2;
    h16* X2 = D3;

    // self stage (batched)
    qkv_self_b<<<dim3(2 * GH), B, 0, stream>>>(in1, in2, wq_s, wk_s, wv_s, SA, SB);
    attn5b<<<dim3(2 * ATB), BA, 0, stream>>>(SA, SB);
    fcln_b<true><<<dim3(2 * GH), B, 0, stream>>>(SA.q, SB.q, in1, in2,
                                                 fc_s, lnw_s, lnb_s, X1, X2);

    // cross stage (batched: crs1 and crs2 are independent)
    Set C1 = {W0, W1, W2};
    Set C2 = {W3, D0, D1};
    qkv_cross_b<<<dim3(2 * GH), B, 0, stream>>>(X1, X2, wq_c, wk_c, wv_c, C1, C2);
    attn5b<<<dim3(2 * ATB), BA, 0, stream>>>(C1, C2);
    h16* Y1 = W1;
    h16* Y2 = W2;
    fcln_b<false><<<dim3(2 * GH), B, 0, stream>>>(C1.q, C2.q, X1, X2,
                                                  fc_c, lnw_c, lnb_c, Y1, Y2);

    // FFNs (batched, fused)
    ffn_fused<<<dim3(2 * GH), B, 0, stream>>>(Y1, Y2, w1, b1, w2, b2,
                                              lnw_f, lnb_f, out1, out2);
}

// Round 10
// 162.930 us; speedup vs baseline: 4.8104x; 1.1269x over previous
//
#include <hip/hip_runtime.h>
#include <hip/hip_bf16.h>

typedef _Float16 h16;
typedef __attribute__((ext_vector_type(8))) _Float16 f16x8v;   // 8 f16 (4 VGPR)
typedef __attribute__((ext_vector_type(2))) _Float16 h2v;      // packed pair
typedef __attribute__((ext_vector_type(4))) float f32x4;       // MFMA acc
#define DI __device__ __forceinline__

constexpr int CH = 128;
constexpr int HH = 96, WW = 96;
constexpr int HW = HH * WW;          // 9216
constexpr int NB = 4;
constexpr int NPIX = NB * HW;        // 36864
constexpr int LDT = 136;             // conv LDS row stride (elems)
constexpr size_t HP = (size_t)NPIX * 32;   // head-plane elements
constexpr int GH = NPIX / 64;        // 576 conv blocks per tensor
// attention tile geometry
constexpr int TY = 4, TX = 32;       // tile pixels
constexpr int HYH = TY + 4, HXH = TX + 4;  // halo 8 x 36
constexpr int LDC = 40;              // LDS ch stride
constexpr int ATB = NPIX / (TY * TX) * 4;  // 1152 attn blocks per set

struct __attribute__((aligned(16))) h16x8 { h16 h[8]; };
struct Set { h16 *q, *k, *v; };      // comp-plane bases, each [4][NPIX][32]

DI float h2f(h16 x) { return (float)x; }
DI h16   f2h(float x) { return (h16)x; }

// ---- GEMM building blocks -------------------------------------------------
// Tile: 64 px x 128 out, K=128. 4 waves. D lane: col(o)=l&15, row=(l>>4)*4+reg.

DI void stage_x_cl(const h16* __restrict__ src, int ldx, h16* xl, int t) {
    #pragma unroll
    for (int i = 0; i < 4; ++i) {
        int id = t + 256 * i, px = id >> 4, cc = (id & 15) * 8;
        *reinterpret_cast<f16x8v*>(&xl[px * LDT + cc]) =
            *reinterpret_cast<const f16x8v*>(&src[(size_t)px * ldx + cc]);
    }
}

// planar f32 [c][HW] -> LDS tile [px][c] f16
DI void stage_x_pl(const float* __restrict__ src, h16* xl, int t) {
    #pragma unroll
    for (int i = 0; i < 8; ++i) {
        int id = t + 256 * i, c = id >> 4, p4 = (id & 15) * 4;
        float4 v = *reinterpret_cast<const float4*>(&src[(size_t)c * HW + p4]);
        xl[(p4 + 0) * LDT + c] = f2h(v.x);
        xl[(p4 + 1) * LDT + c] = f2h(v.y);
        xl[(p4 + 2) * LDT + c] = f2h(v.z);
        xl[(p4 + 3) * LDT + c] = f2h(v.w);
    }
}

// head-major T [h][p][32] -> LDS tile [px][128]
DI void stage_x_hm(const h16* __restrict__ Tq, h16* xl, int p0, int t) {
    const int px = t >> 2, c8 = (t & 3) * 8;
    #pragma unroll
    for (int h = 0; h < 4; ++h)
        *reinterpret_cast<f16x8v*>(&xl[px * LDT + h * 32 + c8]) =
            *reinterpret_cast<const f16x8v*>(&Tq[(size_t)h * HP + (size_t)(p0 + px) * 32 + c8]);
}

DI void stage_w(const float* __restrict__ w, h16* wl, int t) {
    #pragma unroll
    for (int i = 0; i < 8; ++i) {
        int id = t + 256 * i, o = id >> 4, cc = (id & 15) * 8;
        float4 a = *reinterpret_cast<const float4*>(&w[o * CH + cc]);
        float4 b = *reinterpret_cast<const float4*>(&w[o * CH + cc + 4]);
        h16x8 tmp;
        tmp.h[0] = f2h(a.x); tmp.h[1] = f2h(a.y); tmp.h[2] = f2h(a.z); tmp.h[3] = f2h(a.w);
        tmp.h[4] = f2h(b.x); tmp.h[5] = f2h(b.y); tmp.h[6] = f2h(b.z); tmp.h[7] = f2h(b.w);
        *reinterpret_cast<f16x8v*>(&wl[o * LDT + cc]) = *reinterpret_cast<const f16x8v*>(&tmp);
    }
}

DI void gemm64(const h16* xl, const h16* wl, int w, int l, f32x4* acc) {
    const int s = l & 15, g = l >> 4;
    #pragma unroll
    for (int ks = 0; ks < 4; ++ks) {
        f16x8v a = *reinterpret_cast<const f16x8v*>(&xl[(16 * w + s) * LDT + ks * 32 + g * 8]);
        #pragma unroll
        for (int n = 0; n < 8; ++n) {
            f16x8v b = *reinterpret_cast<const f16x8v*>(&wl[(16 * n + s) * LDT + ks * 32 + g * 8]);
            acc[n] = __builtin_amdgcn_mfma_f32_16x16x32_f16(a, b, acc[n], 0, 0, 0);
        }
    }
}

// epilogue into head-major comp plane [head][p][32]
DI void qkv_epi(const f32x4* acc, h16* comp, int p0, int w, int l) {
    const int s = l & 15, g = l >> 4;
    #pragma unroll
    for (int n = 0; n < 8; ++n) {
        const int o = 16 * n + s, head = o >> 5, ch = o & 31;
        h16* pl = comp + (size_t)head * HP;
        #pragma unroll
        for (int j = 0; j < 4; ++j) {
            int px = 16 * w + 4 * g + j;
            pl[(size_t)(p0 + px) * 32 + ch] = f2h(acc[n][j]);
        }
    }
}

// ---- batched self-attn QKV: half0 x0->setA, half1 x1->setB (planar f32) ---
__global__ __launch_bounds__(256, 2)
void qkv_self_b(const float* __restrict__ x0, const float* __restrict__ x1,
                const float* __restrict__ w0, const float* __restrict__ w1_,
                const float* __restrict__ w2_, Set sA, Set sB) {
    __shared__ h16 xl[64 * LDT];
    __shared__ h16 wl[CH * LDT];
    const int bid = blockIdx.x, half = bid / GH, p0 = (bid % GH) * 64;
    const float* xv = half ? x1 : x0;
    Set S = half ? sB : sA;
    const int t = threadIdx.x;
    const int b = p0 / HW, hw0 = p0 % HW;
    stage_x_pl(xv + (size_t)b * CH * HW + hw0, xl, t);
    const int w = t >> 6, l = t & 63;
    #pragma unroll
    for (int m = 0; m < 3; ++m) {
        const float* wm = (m == 0) ? w0 : ((m == 1) ? w1_ : w2_);
        h16* comp = (m == 0) ? S.q : ((m == 1) ? S.k : S.v);
        __syncthreads();
        stage_w(wm, wl, t);
        __syncthreads();
        f32x4 acc[8];
        #pragma unroll
        for (int n = 0; n < 8; ++n) acc[n] = {0.f, 0.f, 0.f, 0.f};
        gemm64(xl, wl, w, l, acc);
        qkv_epi(acc, comp, p0, w, l);
    }
}

// ---- batched cross QKV: half0 (q=xa,kv=xb)->C1, half1 (q=xb,kv=xa)->C2 ----
__global__ __launch_bounds__(256, 2)
void qkv_cross_b(const h16* __restrict__ xa, const h16* __restrict__ xb,
                 const float* __restrict__ wq, const float* __restrict__ wk,
                 const float* __restrict__ wv, Set c1, Set c2) {
    __shared__ h16 xl[64 * LDT];
    __shared__ h16 wl[CH * LDT];
    const int bid = blockIdx.x, half = bid / GH, p0 = (bid % GH) * 64;
    const h16* xq  = half ? xb : xa;
    const h16* xkv = half ? xa : xb;
    Set S = half ? c2 : c1;
    const int t = threadIdx.x;
    const int w = t >> 6, l = t & 63;

    stage_x_cl(xq + (size_t)p0 * CH, CH, xl, t);
    stage_w(wq, wl, t);
    __syncthreads();
    {
        f32x4 acc[8];
        #pragma unroll
        for (int n = 0; n < 8; ++n) acc[n] = {0.f, 0.f, 0.f, 0.f};
        gemm64(xl, wl, w, l, acc);
        qkv_epi(acc, S.q, p0, w, l);
    }
    __syncthreads();
    stage_x_cl(xkv + (size_t)p0 * CH, CH, xl, t);
    stage_w(wk, wl, t);
    __syncthreads();
    {
        f32x4 acc[8];
        #pragma unroll
        for (int n = 0; n < 8; ++n) acc[n] = {0.f, 0.f, 0.f, 0.f};
        gemm64(xl, wl, w, l, acc);
        qkv_epi(acc, S.k, p0, w, l);
    }
    __syncthreads();
    stage_w(wv, wl, t);
    __syncthreads();
    {
        f32x4 acc[8];
        #pragma unroll
        for (int n = 0; n < 8; ++n) acc[n] = {0.f, 0.f, 0.f, 0.f};
        gemm64(xl, wl, w, l, acc);
        qkv_epi(acc, S.v, p0, w, l);
    }
}

// ---- 5x5 local attention (batched over 2 sets) ----------------------------
// Block = (4x32 px tile, head), 256 threads; 2 lanes per (px,head), 16 ch
// each (r10: was 4 lanes/8ch — 50 ds_swizzle/wave dominated the DS pipe).
// K staged in 23KB halo -> QK via 8 fdot2 + ONE shfl_xor -> softmax (scale
// pre-folded into Q) -> V staged into same buffer -> PV in packed-f16
// (v_pk_fma_f16, unnormalized; one packed scale by 1/sum at the end).
// T written in-place over own Q slice.
__global__ __launch_bounds__(256)
void attn5b(Set s0, Set s1) {
    __shared__ h16 kv[HYH * HXH * LDC];          // 23 KB, reused K then V
    const int bid = blockIdx.x, setId = bid / ATB, id = bid - setId * ATB;
    Set S = setId ? s1 : s0;
    const int n = id & 3, tile = id >> 2;
    const int img = tile / 72, rem = tile % 72, tr = rem / 3, tc = rem % 3;
    const int y0 = tr * TY, x0 = tc * TX;
    const int t = threadIdx.x;
    const int p = t >> 1, half = t & 1, ch16 = half * 16;
    const int ty = p >> 5, tx = p & 31;
    h16* Qh = S.q + (size_t)n * HP;
    const h16* Kh = S.k + (size_t)n * HP;
    const h16* Vh = S.v + (size_t)n * HP;
    const int gp = img * HW + (y0 + ty) * WW + (x0 + tx);
    h16* qp = Qh + (size_t)gp * 32 + ch16;

    // own Q slice (16 ch), pre-scaled by 1/sqrt(32) (packed muls)
    f16x8v q0 = *reinterpret_cast<const f16x8v*>(qp);
    f16x8v q1 = *reinterpret_cast<const f16x8v*>(qp + 8);
    {
        const h16 sc = (h16)0.17677669529663689f;
        #pragma unroll
        for (int e = 0; e < 8; ++e) { q0[e] *= sc; q1[e] *= sc; }
    }

    // stage K halo: 8 x 36 px x 4 ch8-chunks = 1152 chunks over 256 threads
    #pragma unroll
    for (int i = 0; i < 5; ++i) {
        int id2 = t + 256 * i;
        if (id2 < 1152) {
            int r = id2 / 144, c = id2 - r * 144, px = c >> 2, c8 = (c & 3) * 8;
            int y = y0 + r - 2, x = x0 + px - 2;
            f16x8v v = {0, 0, 0, 0, 0, 0, 0, 0};
            if ((unsigned)y < (unsigned)HH && (unsigned)x < (unsigned)WW)
                v = *reinterpret_cast<const f16x8v*>(&Kh[((size_t)(img * HW + y * WW + x)) * 32 + c8]);
            *reinterpret_cast<f16x8v*>(&kv[(r * HXH + px) * LDC + c8]) = v;
        }
    }
    __syncthreads();

    float corr[25];
    #pragma unroll
    for (int dy = 0; dy < 5; ++dy)
        #pragma unroll
        for (int dx = 0; dx < 5; ++dx) {
            const h16* kp = &kv[((ty + dy) * HXH + tx + dx) * LDC + ch16];
            f16x8v k0 = *reinterpret_cast<const f16x8v*>(kp);
            f16x8v k1 = *reinterpret_cast<const f16x8v*>(kp + 8);
            float s;
#if __has_builtin(__builtin_amdgcn_fdot2)
            s = __builtin_amdgcn_fdot2(h2v{q0[0], q0[1]}, h2v{k0[0], k0[1]}, 0.f, false);
            s = __builtin_amdgcn_fdot2(h2v{q0[2], q0[3]}, h2v{k0[2], k0[3]}, s, false);
            s = __builtin_amdgcn_fdot2(h2v{q0[4], q0[5]}, h2v{k0[4], k0[5]}, s, false);
            s = __builtin_amdgcn_fdot2(h2v{q0[6], q0[7]}, h2v{k0[6], k0[7]}, s, false);
            s = __builtin_amdgcn_fdot2(h2v{q1[0], q1[1]}, h2v{k1[0], k1[1]}, s, false);
            s = __builtin_amdgcn_fdot2(h2v{q1[2], q1[3]}, h2v{k1[2], k1[3]}, s, false);
            s = __builtin_amdgcn_fdot2(h2v{q1[4], q1[5]}, h2v{k1[4], k1[5]}, s, false);
            s = __builtin_amdgcn_fdot2(h2v{q1[6], q1[7]}, h2v{k1[6], k1[7]}, s, false);
#else
            s = 0.f;
            #pragma unroll
            for (int e = 0; e < 8; ++e) s += h2f(q0[e]) * h2f(k0[e]);
            #pragma unroll
            for (int e = 0; e < 8; ++e) s += h2f(q1[e]) * h2f(k1[e]);
#endif
            s += __shfl_xor(s, 1);
            corr[dy * 5 + dx] = s;
        }

    float m = corr[0];
    #pragma unroll
    for (int j = 1; j < 25; ++j) m = fmaxf(m, corr[j]);
    float sum = 0.f;
    #pragma unroll
    for (int j = 0; j < 25; ++j) {
        float e = __expf(corr[j] - m);
        corr[j] = e; sum += e;
    }
    const float inv = 1.f / sum;

    __syncthreads();                               // all K reads done
    #pragma unroll
    for (int i = 0; i < 5; ++i) {
        int id2 = t + 256 * i;
        if (id2 < 1152) {
            int r = id2 / 144, c = id2 - r * 144, px = c >> 2, c8 = (c & 3) * 8;
            int y = y0 + r - 2, x = x0 + px - 2;
            f16x8v v = {0, 0, 0, 0, 0, 0, 0, 0};
            if ((unsigned)y < (unsigned)HH && (unsigned)x < (unsigned)WW)
                v = *reinterpret_cast<const f16x8v*>(&Vh[((size_t)(img * HW + y * WW + x)) * 32 + c8]);
            *reinterpret_cast<f16x8v*>(&kv[(r * HXH + px) * LDC + c8]) = v;
        }
    }
    __syncthreads();

    // PV: packed-f16 accumulate (unnormalized), scale by inv at the end
    f16x8v o0 = {0, 0, 0, 0, 0, 0, 0, 0};
    f16x8v o1 = {0, 0, 0, 0, 0, 0, 0, 0};
    #pragma unroll
    for (int dy = 0; dy < 5; ++dy)
        #pragma unroll
        for (int dx = 0; dx < 5; ++dx) {
            const h16 ah = f2h(corr[dy * 5 + dx]);
            const f16x8v av = {ah, ah, ah, ah, ah, ah, ah, ah};
            const h16* vp = &kv[((ty + dy) * HXH + tx + dx) * LDC + ch16];
            f16x8v v0 = *reinterpret_cast<const f16x8v*>(vp);
            f16x8v v1 = *reinterpret_cast<const f16x8v*>(vp + 8);
            o0 += av * v0;                       // v_pk_fma_f16
            o1 += av * v1;
        }
    {
        const h16 ih = f2h(inv);
        const f16x8v iv = {ih, ih, ih, ih, ih, ih, ih, ih};
        o0 *= iv; o1 *= iv;
    }
    *reinterpret_cast<f16x8v*>(qp)     = o0;
    *reinterpret_cast<f16x8v*>(qp + 8) = o1;
}

// ---- batched fc conv + resid(pre-LN) + LayerNorm -> f16 pixel-major -------
template<bool RPLANAR>
__global__ __launch_bounds__(256, 2)
void fcln_b(const h16* __restrict__ t0, const h16* __restrict__ t1,
            const void* __restrict__ r0, const void* __restrict__ r1,
            const float* __restrict__ wfc, const float* __restrict__ gamma,
            const float* __restrict__ beta, h16* __restrict__ o0,
            h16* __restrict__ o1) {
    __shared__ h16 xl[64 * LDT];
    __shared__ h16 wl[CH * LDT];
    const int bid = blockIdx.x, half = bid / GH, p0 = (bid % GH) * 64;
    const h16* tin = half ? t1 : t0;
    const void* residv = half ? r1 : r0;
    h16* out = half ? o1 : o0;
    const int t = threadIdx.x;
    stage_x_hm(tin, xl, p0, t);
    stage_w(wfc, wl, t);
    __syncthreads();
    const int w = t >> 6, l = t & 63, s = l & 15, g = l >> 4;
    f32x4 acc[8];
    #pragma unroll
    for (int n = 0; n < 8; ++n) acc[n] = {0.f, 0.f, 0.f, 0.f};
    gemm64(xl, wl, w, l, acc);

    const int b = p0 / HW, hw0 = p0 % HW;
    float r[8][4];
    #pragma unroll
    for (int n = 0; n < 8; ++n) {
        const int o = 16 * n + s;
        #pragma unroll
        for (int j = 0; j < 4; ++j) {
            const int px = 16 * w + 4 * g + j;
            float rv;
            if (RPLANAR)
                rv = ((const float*)residv)[(size_t)b * CH * HW + (size_t)o * HW + hw0 + px];
            else
                rv = h2f(((const h16*)residv)[(size_t)(p0 + px) * CH + o]);
            r[n][j] = acc[n][j] + rv;
        }
    }
    float gm[8], bt[8];
    #pragma unroll
    for (int n = 0; n < 8; ++n) { gm[n] = gamma[16 * n + s]; bt[n] = beta[16 * n + s]; }
    #pragma unroll
    for (int j = 0; j < 4; ++j) {
        float sm = 0.f, sq = 0.f;
        #pragma unroll
        for (int n = 0; n < 8; ++n) { float v = r[n][j]; sm += v; sq += v * v; }
        sm += __shfl_xor(sm, 1); sq += __shfl_xor(sq, 1);
        sm += __shfl_xor(sm, 2); sq += __shfl_xor(sq, 2);
        sm += __shfl_xor(sm, 4); sq += __shfl_xor(sq, 4);
        sm += __shfl_xor(sm, 8); sq += __shfl_xor(sq, 8);
        const float mu = sm * (1.f / 128.f);
        const float var = sq * (1.f / 128.f) - mu * mu;
        const float rs = rsqrtf(var + 1e-6f);
        const int px = 16 * w + 4 * g + j;
        #pragma unroll
        for (int n = 0; n < 8; ++n) {
            const int o = 16 * n + s;
            out[(size_t)(p0 + px) * CH + o] = f2h(gm[n] * (r[n][j] - mu) * rs + bt[n]);
        }
    }
}

// ---- fused FFN (both convs + LN + resid), batched over both tensors -------
__global__ __launch_bounds__(256, 2)
void ffn_fused(const h16* __restrict__ y0, const h16* __restrict__ y1,
               const float* __restrict__ w1m, const float* __restrict__ b1v,
               const float* __restrict__ w2m, const float* __restrict__ b2v,
               const float* __restrict__ gamma, const float* __restrict__ beta,
               float* __restrict__ o0, float* __restrict__ o1) {
    __shared__ __align__(16) char smem[64 * LDT * 2 * 2 + CH * LDT * 2]; // 69632 B
    h16*   xl = (h16*)smem;                           // y tile (kept for resid)
    h16*   hl = (h16*)(smem + 64 * LDT * 2);          // hidden tile
    h16*   wl = (h16*)(smem + 64 * LDT * 2 * 2);      // W1 then W2
    float* ll = (float*)(smem + 64 * LDT * 2 * 2);    // out bounce (aliases wl)
    const int bid = blockIdx.x, half = bid / GH, p0 = (bid % GH) * 64;
    const h16* y = half ? y1 : y0;
    float* outp = half ? o1 : o0;
    const int t = threadIdx.x;
    stage_x_cl(y + (size_t)p0 * CH, CH, xl, t);
    stage_w(w1m, wl, t);
    __syncthreads();
    const int w = t >> 6, l = t & 63, s = l & 15, g = l >> 4;
    f32x4 acc[8];
    #pragma unroll
    for (int n = 0; n < 8; ++n) acc[n] = {0.f, 0.f, 0.f, 0.f};
    gemm64(xl, wl, w, l, acc);
    #pragma unroll
    for (int n = 0; n < 8; ++n) {
        const int o = 16 * n + s;
        const float bv = b1v[o];
        #pragma unroll
        for (int j = 0; j < 4; ++j) {
            const int px = 16 * w + 4 * g + j;
            hl[px * LDT + o] = f2h(fmaxf(acc[n][j] + bv, 0.f));
        }
    }
    __syncthreads();                    // gemm1 wl reads + hl writes done
    stage_w(w2m, wl, t);
    __syncthreads();
    f32x4 acc2[8];
    #pragma unroll
    for (int n = 0; n < 8; ++n) acc2[n] = {0.f, 0.f, 0.f, 0.f};
    gemm64(hl, wl, w, l, acc2);

    float gm[8], bt[8], r[8][4];
    #pragma unroll
    for (int n = 0; n < 8; ++n) {
        const int o = 16 * n + s;
        gm[n] = gamma[o]; bt[n] = beta[o];
        const float bv = b2v[o];
        #pragma unroll
        for (int j = 0; j < 4; ++j) r[n][j] = acc2[n][j] + bv;
    }
    float val[8][4];
    #pragma unroll
    for (int j = 0; j < 4; ++j) {
        float sm = 0.f, sq = 0.f;
        #pragma unroll
        for (int n = 0; n < 8; ++n) { float v = r[n][j]; sm += v; sq += v * v; }
        sm += __shfl_xor(sm, 1); sq += __shfl_xor(sq, 1);
        sm += __shfl_xor(sm, 2); sq += __shfl_xor(sq, 2);
        sm += __shfl_xor(sm, 4); sq += __shfl_xor(sq, 4);
        sm += __shfl_xor(sm, 8); sq += __shfl_xor(sq, 8);
        const float mu = sm * (1.f / 128.f);
        const float var = sq * (1.f / 128.f) - mu * mu;
        const float rs = rsqrtf(var + 1e-6f);
        const int px = 16 * w + 4 * g + j;
        #pragma unroll
        for (int n = 0; n < 8; ++n) {
            const int o = 16 * n + s;
            val[n][j] = gm[n] * (r[n][j] - mu) * rs + bt[n]
                      + h2f(xl[px * LDT + o]);        // resid from staged y
        }
    }
    __syncthreads();                    // gemm2 wl reads done -> ll may alias
    #pragma unroll
    for (int n = 0; n < 8; ++n) {
        const int o = 16 * n + s;
        #pragma unroll
        for (int j = 0; j < 4; ++j) ll[o * 65 + 16 * w + 4 * g + j] = val[n][j];
    }
    __syncthreads();
    const int b = p0 / HW, hw0 = p0 % HW;
    #pragma unroll
    for (int i = 0; i < 8; ++i) {
        int id = t + 256 * i, c = id >> 4, p4 = (id & 15) * 4;
        float4 v = { ll[c * 65 + p4], ll[c * 65 + p4 + 1],
                     ll[c * 65 + p4 + 2], ll[c * 65 + p4 + 3] };
        *reinterpret_cast<float4*>(&outp[(size_t)b * CH * HW + (size_t)c * HW + hw0 + p4]) = v;
    }
}

// ---------------------------------------------------------------------------
// 7 dispatches. Quarters: ws W0..W3, d_out D0..D3 (all f16 planes until the
// final f32 out writes).
//  1 qkv_self_b : in1->SA{W0,W1,W2}, in2->SB{W3,D0,D1}
//  2 attn5b(SA,SB): T_A@W0, T_B@W3 (in-place over Q)
//  3 fcln_b<planar>: (T_A,in1)->X1@D2 ; (T_B,in2)->X2@D3
//  4 qkv_cross_b(X1,X2): C1{W0,W1,W2} (q=X1,kv=X2) ; C2{W3,D0,D1} (q=X2,kv=X1)
//  5 attn5b(C1,C2): T1@W0, T2@W3
//  6 fcln_b<f16>: (T1, resid X1@D2)->Y1@W1 ; (T2, resid X2@D3)->Y2@W2
//  7 ffn_fused: Y1@W1->out1@(D0+D1) ; Y2@W2->out2@(D2+D3)
//    D0/D1 dead after step 5; D2/D3 (X1/X2) dead after step 6. Stream-ordered.
// ---------------------------------------------------------------------------
extern "C" void kernel_launch(void* const* d_in, const int* in_sizes, int n_in,
                              void* d_out, int out_size, void* d_ws, size_t ws_size,
                              hipStream_t stream) {
    (void)in_sizes; (void)n_in; (void)out_size; (void)ws_size;
    const float* in1  = (const float*)d_in[0];
    const float* in2  = (const float*)d_in[1];
    const float* wq_s = (const float*)d_in[2];
    const float* wk_s = (const float*)d_in[3];
    const float* wv_s = (const float*)d_in[4];
    const float* fc_s = (const float*)d_in[5];
    const float* lnw_s= (const float*)d_in[6];
    const float* lnb_s= (const float*)d_in[7];
    const float* wq_c = (const float*)d_in[8];
    const float* wk_c = (const float*)d_in[9];
    const float* wv_c = (const float*)d_in[10];
    const float* fc_c = (const float*)d_in[11];
    const float* lnw_c= (const float*)d_in[12];
    const float* lnb_c= (const float*)d_in[13];
    const float* w1   = (const float*)d_in[14];
    const float* b1   = (const float*)d_in[15];
    const float* w2   = (const float*)d_in[16];
    const float* b2   = (const float*)d_in[17];
    const float* lnw_f= (const float*)d_in[18];
    const float* lnb_f= (const float*)d_in[19];

    const size_t BUF  = (size_t)NPIX * CH;
    const size_t BUFB = BUF * 2;
    char* ws = (char*)d_ws;
    h16* W0 = (h16*)(ws + 0 * BUFB);
    h16* W1 = (h16*)(ws + 1 * BUFB);
    h16* W2 = (h16*)(ws + 2 * BUFB);
    h16* W3 = (h16*)(ws + 3 * BUFB);
    h16* D0 = (h16*)d_out;
    h16* D1 = (h16*)((char*)d_out + 1 * BUFB);
    h16* D2 = (h16*)((char*)d_out + 2 * BUFB);
    h16* D3 = (h16*)((char*)d_out + 3 * BUFB);
    float* out1 = (float*)d_out;
    float* out2 = (float*)d_out + BUF;

    const dim3 B(256), BA(256);

    Set SA = {W0, W1, W2};
    Set SB = {W3, D0, D1};
    h16* X1 = D2;
    h16* X2 = D3;

    // self stage (batched)
    qkv_self_b<<<dim3(2 * GH), B, 0, stream>>>(in1, in2, wq_s, wk_s, wv_s, SA, SB);
    attn5b<<<dim3(2 * ATB), BA, 0, stream>>>(SA, SB);
    fcln_b<true><<<dim3(2 * GH), B, 0, stream>>>(SA.q, SB.q, in1, in2,
                                                 fc_s, lnw_s, lnb_s, X1, X2);

    // cross stage (batched: crs1 and crs2 are independent)
    Set C1 = {W0, W1, W2};
    Set C2 = {W3, D0, D1};
    qkv_cross_b<<<dim3(2 * GH), B, 0, stream>>>(X1, X2, wq_c, wk_c, wv_c, C1, C2);
    attn5b<<<dim3(2 * ATB), BA, 0, stream>>>(C1, C2);
    h16* Y1 = W1;
    h16* Y2 = W2;
    fcln_b<false><<<dim3(2 * GH), B, 0, stream>>>(C1.q, C2.q, X1, X2,
                                                  fc_c, lnw_c, lnb_c, Y1, Y2);

    // FFNs (batched, fused)
    ffn_fused<<<dim3(2 * GH), B, 0, stream>>>(Y1, Y2, w1, b1, w2, b2,
                                              lnw_f, lnb_f, out1, out2);
}